// Round 2
// baseline (3072.408 us; speedup 1.0000x reference)
//
#include <hip/hip_runtime.h>
#include <math.h>

// Problem constants
static constexpr int Bn    = 4;
static constexpr int Cc    = 128;
static constexpr int Hh    = 128;
static constexpr int Wb    = 128;
static constexpr int Nn    = Hh * Wb;      // 16384
static constexpr int HEADS = 8;
static constexpr int CHh   = 16;           // Cc / HEADS
static constexpr int HID   = 340;
static constexpr int HID2  = 680;

// ---------------------------------------------------------------------------
// LayerNorm over channel axis (axis=1), per pixel.
// grid: (Nn/256, 1, Bt). Pointers pre-offset to batch start; b=blockIdx.z.
// ---------------------------------------------------------------------------
__global__ __launch_bounds__(256) void ln_kernel(const float* __restrict__ in,
                                                 const float* __restrict__ w,
                                                 const float* __restrict__ bias,
                                                 float* __restrict__ out) {
    int p = blockIdx.x * 256 + threadIdx.x;
    int b = blockIdx.z;
    const float* ib = in + (size_t)b * Cc * Nn + p;
    float s = 0.f, s2 = 0.f;
    #pragma unroll 8
    for (int c = 0; c < Cc; ++c) {
        float v = ib[(size_t)c * Nn];
        s += v; s2 += v * v;
    }
    float mean = s * (1.0f / Cc);
    float var  = s2 * (1.0f / Cc) - mean * mean;
    float inv  = 1.0f / sqrtf(var + 1e-6f);
    float* ob = out + (size_t)b * Cc * Nn + p;
    #pragma unroll 8
    for (int c = 0; c < Cc; ++c) {
        float v = ib[(size_t)c * Nn];
        ob[(size_t)c * Nn] = w[c] * ((v - mean) * inv) + bias[c];
    }
}

// ---------------------------------------------------------------------------
// 1x1 conv (GEMM): out[b,co,p] = sum_ci W[co*wstride+ci] * in[b,ci,p]
// grid: (Nn/256, ceil(Cout/TCO), Bt). wgt may be pre-offset (chunking).
// ---------------------------------------------------------------------------
template <int TCO>
__global__ __launch_bounds__(256) void conv1x1_kernel(const float* __restrict__ in,
                                                      const float* __restrict__ wgt,
                                                      int wstride,
                                                      const float* __restrict__ bias,
                                                      const float* __restrict__ res,
                                                      float* __restrict__ out,
                                                      int Cin, int Cout, int act) {
    int p   = blockIdx.x * 256 + threadIdx.x;
    int b   = blockIdx.z;
    int co0 = blockIdx.y * TCO;
    float acc[TCO];
    #pragma unroll
    for (int i = 0; i < TCO; ++i) acc[i] = 0.f;

    const float* ib = in + (size_t)b * Cin * Nn + p;
    for (int ci = 0; ci < Cin; ++ci) {
        float v = ib[(size_t)ci * Nn];
        #pragma unroll
        for (int i = 0; i < TCO; ++i) {
            int co = co0 + i; if (co > Cout - 1) co = Cout - 1;   // uniform clamp
            acc[i] += v * wgt[(size_t)co * wstride + ci];
        }
    }
    #pragma unroll
    for (int i = 0; i < TCO; ++i) {
        int co = co0 + i;
        if (co < Cout) {
            float r = acc[i];
            if (bias) r += bias[co];
            if (act == 1) r = fmaxf(r, 0.f);
            size_t o = ((size_t)b * Cout + co) * Nn + p;
            if (res) r += res[o];
            out[o] = r;
        }
    }
}

// ---------------------------------------------------------------------------
// Depthwise 3x3 conv, pad=1. grid: (Nn/256, Ct, Bt). w pre-offset to channel 0.
// ---------------------------------------------------------------------------
__global__ __launch_bounds__(256) void dw3x3_kernel(const float* __restrict__ in,
                                                    const float* __restrict__ w,
                                                    float* __restrict__ out, int Ct) {
    int p = blockIdx.x * 256 + threadIdx.x;
    int c = blockIdx.y;
    int b = blockIdx.z;
    int y = p >> 7, x = p & (Wb - 1);
    const float* ib = in + ((size_t)b * Ct + c) * Nn;
    float wl[9];
    #pragma unroll
    for (int k = 0; k < 9; ++k) wl[k] = w[c * 9 + k];
    float acc = 0.f;
    #pragma unroll
    for (int dy = 0; dy < 3; ++dy) {
        int yy = y + dy - 1;
        if (yy < 0 || yy >= Hh) continue;
        #pragma unroll
        for (int dx = 0; dx < 3; ++dx) {
            int xx = x + dx - 1;
            if (xx < 0 || xx >= Wb) continue;
            acc += wl[dy * 3 + dx] * ib[yy * Wb + xx];
        }
    }
    out[((size_t)b * Ct + c) * Nn + p] = acc;
}

// ---------------------------------------------------------------------------
// L2 normalize along N for each (b,c). In-place. grid: (Cc, 1, Bt), block 256.
// ---------------------------------------------------------------------------
__global__ __launch_bounds__(256) void l2norm_kernel(float* __restrict__ data) {
    int b = blockIdx.z, c = blockIdx.x;
    float* ptr = data + ((size_t)b * Cc + c) * Nn;
    int t = threadIdx.x;
    float s = 0.f;
    for (int i = t; i < Nn; i += 256) { float v = ptr[i]; s += v * v; }
    __shared__ float red[256];
    red[t] = s; __syncthreads();
    for (int st = 128; st > 0; st >>= 1) { if (t < st) red[t] += red[t + st]; __syncthreads(); }
    float scale = 1.0f / fmaxf(sqrtf(red[0]), 1e-12f);
    for (int i = t; i < Nn; i += 256) ptr[i] *= scale;
}

// ---------------------------------------------------------------------------
// Gate stage 2: g = sigmoid(g2.gmid + b2); per-block partial sums.
// grid: (64, 1, Bt). Writes blocksums[out_off + blockIdx.z*64 + blockIdx.x].
// ---------------------------------------------------------------------------
__global__ __launch_bounds__(256) void gate2_kernel(const float* __restrict__ gmid,
                                                    const float* __restrict__ w2,
                                                    const float* __restrict__ b2,
                                                    float* __restrict__ blocksums,
                                                    int out_off) {
    int p = blockIdx.x * 256 + threadIdx.x;
    int b = blockIdx.z;
    float acc = b2[0];
    const float* ib = gmid + (size_t)b * 64 * Nn + p;
    #pragma unroll 8
    for (int ci = 0; ci < 64; ++ci) acc += ib[(size_t)ci * Nn] * w2[ci];
    float g = 1.0f / (1.0f + expf(-acc));
    __shared__ float red[256];
    int t = threadIdx.x;
    red[t] = g; __syncthreads();
    for (int st = 128; st > 0; st >>= 1) { if (t < st) red[t] += red[t + st]; __syncthreads(); }
    if (t == 0) blocksums[out_off + b * 64 + blockIdx.x] = red[0];
}

// dk = clamp(trunc(16 * mean(g)), 1, 16). Deterministic double tree reduce.
__global__ __launch_bounds__(256) void gate_final_kernel(const float* __restrict__ blocksums,
                                                         int* __restrict__ dk_out) {
    __shared__ double sred[256];
    int t = threadIdx.x;
    sred[t] = (double)blocksums[t];
    __syncthreads();
    for (int st = 128; st > 0; st >>= 1) { if (t < st) sred[t] += sred[t + st]; __syncthreads(); }
    if (t == 0) {
        double mean = sred[0] / (double)(Bn * Nn);
        float val = 16.0f * (float)mean;
        int dk = (int)val;           // trunc like astype(int32)
        if (dk < 1) dk = 1;
        if (dk > 16) dk = 16;
        *dk_out = dk;
    }
}

// ---------------------------------------------------------------------------
// attn[b,h,c,d] = temp[h] * sum_n q[b,hc+c,n] * k[b,hc+d,n]
// grid: (HEADS, 1, Bt), block 256 = 16x16 (c,d); LDS-tiled over n.
// q,k are separate 128-ch buffers. attnp pre-offset for per-batch mode.
// ---------------------------------------------------------------------------
__global__ __launch_bounds__(256) void attn_qk_kernel(const float* __restrict__ q,
                                                      const float* __restrict__ k,
                                                      const float* __restrict__ temp,
                                                      float* __restrict__ attnp) {
    int h = blockIdx.x, b = blockIdx.z;
    int t = threadIdx.x;
    int c = t >> 4, d = t & 15;
    __shared__ float qs[16][65];
    __shared__ float ks[16][65];
    const float* qb = q + ((size_t)b * Cc + h * CHh) * Nn;
    const float* kb = k + ((size_t)b * Cc + h * CHh) * Nn;
    float acc = 0.f;
    for (int n0 = 0; n0 < Nn; n0 += 64) {
        for (int idx = t; idx < 1024; idx += 256) {
            int r = idx >> 6, col = idx & 63;
            qs[r][col] = qb[(size_t)r * Nn + n0 + col];
            ks[r][col] = kb[(size_t)r * Nn + n0 + col];
        }
        __syncthreads();
        #pragma unroll
        for (int j = 0; j < 64; ++j) acc += qs[c][j] * ks[d][j];
        __syncthreads();
    }
    attnp[(((size_t)b * HEADS + h) * CHh + c) * CHh + d] = acc * temp[h];
}

// ---------------------------------------------------------------------------
// Dynamic top-k mask + softmax on 16-wide rows. grid: (nmat), block 16.
// rank_i = #{a_j > a_i} + #{j<i : a_j == a_i}  (stable argsort rank)
// ---------------------------------------------------------------------------
__global__ void topk_softmax_kernel(float* __restrict__ attnp, const int* __restrict__ dkp) {
    int bh = blockIdx.x;
    int c = threadIdx.x;
    if (c >= 16) return;
    float* row = attnp + ((size_t)bh * CHh + c) * CHh;
    float a[16];
    #pragma unroll
    for (int d = 0; d < 16; ++d) a[d] = row[d];
    int dk = *dkp;
    unsigned keep = 0;
    float m = -INFINITY;
    #pragma unroll
    for (int d = 0; d < 16; ++d) {
        int rank = 0;
        #pragma unroll
        for (int j = 0; j < 16; ++j)
            rank += (a[j] > a[d]) || (a[j] == a[d] && j < d);
        if (rank < dk) { keep |= (1u << d); m = fmaxf(m, a[d]); }
    }
    float e[16]; float s = 0.f;
    #pragma unroll
    for (int d = 0; d < 16; ++d) {
        e[d] = (keep >> d & 1u) ? expf(a[d] - m) : 0.f;
        s += e[d];
    }
    float invs = 1.0f / s;
    #pragma unroll
    for (int d = 0; d < 16; ++d) row[d] = e[d] * invs;
}

// ---------------------------------------------------------------------------
// out[b, h*16+cr, p] = sum_d attn[b,h,cr,d] * v[b, h*16+d, p]
// grid: (Nn/256, Cc, Bt). v is its own 128-ch buffer.
// ---------------------------------------------------------------------------
__global__ __launch_bounds__(256) void attn_v_kernel(const float* __restrict__ attnp,
                                                     const float* __restrict__ v,
                                                     float* __restrict__ out) {
    int p = blockIdx.x * 256 + threadIdx.x;
    int cg = blockIdx.y;
    int b = blockIdx.z;
    int h = cg >> 4, cr = cg & 15;
    const float* arow = attnp + (((size_t)b * HEADS + h) * CHh + cr) * CHh;
    const float* vb = v + ((size_t)b * Cc + h * CHh) * Nn + p;
    float acc = 0.f;
    #pragma unroll
    for (int d = 0; d < 16; ++d) acc += arow[d] * vb[(size_t)d * Nn];
    out[((size_t)b * Cc + cg) * Nn + p] = acc;
}

// ---------------------------------------------------------------------------
// Fused IEL tail for one batch and a channel chunk [c0, c0+chunkC):
//   u1 = dw3x3(t1,wA); u2 = dw3x3(t2,wB)  (pad=1, zero outside image)
//   prod[c] = (tanh(dw3x3(u1,w1)) + u1) * (tanh(dw3x3(u2,w2)) + u2)
// t1,t2: chunkC channels each (pre-offset). Weights pre-offset to chunk.
// grid: (64, chunkC, 1), block 256 (16x16 tile, halo 2).
// ---------------------------------------------------------------------------
__global__ __launch_bounds__(256) void iel_tail_kernel(const float* __restrict__ t1p,
                                                       const float* __restrict__ t2p,
                                                       const float* __restrict__ dwA,
                                                       const float* __restrict__ dwB,
                                                       const float* __restrict__ dw1p,
                                                       const float* __restrict__ dw2p,
                                                       float* __restrict__ prod) {
    const int c = blockIdx.y;
    const int tilesx = Wb / 16;
    const int ty0 = (blockIdx.x / tilesx) * 16;
    const int tx0 = (blockIdx.x % tilesx) * 16;
    const int tid = threadIdx.x;

    __shared__ float ts[2][20][21];
    __shared__ float us[2][18][19];

    const float* t1 = t1p + (size_t)c * Nn;
    const float* t2 = t2p + (size_t)c * Nn;

    for (int idx = tid; idx < 400; idx += 256) {
        int i = idx / 20, j = idx % 20;
        int gy = ty0 - 2 + i, gx = tx0 - 2 + j;
        bool ok = (gy >= 0 && gy < Hh && gx >= 0 && gx < Wb);
        ts[0][i][j] = ok ? t1[gy * Wb + gx] : 0.f;
        ts[1][i][j] = ok ? t2[gy * Wb + gx] : 0.f;
    }
    __syncthreads();

    float wA[9], wB[9], w1[9], w2[9];
    #pragma unroll
    for (int k = 0; k < 9; ++k) {
        wA[k] = dwA[c * 9 + k];
        wB[k] = dwB[c * 9 + k];
        w1[k] = dw1p[c * 9 + k];
        w2[k] = dw2p[c * 9 + k];
    }

    for (int idx = tid; idx < 324; idx += 256) {
        int i = idx / 18, j = idx % 18;
        int gy = ty0 - 1 + i, gx = tx0 - 1 + j;
        float a0 = 0.f, a1 = 0.f;
        if (gy >= 0 && gy < Hh && gx >= 0 && gx < Wb) {
            #pragma unroll
            for (int dy = 0; dy < 3; ++dy)
                #pragma unroll
                for (int dx = 0; dx < 3; ++dx) {
                    a0 += wA[dy * 3 + dx] * ts[0][i + dy][j + dx];
                    a1 += wB[dy * 3 + dx] * ts[1][i + dy][j + dx];
                }
        }
        us[0][i][j] = a0;
        us[1][i][j] = a1;
    }
    __syncthreads();

    int ty = tid >> 4, tx = tid & 15;
    float c1 = us[0][ty + 1][tx + 1];
    float c2 = us[1][ty + 1][tx + 1];
    float s1 = 0.f, s2 = 0.f;
    #pragma unroll
    for (int dy = 0; dy < 3; ++dy)
        #pragma unroll
        for (int dx = 0; dx < 3; ++dx) {
            s1 += w1[dy * 3 + dx] * us[0][ty + dy][tx + dx];
            s2 += w2[dy * 3 + dx] * us[1][ty + dy][tx + dx];
        }
    float x1t = tanhf(s1) + c1;
    float x2t = tanhf(s2) + c2;
    prod[(size_t)c * Nn + (ty0 + ty) * Wb + (tx0 + tx)] = x1t * x2t;
}

// ---------------------------------------------------------------------------
// Host launcher — adaptive to ws_size (constant across calls => capture-safe)
// ---------------------------------------------------------------------------
extern "C" void kernel_launch(void* const* d_in, const int* in_sizes, int n_in,
                              void* d_out, int out_size, void* d_ws, size_t ws_size,
                              hipStream_t stream) {
    const float* x      = (const float*)d_in[0];
    const float* y      = (const float*)d_in[1];
    const float* ln_w   = (const float*)d_in[2];
    const float* ln_b   = (const float*)d_in[3];
    const float* temp   = (const float*)d_in[4];
    const float* q_w    = (const float*)d_in[5];
    const float* qdw_w  = (const float*)d_in[6];
    const float* kv_w   = (const float*)d_in[7];
    const float* kvdw_w = (const float*)d_in[8];
    const float* po_w   = (const float*)d_in[9];
    const float* g1_w   = (const float*)d_in[10];
    const float* g1_b   = (const float*)d_in[11];
    const float* g2_w   = (const float*)d_in[12];
    const float* g2_b   = (const float*)d_in[13];
    const float* pin_w  = (const float*)d_in[14];
    const float* dw_w   = (const float*)d_in[15];
    const float* dw1_w  = (const float*)d_in[16];
    const float* dw2_w  = (const float*)d_in[17];
    const float* pout_w = (const float*)d_in[18];
    float* out = (float*)d_out;

    // smalls at ws+0, pool at ws+64KiB
    char* ws = (char*)d_ws;
    float* attn      = (float*)ws;           // 8192 floats (B*HEADS*16*16)
    float* blocksums = attn + 8192;          // 256 floats
    int*   dk        = (int*)(blocksums + 256);
    float* pool      = (float*)(ws + 65536);

    const size_t CN  = (size_t)Cc * Nn;            // 2,097,152 floats (8 MiB)
    const size_t SLOT1 = (size_t)Bn * CN;          // 32 MiB slot (floats)
    const size_t TIER1_NEED = 65536 + 6 * SLOT1 * 4;

    dim3 blk(256);

    if (ws_size >= TIER1_NEED) {
        // ================= Tier 1: full-batch phase A (6 x 32MiB slots) =====
        float* S0 = pool;             // xn
        float* S1 = pool + 1 * SLOT1; // yn -> gmid
        float* S2 = pool + 2 * SLOT1; // scratch (q1/k1/v1) -> attn_out
        float* S3 = pool + 3 * SLOT1; // q2
        float* S4 = pool + 4 * SLOT1; // k2
        float* S5 = pool + 5 * SLOT1; // v2

        ln_kernel<<<dim3(Nn / 256, 1, Bn), blk, 0, stream>>>(x, ln_w, ln_b, S0);
        ln_kernel<<<dim3(Nn / 256, 1, Bn), blk, 0, stream>>>(y, ln_w, ln_b, S1);

        conv1x1_kernel<16><<<dim3(Nn / 256, 8, Bn), blk, 0, stream>>>(
            S0, q_w, Cc, nullptr, nullptr, S2, Cc, Cc, 0);
        dw3x3_kernel<<<dim3(Nn / 256, Cc, Bn), blk, 0, stream>>>(S2, qdw_w, S3, Cc);

        conv1x1_kernel<16><<<dim3(Nn / 256, 8, Bn), blk, 0, stream>>>(
            S1, kv_w, Cc, nullptr, nullptr, S2, Cc, Cc, 0);
        dw3x3_kernel<<<dim3(Nn / 256, Cc, Bn), blk, 0, stream>>>(S2, kvdw_w, S4, Cc);

        conv1x1_kernel<16><<<dim3(Nn / 256, 8, Bn), blk, 0, stream>>>(
            S1, kv_w + 128 * 128, Cc, nullptr, nullptr, S2, Cc, Cc, 0);
        dw3x3_kernel<<<dim3(Nn / 256, Cc, Bn), blk, 0, stream>>>(S2, kvdw_w + 128 * 9, S5, Cc);

        // gate (gmid overwrites yn in S1 — yn is dead)
        conv1x1_kernel<16><<<dim3(Nn / 256, 4, Bn), blk, 0, stream>>>(
            S0, g1_w, Cc, g1_b, nullptr, S1, Cc, 64, 1);
        gate2_kernel<<<dim3(Nn / 256, 1, Bn), blk, 0, stream>>>(S1, g2_w, g2_b, blocksums, 0);
        gate_final_kernel<<<dim3(1), blk, 0, stream>>>(blocksums, dk);

        l2norm_kernel<<<dim3(Cc, 1, Bn), blk, 0, stream>>>(S3);
        l2norm_kernel<<<dim3(Cc, 1, Bn), blk, 0, stream>>>(S4);

        attn_qk_kernel<<<dim3(HEADS, 1, Bn), blk, 0, stream>>>(S3, S4, temp, attn);
        topk_softmax_kernel<<<dim3(Bn * HEADS), dim3(16), 0, stream>>>(attn, dk);
        attn_v_kernel<<<dim3(Nn / 256, Cc, Bn), blk, 0, stream>>>(attn, S5, S2);

        conv1x1_kernel<16><<<dim3(Nn / 256, 8, Bn), blk, 0, stream>>>(
            S2, po_w, Cc, nullptr, x, out, Cc, Cc, 0);

        // ---- Phase B: IEL, per-batch inside the same slots ----
        for (int b = 0; b < Bn; ++b) {
            float* outb = out + (size_t)b * CN;
            float* zn = S0, *T1 = S1, *T2 = S2, *prod = S3;  // each <= 32 MiB
            ln_kernel<<<dim3(Nn / 256, 1, 1), blk, 0, stream>>>(outb, ln_w, ln_b, zn);
            conv1x1_kernel<16><<<dim3(Nn / 256, 22, 1), blk, 0, stream>>>(
                zn, pin_w, Cc, nullptr, nullptr, T1, Cc, HID, 0);
            conv1x1_kernel<16><<<dim3(Nn / 256, 22, 1), blk, 0, stream>>>(
                zn, pin_w + (size_t)HID * Cc, Cc, nullptr, nullptr, T2, Cc, HID, 0);
            iel_tail_kernel<<<dim3(64, HID, 1), blk, 0, stream>>>(
                T1, T2, dw_w, dw_w + HID * 9, dw1_w, dw2_w, prod);
            conv1x1_kernel<16><<<dim3(Nn / 256, 8, 1), blk, 0, stream>>>(
                prod, pout_w, HID, nullptr, outb, outb, HID, Cc, 0);
        }
    } else {
        // ================= Tier 2: per-batch everything (~48 MiB pool) ======
        float* s0 = pool;
        float* s1 = pool + 1 * CN;
        float* s2 = pool + 2 * CN;
        float* s3 = pool + 3 * CN;
        float* s4 = pool + 4 * CN;
        float* s5 = pool + 5 * CN;

        // gate pass (needs full-batch mean before any topk)
        for (int b = 0; b < Bn; ++b) {
            const float* xb = x + (size_t)b * CN;
            ln_kernel<<<dim3(Nn / 256, 1, 1), blk, 0, stream>>>(xb, ln_w, ln_b, s0);
            conv1x1_kernel<16><<<dim3(Nn / 256, 4, 1), blk, 0, stream>>>(
                s0, g1_w, Cc, g1_b, nullptr, s1, Cc, 64, 1);
            gate2_kernel<<<dim3(Nn / 256, 1, 1), blk, 0, stream>>>(
                s1, g2_w, g2_b, blocksums, b * 64);
        }
        gate_final_kernel<<<dim3(1), blk, 0, stream>>>(blocksums, dk);

        // attention pass
        for (int b = 0; b < Bn; ++b) {
            const float* xb = x + (size_t)b * CN;
            const float* yb = y + (size_t)b * CN;
            float* outb = out + (size_t)b * CN;
            float* attnb = attn + (size_t)b * HEADS * CHh * CHh;

            ln_kernel<<<dim3(Nn / 256, 1, 1), blk, 0, stream>>>(xb, ln_w, ln_b, s0);
            ln_kernel<<<dim3(Nn / 256, 1, 1), blk, 0, stream>>>(yb, ln_w, ln_b, s1);

            conv1x1_kernel<16><<<dim3(Nn / 256, 8, 1), blk, 0, stream>>>(
                s0, q_w, Cc, nullptr, nullptr, s2, Cc, Cc, 0);
            dw3x3_kernel<<<dim3(Nn / 256, Cc, 1), blk, 0, stream>>>(s2, qdw_w, s3, Cc);
            l2norm_kernel<<<dim3(Cc, 1, 1), blk, 0, stream>>>(s3);

            conv1x1_kernel<16><<<dim3(Nn / 256, 8, 1), blk, 0, stream>>>(
                s1, kv_w, Cc, nullptr, nullptr, s2, Cc, Cc, 0);
            dw3x3_kernel<<<dim3(Nn / 256, Cc, 1), blk, 0, stream>>>(s2, kvdw_w, s4, Cc);
            l2norm_kernel<<<dim3(Cc, 1, 1), blk, 0, stream>>>(s4);

            conv1x1_kernel<16><<<dim3(Nn / 256, 8, 1), blk, 0, stream>>>(
                s1, kv_w + 128 * 128, Cc, nullptr, nullptr, s2, Cc, Cc, 0);
            dw3x3_kernel<<<dim3(Nn / 256, Cc, 1), blk, 0, stream>>>(s2, kvdw_w + 128 * 9, s5, Cc);

            attn_qk_kernel<<<dim3(HEADS, 1, 1), blk, 0, stream>>>(s3, s4, temp, attnb);
            topk_softmax_kernel<<<dim3(HEADS), dim3(16), 0, stream>>>(attnb, dk);
            attn_v_kernel<<<dim3(Nn / 256, Cc, 1), blk, 0, stream>>>(attnb, s5, s2);

            conv1x1_kernel<16><<<dim3(Nn / 256, 8, 1), blk, 0, stream>>>(
                s2, po_w, Cc, nullptr, xb, outb, Cc, Cc, 0);
        }

        // IEL pass, 2 channel chunks of 170
        const int CHUNK = 170;
        const size_t TCH = (size_t)CHUNK * Nn;
        float* zn   = pool;            // 8 MiB
        float* T1   = pool + CN;
        float* T2   = T1 + TCH;
        float* prod = T2 + TCH;
        for (int b = 0; b < Bn; ++b) {
            float* outb = out + (size_t)b * CN;
            ln_kernel<<<dim3(Nn / 256, 1, 1), blk, 0, stream>>>(outb, ln_w, ln_b, zn);
            for (int c0 = 0; c0 < HID; c0 += CHUNK) {
                conv1x1_kernel<16><<<dim3(Nn / 256, 11, 1), blk, 0, stream>>>(
                    zn, pin_w + (size_t)c0 * Cc, Cc, nullptr, nullptr, T1, Cc, CHUNK, 0);
                conv1x1_kernel<16><<<dim3(Nn / 256, 11, 1), blk, 0, stream>>>(
                    zn, pin_w + (size_t)(HID + c0) * Cc, Cc, nullptr, nullptr, T2, Cc, CHUNK, 0);
                iel_tail_kernel<<<dim3(64, CHUNK, 1), blk, 0, stream>>>(
                    T1, T2, dw_w + c0 * 9, dw_w + (HID + c0) * 9,
                    dw1_w + c0 * 9, dw2_w + c0 * 9, prod);
                conv1x1_kernel<16><<<dim3(Nn / 256, 8, 1), blk, 0, stream>>>(
                    prod, pout_w + c0, HID, nullptr, outb, outb, CHUNK, Cc, 0);
            }
        }
    }
}

// Round 3
// 2674.779 us; speedup vs baseline: 1.1487x; 1.1487x over previous
//
#include <hip/hip_runtime.h>
#include <math.h>

// Problem constants
static constexpr int Bn    = 4;
static constexpr int Cc    = 128;
static constexpr int Hh    = 128;
static constexpr int Wb    = 128;
static constexpr int Nn    = Hh * Wb;      // 16384
static constexpr int HEADS = 8;
static constexpr int CHh   = 16;           // Cc / HEADS
static constexpr int HID   = 340;
static constexpr int HID2  = 680;
static constexpr int NS    = 64;           // n-splits for attn QK^T

// ---------------------------------------------------------------------------
// LayerNorm over channel axis (axis=1), per pixel.
// grid: (Nn/256, 1, Bt). b = blockIdx.z.
// ---------------------------------------------------------------------------
__global__ __launch_bounds__(256) void ln_kernel(const float* __restrict__ in,
                                                 const float* __restrict__ w,
                                                 const float* __restrict__ bias,
                                                 float* __restrict__ out) {
    int p = blockIdx.x * 256 + threadIdx.x;
    int b = blockIdx.z;
    const float* ib = in + (size_t)b * Cc * Nn + p;
    float s = 0.f, s2 = 0.f;
    #pragma unroll 8
    for (int c = 0; c < Cc; ++c) {
        float v = ib[(size_t)c * Nn];
        s += v; s2 += v * v;
    }
    float mean = s * (1.0f / Cc);
    float var  = s2 * (1.0f / Cc) - mean * mean;
    float inv  = 1.0f / sqrtf(var + 1e-6f);
    float* ob = out + (size_t)b * Cc * Nn + p;
    #pragma unroll 8
    for (int c = 0; c < Cc; ++c) {
        float v = ib[(size_t)c * Nn];
        ob[(size_t)c * Nn] = w[c] * ((v - mean) * inv) + bias[c];
    }
}

// ---------------------------------------------------------------------------
// 1x1 conv (GEMM): out[b,co,p] = sum_ci W[co*wstride+ci] * in[b,ci,p]
// grid: (Nn/256, ceil(Cout/TCO), Bt). wgt may be pre-offset (chunking).
// ---------------------------------------------------------------------------
template <int TCO>
__global__ __launch_bounds__(256) void conv1x1_kernel(const float* __restrict__ in,
                                                      const float* __restrict__ wgt,
                                                      int wstride,
                                                      const float* __restrict__ bias,
                                                      const float* __restrict__ res,
                                                      float* __restrict__ out,
                                                      int Cin, int Cout, int act) {
    int p   = blockIdx.x * 256 + threadIdx.x;
    int b   = blockIdx.z;
    int co0 = blockIdx.y * TCO;
    float acc[TCO];
    #pragma unroll
    for (int i = 0; i < TCO; ++i) acc[i] = 0.f;

    const float* ib = in + (size_t)b * Cin * Nn + p;
    for (int ci = 0; ci < Cin; ++ci) {
        float v = ib[(size_t)ci * Nn];
        #pragma unroll
        for (int i = 0; i < TCO; ++i) {
            int co = co0 + i; if (co > Cout - 1) co = Cout - 1;   // uniform clamp
            acc[i] += v * wgt[(size_t)co * wstride + ci];
        }
    }
    #pragma unroll
    for (int i = 0; i < TCO; ++i) {
        int co = co0 + i;
        if (co < Cout) {
            float r = acc[i];
            if (bias) r += bias[co];
            if (act == 1) r = fmaxf(r, 0.f);
            size_t o = ((size_t)b * Cout + co) * Nn + p;
            if (res) r += res[o];
            out[o] = r;
        }
    }
}

// ---------------------------------------------------------------------------
// Depthwise 3x3 conv, pad=1. grid: (Nn/256, Ct, Bt). w pre-offset to channel 0.
// ---------------------------------------------------------------------------
__global__ __launch_bounds__(256) void dw3x3_kernel(const float* __restrict__ in,
                                                    const float* __restrict__ w,
                                                    float* __restrict__ out, int Ct) {
    int p = blockIdx.x * 256 + threadIdx.x;
    int c = blockIdx.y;
    int b = blockIdx.z;
    int y = p >> 7, x = p & (Wb - 1);
    const float* ib = in + ((size_t)b * Ct + c) * Nn;
    float wl[9];
    #pragma unroll
    for (int k = 0; k < 9; ++k) wl[k] = w[c * 9 + k];
    float acc = 0.f;
    #pragma unroll
    for (int dy = 0; dy < 3; ++dy) {
        int yy = y + dy - 1;
        if (yy < 0 || yy >= Hh) continue;
        #pragma unroll
        for (int dx = 0; dx < 3; ++dx) {
            int xx = x + dx - 1;
            if (xx < 0 || xx >= Wb) continue;
            acc += wl[dy * 3 + dx] * ib[yy * Wb + xx];
        }
    }
    out[((size_t)b * Ct + c) * Nn + p] = acc;
}

// ---------------------------------------------------------------------------
// L2 normalize along N for each (b,c). In-place. grid: (Cc, 1, Bt), block 256.
// ---------------------------------------------------------------------------
__global__ __launch_bounds__(256) void l2norm_kernel(float* __restrict__ data) {
    int b = blockIdx.z, c = blockIdx.x;
    float* ptr = data + ((size_t)b * Cc + c) * Nn;
    int t = threadIdx.x;
    float s = 0.f;
    for (int i = t; i < Nn; i += 256) { float v = ptr[i]; s += v * v; }
    __shared__ float red[256];
    red[t] = s; __syncthreads();
    for (int st = 128; st > 0; st >>= 1) { if (t < st) red[t] += red[t + st]; __syncthreads(); }
    float scale = 1.0f / fmaxf(sqrtf(red[0]), 1e-12f);
    for (int i = t; i < Nn; i += 256) ptr[i] *= scale;
}

// ---------------------------------------------------------------------------
// Gate stage 2: g = sigmoid(g2.gmid + b2); per-block partial sums.
// grid: (64, 1, Bt). Writes blocksums[out_off + blockIdx.z*64 + blockIdx.x].
// ---------------------------------------------------------------------------
__global__ __launch_bounds__(256) void gate2_kernel(const float* __restrict__ gmid,
                                                    const float* __restrict__ w2,
                                                    const float* __restrict__ b2,
                                                    float* __restrict__ blocksums,
                                                    int out_off) {
    int p = blockIdx.x * 256 + threadIdx.x;
    int b = blockIdx.z;
    float acc = b2[0];
    const float* ib = gmid + (size_t)b * 64 * Nn + p;
    #pragma unroll 8
    for (int ci = 0; ci < 64; ++ci) acc += ib[(size_t)ci * Nn] * w2[ci];
    float g = 1.0f / (1.0f + expf(-acc));
    __shared__ float red[256];
    int t = threadIdx.x;
    red[t] = g; __syncthreads();
    for (int st = 128; st > 0; st >>= 1) { if (t < st) red[t] += red[t + st]; __syncthreads(); }
    if (t == 0) blocksums[out_off + b * 64 + blockIdx.x] = red[0];
}

// dk = clamp(trunc(16 * mean(g)), 1, 16). Deterministic double tree reduce.
__global__ __launch_bounds__(256) void gate_final_kernel(const float* __restrict__ blocksums,
                                                         int* __restrict__ dk_out) {
    __shared__ double sred[256];
    int t = threadIdx.x;
    sred[t] = (double)blocksums[t];
    __syncthreads();
    for (int st = 128; st > 0; st >>= 1) { if (t < st) sred[t] += sred[t + st]; __syncthreads(); }
    if (t == 0) {
        double mean = sred[0] / (double)(Bn * Nn);
        float val = 16.0f * (float)mean;
        int dk = (int)val;           // trunc like astype(int32)
        if (dk < 1) dk = 1;
        if (dk > 16) dk = 16;
        *dk_out = dk;
    }
}

// ---------------------------------------------------------------------------
// QK^T partial: partial[(b*HEADS+h)*NS+ns][c][d] =
//   sum_{n in chunk ns} q[b,hc+c,n] * k[b,hc+d,n]
// grid: (NS, HEADS, Bt), block 256 = 16x16 (c,d). Chunk = Nn/NS = 256 cols.
// ---------------------------------------------------------------------------
__global__ __launch_bounds__(256) void attn_qk_partial_kernel(const float* __restrict__ q,
                                                              const float* __restrict__ k,
                                                              float* __restrict__ partial) {
    int ns = blockIdx.x, h = blockIdx.y, b = blockIdx.z;
    int t = threadIdx.x;
    int c = t >> 4, d = t & 15;
    __shared__ float qs[16][65];
    __shared__ float ks[16][65];
    const float* qb = q + ((size_t)b * Cc + h * CHh) * Nn;
    const float* kb = k + ((size_t)b * Cc + h * CHh) * Nn;
    float acc = 0.f;
    int nbeg = ns * (Nn / NS);
    for (int n0 = nbeg; n0 < nbeg + (Nn / NS); n0 += 64) {
        for (int idx = t; idx < 1024; idx += 256) {
            int r = idx >> 6, col = idx & 63;
            qs[r][col] = qb[(size_t)r * Nn + n0 + col];
            ks[r][col] = kb[(size_t)r * Nn + n0 + col];
        }
        __syncthreads();
        #pragma unroll
        for (int j = 0; j < 64; ++j) acc += qs[c][j] * ks[d][j];
        __syncthreads();
    }
    partial[(((size_t)(b * HEADS + h)) * NS + ns) * 256 + t] = acc;
}

// Deterministic reduce over ns (fixed order) + temperature scale.
// grid: (nmat), block 256. h = blockIdx.x % HEADS. attnp/partial pre-offset ok.
__global__ __launch_bounds__(256) void attn_reduce_kernel(const float* __restrict__ partial,
                                                          const float* __restrict__ temp,
                                                          float* __restrict__ attnp) {
    int bh = blockIdx.x;
    int h = bh % HEADS;
    int t = threadIdx.x;
    const float* pp = partial + (size_t)bh * NS * 256 + t;
    float s = 0.f;
    #pragma unroll 8
    for (int ns = 0; ns < NS; ++ns) s += pp[(size_t)ns * 256];
    attnp[(size_t)bh * 256 + t] = s * temp[h];
}

// ---------------------------------------------------------------------------
// Dynamic top-k mask + softmax on 16-wide rows. grid: (nmat), block 16.
// rank_i = #{a_j > a_i} + #{j<i : a_j == a_i}  (stable argsort rank)
// ---------------------------------------------------------------------------
__global__ void topk_softmax_kernel(float* __restrict__ attnp, const int* __restrict__ dkp) {
    int bh = blockIdx.x;
    int c = threadIdx.x;
    if (c >= 16) return;
    float* row = attnp + ((size_t)bh * CHh + c) * CHh;
    float a[16];
    #pragma unroll
    for (int d = 0; d < 16; ++d) a[d] = row[d];
    int dk = *dkp;
    unsigned keep = 0;
    float m = -INFINITY;
    #pragma unroll
    for (int d = 0; d < 16; ++d) {
        int rank = 0;
        #pragma unroll
        for (int j = 0; j < 16; ++j)
            rank += (a[j] > a[d]) || (a[j] == a[d] && j < d);
        if (rank < dk) { keep |= (1u << d); m = fmaxf(m, a[d]); }
    }
    float e[16]; float s = 0.f;
    #pragma unroll
    for (int d = 0; d < 16; ++d) {
        e[d] = (keep >> d & 1u) ? expf(a[d] - m) : 0.f;
        s += e[d];
    }
    float invs = 1.0f / s;
    #pragma unroll
    for (int d = 0; d < 16; ++d) row[d] = e[d] * invs;
}

// ---------------------------------------------------------------------------
// out[b, h*16+cr, p] = sum_d attn[b,h,cr,d] * v[b, h*16+d, p]
// grid: (Nn/256, Cc, Bt). v is its own 128-ch buffer.
// ---------------------------------------------------------------------------
__global__ __launch_bounds__(256) void attn_v_kernel(const float* __restrict__ attnp,
                                                     const float* __restrict__ v,
                                                     float* __restrict__ out) {
    int p = blockIdx.x * 256 + threadIdx.x;
    int cg = blockIdx.y;
    int b = blockIdx.z;
    int h = cg >> 4, cr = cg & 15;
    const float* arow = attnp + (((size_t)b * HEADS + h) * CHh + cr) * CHh;
    const float* vb = v + ((size_t)b * Cc + h * CHh) * Nn + p;
    float acc = 0.f;
    #pragma unroll
    for (int d = 0; d < 16; ++d) acc += arow[d] * vb[(size_t)d * Nn];
    out[((size_t)b * Cc + cg) * Nn + p] = acc;
}

// ---------------------------------------------------------------------------
// Fused IEL tail for one batch and a channel chunk [c0, c0+chunkC):
//   u1 = dw3x3(t1,wA); u2 = dw3x3(t2,wB)  (pad=1, zero outside image)
//   prod[c] = (tanh(dw3x3(u1,w1)) + u1) * (tanh(dw3x3(u2,w2)) + u2)
// grid: (64, chunkC, 1), block 256 (16x16 tile, halo 2).
// ---------------------------------------------------------------------------
__global__ __launch_bounds__(256) void iel_tail_kernel(const float* __restrict__ t1p,
                                                       const float* __restrict__ t2p,
                                                       const float* __restrict__ dwA,
                                                       const float* __restrict__ dwB,
                                                       const float* __restrict__ dw1p,
                                                       const float* __restrict__ dw2p,
                                                       float* __restrict__ prod) {
    const int c = blockIdx.y;
    const int tilesx = Wb / 16;
    const int ty0 = (blockIdx.x / tilesx) * 16;
    const int tx0 = (blockIdx.x % tilesx) * 16;
    const int tid = threadIdx.x;

    __shared__ float ts[2][20][21];
    __shared__ float us[2][18][19];

    const float* t1 = t1p + (size_t)c * Nn;
    const float* t2 = t2p + (size_t)c * Nn;

    for (int idx = tid; idx < 400; idx += 256) {
        int i = idx / 20, j = idx % 20;
        int gy = ty0 - 2 + i, gx = tx0 - 2 + j;
        bool ok = (gy >= 0 && gy < Hh && gx >= 0 && gx < Wb);
        ts[0][i][j] = ok ? t1[gy * Wb + gx] : 0.f;
        ts[1][i][j] = ok ? t2[gy * Wb + gx] : 0.f;
    }
    __syncthreads();

    float wA[9], wB[9], w1[9], w2[9];
    #pragma unroll
    for (int k = 0; k < 9; ++k) {
        wA[k] = dwA[c * 9 + k];
        wB[k] = dwB[c * 9 + k];
        w1[k] = dw1p[c * 9 + k];
        w2[k] = dw2p[c * 9 + k];
    }

    for (int idx = tid; idx < 324; idx += 256) {
        int i = idx / 18, j = idx % 18;
        int gy = ty0 - 1 + i, gx = tx0 - 1 + j;
        float a0 = 0.f, a1 = 0.f;
        if (gy >= 0 && gy < Hh && gx >= 0 && gx < Wb) {
            #pragma unroll
            for (int dy = 0; dy < 3; ++dy)
                #pragma unroll
                for (int dx = 0; dx < 3; ++dx) {
                    a0 += wA[dy * 3 + dx] * ts[0][i + dy][j + dx];
                    a1 += wB[dy * 3 + dx] * ts[1][i + dy][j + dx];
                }
        }
        us[0][i][j] = a0;
        us[1][i][j] = a1;
    }
    __syncthreads();

    int ty = tid >> 4, tx = tid & 15;
    float c1 = us[0][ty + 1][tx + 1];
    float c2 = us[1][ty + 1][tx + 1];
    float s1 = 0.f, s2 = 0.f;
    #pragma unroll
    for (int dy = 0; dy < 3; ++dy)
        #pragma unroll
        for (int dx = 0; dx < 3; ++dx) {
            s1 += w1[dy * 3 + dx] * us[0][ty + dy][tx + dx];
            s2 += w2[dy * 3 + dx] * us[1][ty + dy][tx + dx];
        }
    float x1t = tanhf(s1) + c1;
    float x2t = tanhf(s2) + c2;
    prod[(size_t)c * Nn + (ty0 + ty) * Wb + (tx0 + tx)] = x1t * x2t;
}

// ---------------------------------------------------------------------------
// Host launcher — adaptive to ws_size (constant across calls => capture-safe)
// ---------------------------------------------------------------------------
extern "C" void kernel_launch(void* const* d_in, const int* in_sizes, int n_in,
                              void* d_out, int out_size, void* d_ws, size_t ws_size,
                              hipStream_t stream) {
    const float* x      = (const float*)d_in[0];
    const float* y      = (const float*)d_in[1];
    const float* ln_w   = (const float*)d_in[2];
    const float* ln_b   = (const float*)d_in[3];
    const float* temp   = (const float*)d_in[4];
    const float* q_w    = (const float*)d_in[5];
    const float* qdw_w  = (const float*)d_in[6];
    const float* kv_w   = (const float*)d_in[7];
    const float* kvdw_w = (const float*)d_in[8];
    const float* po_w   = (const float*)d_in[9];
    const float* g1_w   = (const float*)d_in[10];
    const float* g1_b   = (const float*)d_in[11];
    const float* g2_w   = (const float*)d_in[12];
    const float* g2_b   = (const float*)d_in[13];
    const float* pin_w  = (const float*)d_in[14];
    const float* dw_w   = (const float*)d_in[15];
    const float* dw1_w  = (const float*)d_in[16];
    const float* dw2_w  = (const float*)d_in[17];
    const float* pout_w = (const float*)d_in[18];
    float* out = (float*)d_out;

    // smalls at ws+0, pool at ws+64KiB
    char* ws = (char*)d_ws;
    float* attn      = (float*)ws;           // 8192 floats (B*HEADS*16*16)
    float* blocksums = attn + 8192;          // 256 floats
    int*   dk        = (int*)(blocksums + 256);
    float* pool      = (float*)(ws + 65536);

    const size_t CN  = (size_t)Cc * Nn;            // 2,097,152 floats (8 MiB)
    const size_t SLOT1 = (size_t)Bn * CN;          // 32 MiB slot (floats)
    const size_t TIER1_NEED = 65536 + 6 * SLOT1 * 4;

    dim3 blk(256);

    if (ws_size >= TIER1_NEED) {
        // ================= Tier 1: full-batch phase A (6 x 32MiB slots) =====
        float* S0 = pool;             // xn
        float* S1 = pool + 1 * SLOT1; // yn -> gmid -> attn partial
        float* S2 = pool + 2 * SLOT1; // scratch (q1/k1/v1) -> attn_out
        float* S3 = pool + 3 * SLOT1; // q2
        float* S4 = pool + 4 * SLOT1; // k2
        float* S5 = pool + 5 * SLOT1; // v2

        ln_kernel<<<dim3(Nn / 256, 1, Bn), blk, 0, stream>>>(x, ln_w, ln_b, S0);
        ln_kernel<<<dim3(Nn / 256, 1, Bn), blk, 0, stream>>>(y, ln_w, ln_b, S1);

        conv1x1_kernel<16><<<dim3(Nn / 256, 8, Bn), blk, 0, stream>>>(
            S0, q_w, Cc, nullptr, nullptr, S2, Cc, Cc, 0);
        dw3x3_kernel<<<dim3(Nn / 256, Cc, Bn), blk, 0, stream>>>(S2, qdw_w, S3, Cc);

        conv1x1_kernel<16><<<dim3(Nn / 256, 8, Bn), blk, 0, stream>>>(
            S1, kv_w, Cc, nullptr, nullptr, S2, Cc, Cc, 0);
        dw3x3_kernel<<<dim3(Nn / 256, Cc, Bn), blk, 0, stream>>>(S2, kvdw_w, S4, Cc);

        conv1x1_kernel<16><<<dim3(Nn / 256, 8, Bn), blk, 0, stream>>>(
            S1, kv_w + 128 * 128, Cc, nullptr, nullptr, S2, Cc, Cc, 0);
        dw3x3_kernel<<<dim3(Nn / 256, Cc, Bn), blk, 0, stream>>>(S2, kvdw_w + 128 * 9, S5, Cc);

        // gate (gmid overwrites yn in S1 — yn is dead)
        conv1x1_kernel<16><<<dim3(Nn / 256, 4, Bn), blk, 0, stream>>>(
            S0, g1_w, Cc, g1_b, nullptr, S1, Cc, 64, 1);
        gate2_kernel<<<dim3(Nn / 256, 1, Bn), blk, 0, stream>>>(S1, g2_w, g2_b, blocksums, 0);
        gate_final_kernel<<<dim3(1), blk, 0, stream>>>(blocksums, dk);

        l2norm_kernel<<<dim3(Cc, 1, Bn), blk, 0, stream>>>(S3);
        l2norm_kernel<<<dim3(Cc, 1, Bn), blk, 0, stream>>>(S4);

        // attn partial reuses S1 (gmid dead after gate2): 2 MiB
        float* partial = S1;
        attn_qk_partial_kernel<<<dim3(NS, HEADS, Bn), blk, 0, stream>>>(S3, S4, partial);
        attn_reduce_kernel<<<dim3(Bn * HEADS), blk, 0, stream>>>(partial, temp, attn);
        topk_softmax_kernel<<<dim3(Bn * HEADS), dim3(16), 0, stream>>>(attn, dk);
        attn_v_kernel<<<dim3(Nn / 256, Cc, Bn), blk, 0, stream>>>(attn, S5, S2);

        conv1x1_kernel<16><<<dim3(Nn / 256, 8, Bn), blk, 0, stream>>>(
            S2, po_w, Cc, nullptr, x, out, Cc, Cc, 0);

        // ---- Phase B: IEL, per-batch inside the same slots ----
        for (int b = 0; b < Bn; ++b) {
            float* outb = out + (size_t)b * CN;
            float* zn = S0, *T1 = S1, *T2 = S2, *prod = S3;  // each <= 32 MiB
            ln_kernel<<<dim3(Nn / 256, 1, 1), blk, 0, stream>>>(outb, ln_w, ln_b, zn);
            conv1x1_kernel<16><<<dim3(Nn / 256, 22, 1), blk, 0, stream>>>(
                zn, pin_w, Cc, nullptr, nullptr, T1, Cc, HID, 0);
            conv1x1_kernel<16><<<dim3(Nn / 256, 22, 1), blk, 0, stream>>>(
                zn, pin_w + (size_t)HID * Cc, Cc, nullptr, nullptr, T2, Cc, HID, 0);
            iel_tail_kernel<<<dim3(64, HID, 1), blk, 0, stream>>>(
                T1, T2, dw_w, dw_w + HID * 9, dw1_w, dw2_w, prod);
            conv1x1_kernel<16><<<dim3(Nn / 256, 8, 1), blk, 0, stream>>>(
                prod, pout_w, HID, nullptr, outb, outb, HID, Cc, 0);
        }
    } else {
        // ================= Tier 2: per-batch everything (~48 MiB pool) ======
        float* s0 = pool;
        float* s1 = pool + 1 * CN;
        float* s2 = pool + 2 * CN;
        float* s3 = pool + 3 * CN;
        float* s4 = pool + 4 * CN;
        float* s5 = pool + 5 * CN;

        // gate pass (needs full-batch mean before any topk)
        for (int b = 0; b < Bn; ++b) {
            const float* xb = x + (size_t)b * CN;
            ln_kernel<<<dim3(Nn / 256, 1, 1), blk, 0, stream>>>(xb, ln_w, ln_b, s0);
            conv1x1_kernel<16><<<dim3(Nn / 256, 4, 1), blk, 0, stream>>>(
                s0, g1_w, Cc, g1_b, nullptr, s1, Cc, 64, 1);
            gate2_kernel<<<dim3(Nn / 256, 1, 1), blk, 0, stream>>>(
                s1, g2_w, g2_b, blocksums, b * 64);
        }
        gate_final_kernel<<<dim3(1), blk, 0, stream>>>(blocksums, dk);

        // attention pass
        for (int b = 0; b < Bn; ++b) {
            const float* xb = x + (size_t)b * CN;
            const float* yb = y + (size_t)b * CN;
            float* outb = out + (size_t)b * CN;
            float* attnb = attn + (size_t)b * HEADS * CHh * CHh;

            ln_kernel<<<dim3(Nn / 256, 1, 1), blk, 0, stream>>>(xb, ln_w, ln_b, s0);
            ln_kernel<<<dim3(Nn / 256, 1, 1), blk, 0, stream>>>(yb, ln_w, ln_b, s1);

            conv1x1_kernel<16><<<dim3(Nn / 256, 8, 1), blk, 0, stream>>>(
                s0, q_w, Cc, nullptr, nullptr, s2, Cc, Cc, 0);
            dw3x3_kernel<<<dim3(Nn / 256, Cc, 1), blk, 0, stream>>>(s2, qdw_w, s3, Cc);
            l2norm_kernel<<<dim3(Cc, 1, 1), blk, 0, stream>>>(s3);

            conv1x1_kernel<16><<<dim3(Nn / 256, 8, 1), blk, 0, stream>>>(
                s1, kv_w, Cc, nullptr, nullptr, s2, Cc, Cc, 0);
            dw3x3_kernel<<<dim3(Nn / 256, Cc, 1), blk, 0, stream>>>(s2, kvdw_w, s4, Cc);
            l2norm_kernel<<<dim3(Cc, 1, 1), blk, 0, stream>>>(s4);

            conv1x1_kernel<16><<<dim3(Nn / 256, 8, 1), blk, 0, stream>>>(
                s1, kv_w + 128 * 128, Cc, nullptr, nullptr, s2, Cc, Cc, 0);
            dw3x3_kernel<<<dim3(Nn / 256, Cc, 1), blk, 0, stream>>>(s2, kvdw_w + 128 * 9, s5, Cc);

            // partial reuses s2 (dead here; attn_v output comes later)
            attn_qk_partial_kernel<<<dim3(NS, HEADS, 1), blk, 0, stream>>>(s3, s4, s2);
            attn_reduce_kernel<<<dim3(HEADS), blk, 0, stream>>>(s2, temp, attnb);
            topk_softmax_kernel<<<dim3(HEADS), dim3(16), 0, stream>>>(attnb, dk);
            attn_v_kernel<<<dim3(Nn / 256, Cc, 1), blk, 0, stream>>>(attnb, s5, s2);

            conv1x1_kernel<16><<<dim3(Nn / 256, 8, 1), blk, 0, stream>>>(
                s2, po_w, Cc, nullptr, xb, outb, Cc, Cc, 0);
        }

        // IEL pass, 2 channel chunks of 170
        const int CHUNK = 170;
        const size_t TCH = (size_t)CHUNK * Nn;
        float* zn   = pool;            // 8 MiB
        float* T1   = pool + CN;
        float* T2   = T1 + TCH;
        float* prod = T2 + TCH;
        for (int b = 0; b < Bn; ++b) {
            float* outb = out + (size_t)b * CN;
            ln_kernel<<<dim3(Nn / 256, 1, 1), blk, 0, stream>>>(outb, ln_w, ln_b, zn);
            for (int c0 = 0; c0 < HID; c0 += CHUNK) {
                conv1x1_kernel<16><<<dim3(Nn / 256, 11, 1), blk, 0, stream>>>(
                    zn, pin_w + (size_t)c0 * Cc, Cc, nullptr, nullptr, T1, Cc, CHUNK, 0);
                conv1x1_kernel<16><<<dim3(Nn / 256, 11, 1), blk, 0, stream>>>(
                    zn, pin_w + (size_t)(HID + c0) * Cc, Cc, nullptr, nullptr, T2, Cc, CHUNK, 0);
                iel_tail_kernel<<<dim3(64, CHUNK, 1), blk, 0, stream>>>(
                    T1, T2, dw_w + c0 * 9, dw_w + (HID + c0) * 9,
                    dw1_w + c0 * 9, dw2_w + c0 * 9, prod);
                conv1x1_kernel<16><<<dim3(Nn / 256, 8, 1), blk, 0, stream>>>(
                    prod, pout_w + c0, HID, nullptr, outb, outb, CHUNK, Cc, 0);
            }
        }
    }
}

// Round 4
// 1364.582 us; speedup vs baseline: 2.2515x; 1.9601x over previous
//
#include <hip/hip_runtime.h>
#include <math.h>

// Problem constants
static constexpr int Bn    = 4;
static constexpr int Cc    = 128;
static constexpr int Hh    = 128;
static constexpr int Wb    = 128;
static constexpr int Nn    = Hh * Wb;      // 16384
static constexpr int HEADS = 8;
static constexpr int CHh   = 16;           // Cc / HEADS
static constexpr int HID   = 340;
static constexpr int HID2  = 680;
static constexpr int NS    = 64;           // n-splits for attn QK^T

// ---------------------------------------------------------------------------
// LayerNorm over channel axis (axis=1), per pixel.
// grid: (Nn/256, 1, Bt). b = blockIdx.z.
// ---------------------------------------------------------------------------
__global__ __launch_bounds__(256) void ln_kernel(const float* __restrict__ in,
                                                 const float* __restrict__ w,
                                                 const float* __restrict__ bias,
                                                 float* __restrict__ out) {
    int p = blockIdx.x * 256 + threadIdx.x;
    int b = blockIdx.z;
    const float* ib = in + (size_t)b * Cc * Nn + p;
    float s = 0.f, s2 = 0.f;
    #pragma unroll 8
    for (int c = 0; c < Cc; ++c) {
        float v = ib[(size_t)c * Nn];
        s += v; s2 += v * v;
    }
    float mean = s * (1.0f / Cc);
    float var  = s2 * (1.0f / Cc) - mean * mean;
    float inv  = 1.0f / sqrtf(var + 1e-6f);
    float* ob = out + (size_t)b * Cc * Nn + p;
    #pragma unroll 8
    for (int c = 0; c < Cc; ++c) {
        float v = ib[(size_t)c * Nn];
        ob[(size_t)c * Nn] = w[c] * ((v - mean) * inv) + bias[c];
    }
}

// ---------------------------------------------------------------------------
// Vectorized 1x1 conv (GEMM): out[b,co,p] = sum_ci W[co*wstride+ci]*in[b,ci,p]
// Each thread: 4 consecutive pixels (float4) x TCO output channels.
// Weight rows hoisted to uniform pointers (SGPR/s_load). ci-loop unrolled 4
// to keep >=4 global_load_dwordx4 in flight (latency hiding via ILP).
// grid: (Nn/1024, ceil(Cout/TCO), Bt)
// ---------------------------------------------------------------------------
template <int TCO>
__global__ __launch_bounds__(256) void conv1x1v_kernel(const float* __restrict__ in,
                                                       const float* __restrict__ wgt,
                                                       int wstride,
                                                       const float* __restrict__ bias,
                                                       const float* __restrict__ res,
                                                       float* __restrict__ out,
                                                       int Cin, int Cout, int act) {
    int pg  = blockIdx.x * 256 + threadIdx.x;   // pixel group (4 px)
    int b   = blockIdx.z;
    int co0 = blockIdx.y * TCO;

    const float* wrow[TCO];
    #pragma unroll
    for (int i = 0; i < TCO; ++i) {
        int co = co0 + i; if (co > Cout - 1) co = Cout - 1;   // uniform clamp
        wrow[i] = wgt + (size_t)co * wstride;
    }

    float4 acc[TCO];
    #pragma unroll
    for (int i = 0; i < TCO; ++i) acc[i] = make_float4(0.f, 0.f, 0.f, 0.f);

    const float* ib = in + (size_t)b * Cin * Nn + (size_t)pg * 4;
    #pragma unroll 4
    for (int ci = 0; ci < Cin; ++ci) {
        float4 v = *(const float4*)(ib + (size_t)ci * Nn);
        #pragma unroll
        for (int i = 0; i < TCO; ++i) {
            float w = wrow[i][ci];
            acc[i].x += v.x * w;
            acc[i].y += v.y * w;
            acc[i].z += v.z * w;
            acc[i].w += v.w * w;
        }
    }

    #pragma unroll
    for (int i = 0; i < TCO; ++i) {
        int co = co0 + i;
        if (co < Cout) {
            float4 r = acc[i];
            if (bias) { float bb = bias[co]; r.x += bb; r.y += bb; r.z += bb; r.w += bb; }
            if (act == 1) {
                r.x = fmaxf(r.x, 0.f); r.y = fmaxf(r.y, 0.f);
                r.z = fmaxf(r.z, 0.f); r.w = fmaxf(r.w, 0.f);
            }
            size_t o = ((size_t)b * Cout + co) * Nn + (size_t)pg * 4;
            if (res) {
                float4 rv = *(const float4*)(res + o);
                r.x += rv.x; r.y += rv.y; r.z += rv.z; r.w += rv.w;
            }
            *(float4*)(out + o) = r;
        }
    }
}

// ---------------------------------------------------------------------------
// Depthwise 3x3 conv, pad=1. grid: (Nn/256, Ct, Bt). w pre-offset to channel 0.
// ---------------------------------------------------------------------------
__global__ __launch_bounds__(256) void dw3x3_kernel(const float* __restrict__ in,
                                                    const float* __restrict__ w,
                                                    float* __restrict__ out, int Ct) {
    int p = blockIdx.x * 256 + threadIdx.x;
    int c = blockIdx.y;
    int b = blockIdx.z;
    int y = p >> 7, x = p & (Wb - 1);
    const float* ib = in + ((size_t)b * Ct + c) * Nn;
    float wl[9];
    #pragma unroll
    for (int k = 0; k < 9; ++k) wl[k] = w[c * 9 + k];
    float acc = 0.f;
    #pragma unroll
    for (int dy = 0; dy < 3; ++dy) {
        int yy = y + dy - 1;
        if (yy < 0 || yy >= Hh) continue;
        #pragma unroll
        for (int dx = 0; dx < 3; ++dx) {
            int xx = x + dx - 1;
            if (xx < 0 || xx >= Wb) continue;
            acc += wl[dy * 3 + dx] * ib[yy * Wb + xx];
        }
    }
    out[((size_t)b * Ct + c) * Nn + p] = acc;
}

// ---------------------------------------------------------------------------
// L2 normalize along N for each (b,c). In-place. grid: (Cc, 1, Bt), block 256.
// ---------------------------------------------------------------------------
__global__ __launch_bounds__(256) void l2norm_kernel(float* __restrict__ data) {
    int b = blockIdx.z, c = blockIdx.x;
    float* ptr = data + ((size_t)b * Cc + c) * Nn;
    int t = threadIdx.x;
    float s = 0.f;
    for (int i = t; i < Nn; i += 256) { float v = ptr[i]; s += v * v; }
    __shared__ float red[256];
    red[t] = s; __syncthreads();
    for (int st = 128; st > 0; st >>= 1) { if (t < st) red[t] += red[t + st]; __syncthreads(); }
    float scale = 1.0f / fmaxf(sqrtf(red[0]), 1e-12f);
    for (int i = t; i < Nn; i += 256) ptr[i] *= scale;
}

// ---------------------------------------------------------------------------
// Gate stage 2: g = sigmoid(g2.gmid + b2); per-block partial sums.
// grid: (64, 1, Bt). Writes blocksums[out_off + blockIdx.z*64 + blockIdx.x].
// ---------------------------------------------------------------------------
__global__ __launch_bounds__(256) void gate2_kernel(const float* __restrict__ gmid,
                                                    const float* __restrict__ w2,
                                                    const float* __restrict__ b2,
                                                    float* __restrict__ blocksums,
                                                    int out_off) {
    int p = blockIdx.x * 256 + threadIdx.x;
    int b = blockIdx.z;
    float acc = b2[0];
    const float* ib = gmid + (size_t)b * 64 * Nn + p;
    #pragma unroll 8
    for (int ci = 0; ci < 64; ++ci) acc += ib[(size_t)ci * Nn] * w2[ci];
    float g = 1.0f / (1.0f + expf(-acc));
    __shared__ float red[256];
    int t = threadIdx.x;
    red[t] = g; __syncthreads();
    for (int st = 128; st > 0; st >>= 1) { if (t < st) red[t] += red[t + st]; __syncthreads(); }
    if (t == 0) blocksums[out_off + b * 64 + blockIdx.x] = red[0];
}

// dk = clamp(trunc(16 * mean(g)), 1, 16). Deterministic double tree reduce.
__global__ __launch_bounds__(256) void gate_final_kernel(const float* __restrict__ blocksums,
                                                         int* __restrict__ dk_out) {
    __shared__ double sred[256];
    int t = threadIdx.x;
    sred[t] = (double)blocksums[t];
    __syncthreads();
    for (int st = 128; st > 0; st >>= 1) { if (t < st) sred[t] += sred[t + st]; __syncthreads(); }
    if (t == 0) {
        double mean = sred[0] / (double)(Bn * Nn);
        float val = 16.0f * (float)mean;
        int dk = (int)val;           // trunc like astype(int32)
        if (dk < 1) dk = 1;
        if (dk > 16) dk = 16;
        *dk_out = dk;
    }
}

// ---------------------------------------------------------------------------
// QK^T partial: partial[(b*HEADS+h)*NS+ns][c][d] =
//   sum_{n in chunk ns} q[b,hc+c,n] * k[b,hc+d,n]
// grid: (NS, HEADS, Bt), block 256 = 16x16 (c,d). Chunk = Nn/NS = 256 cols.
// ---------------------------------------------------------------------------
__global__ __launch_bounds__(256) void attn_qk_partial_kernel(const float* __restrict__ q,
                                                              const float* __restrict__ k,
                                                              float* __restrict__ partial) {
    int ns = blockIdx.x, h = blockIdx.y, b = blockIdx.z;
    int t = threadIdx.x;
    int c = t >> 4, d = t & 15;
    __shared__ float qs[16][65];
    __shared__ float ks[16][65];
    const float* qb = q + ((size_t)b * Cc + h * CHh) * Nn;
    const float* kb = k + ((size_t)b * Cc + h * CHh) * Nn;
    float acc = 0.f;
    int nbeg = ns * (Nn / NS);
    for (int n0 = nbeg; n0 < nbeg + (Nn / NS); n0 += 64) {
        for (int idx = t; idx < 1024; idx += 256) {
            int r = idx >> 6, col = idx & 63;
            qs[r][col] = qb[(size_t)r * Nn + n0 + col];
            ks[r][col] = kb[(size_t)r * Nn + n0 + col];
        }
        __syncthreads();
        #pragma unroll
        for (int j = 0; j < 64; ++j) acc += qs[c][j] * ks[d][j];
        __syncthreads();
    }
    partial[(((size_t)(b * HEADS + h)) * NS + ns) * 256 + t] = acc;
}

// Deterministic reduce over ns (fixed order) + temperature scale.
__global__ __launch_bounds__(256) void attn_reduce_kernel(const float* __restrict__ partial,
                                                          const float* __restrict__ temp,
                                                          float* __restrict__ attnp) {
    int bh = blockIdx.x;
    int h = bh % HEADS;
    int t = threadIdx.x;
    const float* pp = partial + (size_t)bh * NS * 256 + t;
    float s = 0.f;
    #pragma unroll 8
    for (int ns = 0; ns < NS; ++ns) s += pp[(size_t)ns * 256];
    attnp[(size_t)bh * 256 + t] = s * temp[h];
}

// ---------------------------------------------------------------------------
// Dynamic top-k mask + softmax on 16-wide rows. grid: (nmat), block 16.
// rank_i = #{a_j > a_i} + #{j<i : a_j == a_i}  (stable argsort rank)
// ---------------------------------------------------------------------------
__global__ void topk_softmax_kernel(float* __restrict__ attnp, const int* __restrict__ dkp) {
    int bh = blockIdx.x;
    int c = threadIdx.x;
    if (c >= 16) return;
    float* row = attnp + ((size_t)bh * CHh + c) * CHh;
    float a[16];
    #pragma unroll
    for (int d = 0; d < 16; ++d) a[d] = row[d];
    int dk = *dkp;
    unsigned keep = 0;
    float m = -INFINITY;
    #pragma unroll
    for (int d = 0; d < 16; ++d) {
        int rank = 0;
        #pragma unroll
        for (int j = 0; j < 16; ++j)
            rank += (a[j] > a[d]) || (a[j] == a[d] && j < d);
        if (rank < dk) { keep |= (1u << d); m = fmaxf(m, a[d]); }
    }
    float e[16]; float s = 0.f;
    #pragma unroll
    for (int d = 0; d < 16; ++d) {
        e[d] = (keep >> d & 1u) ? expf(a[d] - m) : 0.f;
        s += e[d];
    }
    float invs = 1.0f / s;
    #pragma unroll
    for (int d = 0; d < 16; ++d) row[d] = e[d] * invs;
}

// ---------------------------------------------------------------------------
// out[b, h*16+cr, p] = sum_d attn[b,h,cr,d] * v[b, h*16+d, p]
// grid: (Nn/256, Cc, Bt). v is its own 128-ch buffer.
// ---------------------------------------------------------------------------
__global__ __launch_bounds__(256) void attn_v_kernel(const float* __restrict__ attnp,
                                                     const float* __restrict__ v,
                                                     float* __restrict__ out) {
    int p = blockIdx.x * 256 + threadIdx.x;
    int cg = blockIdx.y;
    int b = blockIdx.z;
    int h = cg >> 4, cr = cg & 15;
    const float* arow = attnp + (((size_t)b * HEADS + h) * CHh + cr) * CHh;
    const float* vb = v + ((size_t)b * Cc + h * CHh) * Nn + p;
    float acc = 0.f;
    #pragma unroll
    for (int d = 0; d < 16; ++d) acc += arow[d] * vb[(size_t)d * Nn];
    out[((size_t)b * Cc + cg) * Nn + p] = acc;
}

// ---------------------------------------------------------------------------
// Fused IEL tail for one batch and a channel chunk [c0, c0+chunkC):
//   u1 = dw3x3(t1,wA); u2 = dw3x3(t2,wB)  (pad=1, zero outside image)
//   prod[c] = (tanh(dw3x3(u1,w1)) + u1) * (tanh(dw3x3(u2,w2)) + u2)
// grid: (64, chunkC, 1), block 256 (16x16 tile, halo 2).
// ---------------------------------------------------------------------------
__global__ __launch_bounds__(256) void iel_tail_kernel(const float* __restrict__ t1p,
                                                       const float* __restrict__ t2p,
                                                       const float* __restrict__ dwA,
                                                       const float* __restrict__ dwB,
                                                       const float* __restrict__ dw1p,
                                                       const float* __restrict__ dw2p,
                                                       float* __restrict__ prod) {
    const int c = blockIdx.y;
    const int tilesx = Wb / 16;
    const int ty0 = (blockIdx.x / tilesx) * 16;
    const int tx0 = (blockIdx.x % tilesx) * 16;
    const int tid = threadIdx.x;

    __shared__ float ts[2][20][21];
    __shared__ float us[2][18][19];

    const float* t1 = t1p + (size_t)c * Nn;
    const float* t2 = t2p + (size_t)c * Nn;

    for (int idx = tid; idx < 400; idx += 256) {
        int i = idx / 20, j = idx % 20;
        int gy = ty0 - 2 + i, gx = tx0 - 2 + j;
        bool ok = (gy >= 0 && gy < Hh && gx >= 0 && gx < Wb);
        ts[0][i][j] = ok ? t1[gy * Wb + gx] : 0.f;
        ts[1][i][j] = ok ? t2[gy * Wb + gx] : 0.f;
    }
    __syncthreads();

    float wA[9], wB[9], w1[9], w2[9];
    #pragma unroll
    for (int k = 0; k < 9; ++k) {
        wA[k] = dwA[c * 9 + k];
        wB[k] = dwB[c * 9 + k];
        w1[k] = dw1p[c * 9 + k];
        w2[k] = dw2p[c * 9 + k];
    }

    for (int idx = tid; idx < 324; idx += 256) {
        int i = idx / 18, j = idx % 18;
        int gy = ty0 - 1 + i, gx = tx0 - 1 + j;
        float a0 = 0.f, a1 = 0.f;
        if (gy >= 0 && gy < Hh && gx >= 0 && gx < Wb) {
            #pragma unroll
            for (int dy = 0; dy < 3; ++dy)
                #pragma unroll
                for (int dx = 0; dx < 3; ++dx) {
                    a0 += wA[dy * 3 + dx] * ts[0][i + dy][j + dx];
                    a1 += wB[dy * 3 + dx] * ts[1][i + dy][j + dx];
                }
        }
        us[0][i][j] = a0;
        us[1][i][j] = a1;
    }
    __syncthreads();

    int ty = tid >> 4, tx = tid & 15;
    float c1 = us[0][ty + 1][tx + 1];
    float c2 = us[1][ty + 1][tx + 1];
    float s1 = 0.f, s2 = 0.f;
    #pragma unroll
    for (int dy = 0; dy < 3; ++dy)
        #pragma unroll
        for (int dx = 0; dx < 3; ++dx) {
            s1 += w1[dy * 3 + dx] * us[0][ty + dy][tx + dx];
            s2 += w2[dy * 3 + dx] * us[1][ty + dy][tx + dx];
        }
    float x1t = tanhf(s1) + c1;
    float x2t = tanhf(s2) + c2;
    prod[(size_t)c * Nn + (ty0 + ty) * Wb + (tx0 + tx)] = x1t * x2t;
}

// ---------------------------------------------------------------------------
// Host launcher — adaptive to ws_size (constant across calls => capture-safe)
// ---------------------------------------------------------------------------
extern "C" void kernel_launch(void* const* d_in, const int* in_sizes, int n_in,
                              void* d_out, int out_size, void* d_ws, size_t ws_size,
                              hipStream_t stream) {
    const float* x      = (const float*)d_in[0];
    const float* y      = (const float*)d_in[1];
    const float* ln_w   = (const float*)d_in[2];
    const float* ln_b   = (const float*)d_in[3];
    const float* temp   = (const float*)d_in[4];
    const float* q_w    = (const float*)d_in[5];
    const float* qdw_w  = (const float*)d_in[6];
    const float* kv_w   = (const float*)d_in[7];
    const float* kvdw_w = (const float*)d_in[8];
    const float* po_w   = (const float*)d_in[9];
    const float* g1_w   = (const float*)d_in[10];
    const float* g1_b   = (const float*)d_in[11];
    const float* g2_w   = (const float*)d_in[12];
    const float* g2_b   = (const float*)d_in[13];
    const float* pin_w  = (const float*)d_in[14];
    const float* dw_w   = (const float*)d_in[15];
    const float* dw1_w  = (const float*)d_in[16];
    const float* dw2_w  = (const float*)d_in[17];
    const float* pout_w = (const float*)d_in[18];
    float* out = (float*)d_out;

    // smalls at ws+0, pool at ws+64KiB
    char* ws = (char*)d_ws;
    float* attn      = (float*)ws;           // 8192 floats (B*HEADS*16*16)
    float* blocksums = attn + 8192;          // 256 floats
    int*   dk        = (int*)(blocksums + 256);
    float* pool      = (float*)(ws + 65536);

    const size_t CN  = (size_t)Cc * Nn;            // 2,097,152 floats (8 MiB)
    const size_t SLOT1 = (size_t)Bn * CN;          // 32 MiB slot (floats)
    const size_t TIER1_NEED = 65536 + 6 * SLOT1 * 4;

    dim3 blk(256);
    const int PGX = Nn / 1024;   // 16 blocks in x for the vectorized conv

    if (ws_size >= TIER1_NEED) {
        // ================= Tier 1: full-batch phase A (6 x 32MiB slots) =====
        float* S0 = pool;             // xn -> zn (phase B)
        float* S1 = pool + 1 * SLOT1; // yn -> gmid -> attn partial -> T1
        float* S2 = pool + 2 * SLOT1; // scratch (q1/k1/v1) -> attn_out -> T2
        float* S3 = pool + 3 * SLOT1; // q2 -> prod
        float* S4 = pool + 4 * SLOT1; // k2
        float* S5 = pool + 5 * SLOT1; // v2

        ln_kernel<<<dim3(Nn / 256, 1, Bn), blk, 0, stream>>>(x, ln_w, ln_b, S0);
        ln_kernel<<<dim3(Nn / 256, 1, Bn), blk, 0, stream>>>(y, ln_w, ln_b, S1);

        conv1x1v_kernel<16><<<dim3(PGX, 8, Bn), blk, 0, stream>>>(
            S0, q_w, Cc, nullptr, nullptr, S2, Cc, Cc, 0);
        dw3x3_kernel<<<dim3(Nn / 256, Cc, Bn), blk, 0, stream>>>(S2, qdw_w, S3, Cc);

        conv1x1v_kernel<16><<<dim3(PGX, 8, Bn), blk, 0, stream>>>(
            S1, kv_w, Cc, nullptr, nullptr, S2, Cc, Cc, 0);
        dw3x3_kernel<<<dim3(Nn / 256, Cc, Bn), blk, 0, stream>>>(S2, kvdw_w, S4, Cc);

        conv1x1v_kernel<16><<<dim3(PGX, 8, Bn), blk, 0, stream>>>(
            S1, kv_w + 128 * 128, Cc, nullptr, nullptr, S2, Cc, Cc, 0);
        dw3x3_kernel<<<dim3(Nn / 256, Cc, Bn), blk, 0, stream>>>(S2, kvdw_w + 128 * 9, S5, Cc);

        // gate (gmid overwrites yn in S1 — yn is dead)
        conv1x1v_kernel<16><<<dim3(PGX, 4, Bn), blk, 0, stream>>>(
            S0, g1_w, Cc, g1_b, nullptr, S1, Cc, 64, 1);
        gate2_kernel<<<dim3(Nn / 256, 1, Bn), blk, 0, stream>>>(S1, g2_w, g2_b, blocksums, 0);
        gate_final_kernel<<<dim3(1), blk, 0, stream>>>(blocksums, dk);

        l2norm_kernel<<<dim3(Cc, 1, Bn), blk, 0, stream>>>(S3);
        l2norm_kernel<<<dim3(Cc, 1, Bn), blk, 0, stream>>>(S4);

        // attn partial reuses S1 (gmid dead after gate2): 2 MiB
        float* partial = S1;
        attn_qk_partial_kernel<<<dim3(NS, HEADS, Bn), blk, 0, stream>>>(S3, S4, partial);
        attn_reduce_kernel<<<dim3(Bn * HEADS), blk, 0, stream>>>(partial, temp, attn);
        topk_softmax_kernel<<<dim3(Bn * HEADS), dim3(16), 0, stream>>>(attn, dk);
        attn_v_kernel<<<dim3(Nn / 256, Cc, Bn), blk, 0, stream>>>(attn, S5, S2);

        conv1x1v_kernel<16><<<dim3(PGX, 8, Bn), blk, 0, stream>>>(
            S2, po_w, Cc, nullptr, x, out, Cc, Cc, 0);

        // ---- Phase B: IEL ----
        // batched LN into S0 (dead xn slot)
        ln_kernel<<<dim3(Nn / 256, 1, Bn), blk, 0, stream>>>(out, ln_w, ln_b, S0);

        for (int b = 0; b < Bn; ++b) {
            float* znb  = S0 + (size_t)b * CN;
            float* outb = out + (size_t)b * CN;
            float* T1 = S1, *T2 = S2, *prod = S3;  // each <= 32 MiB
            conv1x1v_kernel<20><<<dim3(PGX, 17, 1), blk, 0, stream>>>(
                znb, pin_w, Cc, nullptr, nullptr, T1, Cc, HID, 0);
            conv1x1v_kernel<20><<<dim3(PGX, 17, 1), blk, 0, stream>>>(
                znb, pin_w + (size_t)HID * Cc, Cc, nullptr, nullptr, T2, Cc, HID, 0);
            iel_tail_kernel<<<dim3(64, HID, 1), blk, 0, stream>>>(
                T1, T2, dw_w, dw_w + HID * 9, dw1_w, dw2_w, prod);
            conv1x1v_kernel<8><<<dim3(PGX, 16, 1), blk, 0, stream>>>(
                prod, pout_w, HID, nullptr, outb, outb, HID, Cc, 0);
        }
    } else {
        // ================= Tier 2: per-batch everything (~48 MiB pool) ======
        float* s0 = pool;
        float* s1 = pool + 1 * CN;
        float* s2 = pool + 2 * CN;
        float* s3 = pool + 3 * CN;
        float* s4 = pool + 4 * CN;
        float* s5 = pool + 5 * CN;

        // gate pass (needs full-batch mean before any topk)
        for (int b = 0; b < Bn; ++b) {
            const float* xb = x + (size_t)b * CN;
            ln_kernel<<<dim3(Nn / 256, 1, 1), blk, 0, stream>>>(xb, ln_w, ln_b, s0);
            conv1x1v_kernel<16><<<dim3(PGX, 4, 1), blk, 0, stream>>>(
                s0, g1_w, Cc, g1_b, nullptr, s1, Cc, 64, 1);
            gate2_kernel<<<dim3(Nn / 256, 1, 1), blk, 0, stream>>>(
                s1, g2_w, g2_b, blocksums, b * 64);
        }
        gate_final_kernel<<<dim3(1), blk, 0, stream>>>(blocksums, dk);

        // attention pass
        for (int b = 0; b < Bn; ++b) {
            const float* xb = x + (size_t)b * CN;
            const float* yb = y + (size_t)b * CN;
            float* outb = out + (size_t)b * CN;
            float* attnb = attn + (size_t)b * HEADS * CHh * CHh;

            ln_kernel<<<dim3(Nn / 256, 1, 1), blk, 0, stream>>>(xb, ln_w, ln_b, s0);
            ln_kernel<<<dim3(Nn / 256, 1, 1), blk, 0, stream>>>(yb, ln_w, ln_b, s1);

            conv1x1v_kernel<16><<<dim3(PGX, 8, 1), blk, 0, stream>>>(
                s0, q_w, Cc, nullptr, nullptr, s2, Cc, Cc, 0);
            dw3x3_kernel<<<dim3(Nn / 256, Cc, 1), blk, 0, stream>>>(s2, qdw_w, s3, Cc);
            l2norm_kernel<<<dim3(Cc, 1, 1), blk, 0, stream>>>(s3);

            conv1x1v_kernel<16><<<dim3(PGX, 8, 1), blk, 0, stream>>>(
                s1, kv_w, Cc, nullptr, nullptr, s2, Cc, Cc, 0);
            dw3x3_kernel<<<dim3(Nn / 256, Cc, 1), blk, 0, stream>>>(s2, kvdw_w, s4, Cc);
            l2norm_kernel<<<dim3(Cc, 1, 1), blk, 0, stream>>>(s4);

            conv1x1v_kernel<16><<<dim3(PGX, 8, 1), blk, 0, stream>>>(
                s1, kv_w + 128 * 128, Cc, nullptr, nullptr, s2, Cc, Cc, 0);
            dw3x3_kernel<<<dim3(Nn / 256, Cc, 1), blk, 0, stream>>>(s2, kvdw_w + 128 * 9, s5, Cc);

            // partial reuses s2 (dead here; attn_v output comes later)
            attn_qk_partial_kernel<<<dim3(NS, HEADS, 1), blk, 0, stream>>>(s3, s4, s2);
            attn_reduce_kernel<<<dim3(HEADS), blk, 0, stream>>>(s2, temp, attnb);
            topk_softmax_kernel<<<dim3(HEADS), dim3(16), 0, stream>>>(attnb, dk);
            attn_v_kernel<<<dim3(Nn / 256, Cc, 1), blk, 0, stream>>>(attnb, s5, s2);

            conv1x1v_kernel<16><<<dim3(PGX, 8, 1), blk, 0, stream>>>(
                s2, po_w, Cc, nullptr, xb, outb, Cc, Cc, 0);
        }

        // IEL pass, 2 channel chunks of 170
        const int CHUNK = 170;
        const size_t TCH = (size_t)CHUNK * Nn;
        float* zn   = pool;            // 8 MiB
        float* T1   = pool + CN;
        float* T2   = T1 + TCH;
        float* prod = T2 + TCH;
        for (int b = 0; b < Bn; ++b) {
            float* outb = out + (size_t)b * CN;
            ln_kernel<<<dim3(Nn / 256, 1, 1), blk, 0, stream>>>(outb, ln_w, ln_b, zn);
            for (int c0 = 0; c0 < HID; c0 += CHUNK) {
                conv1x1v_kernel<20><<<dim3(PGX, 9, 1), blk, 0, stream>>>(
                    zn, pin_w + (size_t)c0 * Cc, Cc, nullptr, nullptr, T1, Cc, CHUNK, 0);
                conv1x1v_kernel<20><<<dim3(PGX, 9, 1), blk, 0, stream>>>(
                    zn, pin_w + (size_t)(HID + c0) * Cc, Cc, nullptr, nullptr, T2, Cc, CHUNK, 0);
                iel_tail_kernel<<<dim3(64, CHUNK, 1), blk, 0, stream>>>(
                    T1, T2, dw_w + c0 * 9, dw_w + (HID + c0) * 9,
                    dw1_w + c0 * 9, dw2_w + c0 * 9, prod);
                conv1x1v_kernel<8><<<dim3(PGX, 16, 1), blk, 0, stream>>>(
                    prod, pout_w + c0, HID, nullptr, outb, outb, CHUNK, Cc, 0);
            }
        }
    }
}

// Round 5
// 1083.791 us; speedup vs baseline: 2.8349x; 1.2591x over previous
//
#include <hip/hip_runtime.h>
#include <math.h>

// Problem constants
static constexpr int Bn    = 4;
static constexpr int Cc    = 128;
static constexpr int Hh    = 128;
static constexpr int Wb    = 128;
static constexpr int Nn    = Hh * Wb;      // 16384
static constexpr int HEADS = 8;
static constexpr int CHh   = 16;           // Cc / HEADS
static constexpr int HID   = 340;
static constexpr int HID2  = 680;
static constexpr int NS    = 64;           // n-splits for attn QK^T

// ---------------------------------------------------------------------------
// LayerNorm over channel axis (axis=1), per pixel.
// grid: (Nn/256, 1, Bt). b = blockIdx.z.
// ---------------------------------------------------------------------------
__global__ __launch_bounds__(256) void ln_kernel(const float* __restrict__ in,
                                                 const float* __restrict__ w,
                                                 const float* __restrict__ bias,
                                                 float* __restrict__ out) {
    int p = blockIdx.x * 256 + threadIdx.x;
    int b = blockIdx.z;
    const float* ib = in + (size_t)b * Cc * Nn + p;
    float s = 0.f, s2 = 0.f;
    #pragma unroll 8
    for (int c = 0; c < Cc; ++c) {
        float v = ib[(size_t)c * Nn];
        s += v; s2 += v * v;
    }
    float mean = s * (1.0f / Cc);
    float var  = s2 * (1.0f / Cc) - mean * mean;
    float inv  = 1.0f / sqrtf(var + 1e-6f);
    float* ob = out + (size_t)b * Cc * Nn + p;
    #pragma unroll 8
    for (int c = 0; c < Cc; ++c) {
        float v = ib[(size_t)c * Nn];
        ob[(size_t)c * Nn] = w[c] * ((v - mean) * inv) + bias[c];
    }
}

// ---------------------------------------------------------------------------
// Vectorized 1x1 conv (GEMM): out[b,co,p] = sum_ci W[co*wstride+ci]*in[b,ci,p]
// Each thread: 4 consecutive pixels (float4) x TCO output channels.
// Weight rows uniform (SGPR/s_load). ci-loop unrolled 8 -> 8 dwordx4 in
// flight per thread (ILP latency hiding). grid: (Nn/1024, ceil(Cout/TCO), Bt)
// ---------------------------------------------------------------------------
template <int TCO>
__global__ __launch_bounds__(256) void conv1x1v_kernel(const float* __restrict__ in,
                                                       const float* __restrict__ wgt,
                                                       int wstride,
                                                       const float* __restrict__ bias,
                                                       const float* __restrict__ res,
                                                       float* __restrict__ out,
                                                       int Cin, int Cout, int act) {
    int pg  = blockIdx.x * 256 + threadIdx.x;   // pixel group (4 px)
    int b   = blockIdx.z;
    int co0 = blockIdx.y * TCO;

    const float* wrow[TCO];
    #pragma unroll
    for (int i = 0; i < TCO; ++i) {
        int co = co0 + i; if (co > Cout - 1) co = Cout - 1;   // uniform clamp
        wrow[i] = wgt + (size_t)co * wstride;
    }

    float4 acc[TCO];
    #pragma unroll
    for (int i = 0; i < TCO; ++i) acc[i] = make_float4(0.f, 0.f, 0.f, 0.f);

    const float* ib = in + (size_t)b * Cin * Nn + (size_t)pg * 4;
    #pragma unroll 8
    for (int ci = 0; ci < Cin; ++ci) {
        float4 v = *(const float4*)(ib + (size_t)ci * Nn);
        #pragma unroll
        for (int i = 0; i < TCO; ++i) {
            float w = wrow[i][ci];
            acc[i].x += v.x * w;
            acc[i].y += v.y * w;
            acc[i].z += v.z * w;
            acc[i].w += v.w * w;
        }
    }

    #pragma unroll
    for (int i = 0; i < TCO; ++i) {
        int co = co0 + i;
        if (co < Cout) {
            float4 r = acc[i];
            if (bias) { float bb = bias[co]; r.x += bb; r.y += bb; r.z += bb; r.w += bb; }
            if (act == 1) {
                r.x = fmaxf(r.x, 0.f); r.y = fmaxf(r.y, 0.f);
                r.z = fmaxf(r.z, 0.f); r.w = fmaxf(r.w, 0.f);
            }
            size_t o = ((size_t)b * Cout + co) * Nn + (size_t)pg * 4;
            if (res) {
                float4 rv = *(const float4*)(res + o);
                r.x += rv.x; r.y += rv.y; r.z += rv.z; r.w += rv.w;
            }
            *(float4*)(out + o) = r;
        }
    }
}

// ---------------------------------------------------------------------------
// Depthwise 3x3 conv, pad=1. grid: (Nn/256, Ct, Bt). w pre-offset to channel 0.
// ---------------------------------------------------------------------------
__global__ __launch_bounds__(256) void dw3x3_kernel(const float* __restrict__ in,
                                                    const float* __restrict__ w,
                                                    float* __restrict__ out, int Ct) {
    int p = blockIdx.x * 256 + threadIdx.x;
    int c = blockIdx.y;
    int b = blockIdx.z;
    int y = p >> 7, x = p & (Wb - 1);
    const float* ib = in + ((size_t)b * Ct + c) * Nn;
    float wl[9];
    #pragma unroll
    for (int k = 0; k < 9; ++k) wl[k] = w[c * 9 + k];
    float acc = 0.f;
    #pragma unroll
    for (int dy = 0; dy < 3; ++dy) {
        int yy = y + dy - 1;
        if (yy < 0 || yy >= Hh) continue;
        #pragma unroll
        for (int dx = 0; dx < 3; ++dx) {
            int xx = x + dx - 1;
            if (xx < 0 || xx >= Wb) continue;
            acc += wl[dy * 3 + dx] * ib[yy * Wb + xx];
        }
    }
    out[((size_t)b * Ct + c) * Nn + p] = acc;
}

// ---------------------------------------------------------------------------
// L2 normalize along N for each (b,c). In-place. grid: (Cc, 1, Bt), block 256.
// ---------------------------------------------------------------------------
__global__ __launch_bounds__(256) void l2norm_kernel(float* __restrict__ data) {
    int b = blockIdx.z, c = blockIdx.x;
    float* ptr = data + ((size_t)b * Cc + c) * Nn;
    int t = threadIdx.x;
    float s = 0.f;
    for (int i = t; i < Nn; i += 256) { float v = ptr[i]; s += v * v; }
    __shared__ float red[256];
    red[t] = s; __syncthreads();
    for (int st = 128; st > 0; st >>= 1) { if (t < st) red[t] += red[t + st]; __syncthreads(); }
    float scale = 1.0f / fmaxf(sqrtf(red[0]), 1e-12f);
    for (int i = t; i < Nn; i += 256) ptr[i] *= scale;
}

// ---------------------------------------------------------------------------
// Gate stage 2: g = sigmoid(g2.gmid + b2); per-block partial sums.
// grid: (64, 1, Bt). Writes blocksums[out_off + blockIdx.z*64 + blockIdx.x].
// ---------------------------------------------------------------------------
__global__ __launch_bounds__(256) void gate2_kernel(const float* __restrict__ gmid,
                                                    const float* __restrict__ w2,
                                                    const float* __restrict__ b2,
                                                    float* __restrict__ blocksums,
                                                    int out_off) {
    int p = blockIdx.x * 256 + threadIdx.x;
    int b = blockIdx.z;
    float acc = b2[0];
    const float* ib = gmid + (size_t)b * 64 * Nn + p;
    #pragma unroll 8
    for (int ci = 0; ci < 64; ++ci) acc += ib[(size_t)ci * Nn] * w2[ci];
    float g = 1.0f / (1.0f + expf(-acc));
    __shared__ float red[256];
    int t = threadIdx.x;
    red[t] = g; __syncthreads();
    for (int st = 128; st > 0; st >>= 1) { if (t < st) red[t] += red[t + st]; __syncthreads(); }
    if (t == 0) blocksums[out_off + b * 64 + blockIdx.x] = red[0];
}

// dk = clamp(trunc(16 * mean(g)), 1, 16). Deterministic double tree reduce.
__global__ __launch_bounds__(256) void gate_final_kernel(const float* __restrict__ blocksums,
                                                         int* __restrict__ dk_out) {
    __shared__ double sred[256];
    int t = threadIdx.x;
    sred[t] = (double)blocksums[t];
    __syncthreads();
    for (int st = 128; st > 0; st >>= 1) { if (t < st) sred[t] += sred[t + st]; __syncthreads(); }
    if (t == 0) {
        double mean = sred[0] / (double)(Bn * Nn);
        float val = 16.0f * (float)mean;
        int dk = (int)val;           // trunc like astype(int32)
        if (dk < 1) dk = 1;
        if (dk > 16) dk = 16;
        *dk_out = dk;
    }
}

// ---------------------------------------------------------------------------
// QK^T partial. grid: (NS, HEADS, Bt), block 256 = 16x16 (c,d).
// ---------------------------------------------------------------------------
__global__ __launch_bounds__(256) void attn_qk_partial_kernel(const float* __restrict__ q,
                                                              const float* __restrict__ k,
                                                              float* __restrict__ partial) {
    int ns = blockIdx.x, h = blockIdx.y, b = blockIdx.z;
    int t = threadIdx.x;
    int c = t >> 4, d = t & 15;
    __shared__ float qs[16][65];
    __shared__ float ks[16][65];
    const float* qb = q + ((size_t)b * Cc + h * CHh) * Nn;
    const float* kb = k + ((size_t)b * Cc + h * CHh) * Nn;
    float acc = 0.f;
    int nbeg = ns * (Nn / NS);
    for (int n0 = nbeg; n0 < nbeg + (Nn / NS); n0 += 64) {
        for (int idx = t; idx < 1024; idx += 256) {
            int r = idx >> 6, col = idx & 63;
            qs[r][col] = qb[(size_t)r * Nn + n0 + col];
            ks[r][col] = kb[(size_t)r * Nn + n0 + col];
        }
        __syncthreads();
        #pragma unroll
        for (int j = 0; j < 64; ++j) acc += qs[c][j] * ks[d][j];
        __syncthreads();
    }
    partial[(((size_t)(b * HEADS + h)) * NS + ns) * 256 + t] = acc;
}

// Deterministic reduce over ns (fixed order) + temperature scale.
__global__ __launch_bounds__(256) void attn_reduce_kernel(const float* __restrict__ partial,
                                                          const float* __restrict__ temp,
                                                          float* __restrict__ attnp) {
    int bh = blockIdx.x;
    int h = bh % HEADS;
    int t = threadIdx.x;
    const float* pp = partial + (size_t)bh * NS * 256 + t;
    float s = 0.f;
    #pragma unroll 8
    for (int ns = 0; ns < NS; ++ns) s += pp[(size_t)ns * 256];
    attnp[(size_t)bh * 256 + t] = s * temp[h];
}

// ---------------------------------------------------------------------------
// Dynamic top-k mask + softmax on 16-wide rows. grid: (nmat), block 16.
// rank_i = #{a_j > a_i} + #{j<i : a_j == a_i}  (stable argsort rank)
// ---------------------------------------------------------------------------
__global__ void topk_softmax_kernel(float* __restrict__ attnp, const int* __restrict__ dkp) {
    int bh = blockIdx.x;
    int c = threadIdx.x;
    if (c >= 16) return;
    float* row = attnp + ((size_t)bh * CHh + c) * CHh;
    float a[16];
    #pragma unroll
    for (int d = 0; d < 16; ++d) a[d] = row[d];
    int dk = *dkp;
    unsigned keep = 0;
    float m = -INFINITY;
    #pragma unroll
    for (int d = 0; d < 16; ++d) {
        int rank = 0;
        #pragma unroll
        for (int j = 0; j < 16; ++j)
            rank += (a[j] > a[d]) || (a[j] == a[d] && j < d);
        if (rank < dk) { keep |= (1u << d); m = fmaxf(m, a[d]); }
    }
    float e[16]; float s = 0.f;
    #pragma unroll
    for (int d = 0; d < 16; ++d) {
        e[d] = (keep >> d & 1u) ? expf(a[d] - m) : 0.f;
        s += e[d];
    }
    float invs = 1.0f / s;
    #pragma unroll
    for (int d = 0; d < 16; ++d) row[d] = e[d] * invs;
}

// ---------------------------------------------------------------------------
// out[b, h*16+cr, p] = sum_d attn[b,h,cr,d] * v[b, h*16+d, p]
// grid: (Nn/256, Cc, Bt).
// ---------------------------------------------------------------------------
__global__ __launch_bounds__(256) void attn_v_kernel(const float* __restrict__ attnp,
                                                     const float* __restrict__ v,
                                                     float* __restrict__ out) {
    int p = blockIdx.x * 256 + threadIdx.x;
    int cg = blockIdx.y;
    int b = blockIdx.z;
    int h = cg >> 4, cr = cg & 15;
    const float* arow = attnp + (((size_t)b * HEADS + h) * CHh + cr) * CHh;
    const float* vb = v + ((size_t)b * Cc + h * CHh) * Nn + p;
    float acc = 0.f;
    #pragma unroll
    for (int d = 0; d < 16; ++d) acc += arow[d] * vb[(size_t)d * Nn];
    out[((size_t)b * Cc + cg) * Nn + p] = acc;
}

// ---------------------------------------------------------------------------
// Fused IEL tail, batched. grid: (64, HID, BT), block 256 (16x16 tile, halo 2).
// t1p,t2p,prod strides: b*HID*Nn per batch. Weights not batch-dependent.
// ---------------------------------------------------------------------------
__global__ __launch_bounds__(256) void iel_tail_kernel(const float* __restrict__ t1p,
                                                       const float* __restrict__ t2p,
                                                       const float* __restrict__ dwA,
                                                       const float* __restrict__ dwB,
                                                       const float* __restrict__ dw1p,
                                                       const float* __restrict__ dw2p,
                                                       float* __restrict__ prod) {
    const int c = blockIdx.y;
    const int b = blockIdx.z;
    const int tilesx = Wb / 16;
    const int ty0 = (blockIdx.x / tilesx) * 16;
    const int tx0 = (blockIdx.x % tilesx) * 16;
    const int tid = threadIdx.x;

    __shared__ float ts[2][20][21];
    __shared__ float us[2][18][19];

    const float* t1 = t1p + ((size_t)b * HID + c) * Nn;
    const float* t2 = t2p + ((size_t)b * HID + c) * Nn;

    for (int idx = tid; idx < 400; idx += 256) {
        int i = idx / 20, j = idx % 20;
        int gy = ty0 - 2 + i, gx = tx0 - 2 + j;
        bool ok = (gy >= 0 && gy < Hh && gx >= 0 && gx < Wb);
        ts[0][i][j] = ok ? t1[gy * Wb + gx] : 0.f;
        ts[1][i][j] = ok ? t2[gy * Wb + gx] : 0.f;
    }
    __syncthreads();

    float wA[9], wB[9], w1[9], w2[9];
    #pragma unroll
    for (int k = 0; k < 9; ++k) {
        wA[k] = dwA[c * 9 + k];
        wB[k] = dwB[c * 9 + k];
        w1[k] = dw1p[c * 9 + k];
        w2[k] = dw2p[c * 9 + k];
    }

    for (int idx = tid; idx < 324; idx += 256) {
        int i = idx / 18, j = idx % 18;
        int gy = ty0 - 1 + i, gx = tx0 - 1 + j;
        float a0 = 0.f, a1 = 0.f;
        if (gy >= 0 && gy < Hh && gx >= 0 && gx < Wb) {
            #pragma unroll
            for (int dy = 0; dy < 3; ++dy)
                #pragma unroll
                for (int dx = 0; dx < 3; ++dx) {
                    a0 += wA[dy * 3 + dx] * ts[0][i + dy][j + dx];
                    a1 += wB[dy * 3 + dx] * ts[1][i + dy][j + dx];
                }
        }
        us[0][i][j] = a0;
        us[1][i][j] = a1;
    }
    __syncthreads();

    int ty = tid >> 4, tx = tid & 15;
    float c1 = us[0][ty + 1][tx + 1];
    float c2 = us[1][ty + 1][tx + 1];
    float s1 = 0.f, s2 = 0.f;
    #pragma unroll
    for (int dy = 0; dy < 3; ++dy)
        #pragma unroll
        for (int dx = 0; dx < 3; ++dx) {
            s1 += w1[dy * 3 + dx] * us[0][ty + dy][tx + dx];
            s2 += w2[dy * 3 + dx] * us[1][ty + dy][tx + dx];
        }
    float x1t = tanhf(s1) + c1;
    float x2t = tanhf(s2) + c2;
    prod[((size_t)b * HID + c) * Nn + (ty0 + ty) * Wb + (tx0 + tx)] = x1t * x2t;
}

// ---------------------------------------------------------------------------
// Host launcher — adaptive to ws_size (constant across calls => capture-safe)
// ---------------------------------------------------------------------------
extern "C" void kernel_launch(void* const* d_in, const int* in_sizes, int n_in,
                              void* d_out, int out_size, void* d_ws, size_t ws_size,
                              hipStream_t stream) {
    const float* x      = (const float*)d_in[0];
    const float* y      = (const float*)d_in[1];
    const float* ln_w   = (const float*)d_in[2];
    const float* ln_b   = (const float*)d_in[3];
    const float* temp   = (const float*)d_in[4];
    const float* q_w    = (const float*)d_in[5];
    const float* qdw_w  = (const float*)d_in[6];
    const float* kv_w   = (const float*)d_in[7];
    const float* kvdw_w = (const float*)d_in[8];
    const float* po_w   = (const float*)d_in[9];
    const float* g1_w   = (const float*)d_in[10];
    const float* g1_b   = (const float*)d_in[11];
    const float* g2_w   = (const float*)d_in[12];
    const float* g2_b   = (const float*)d_in[13];
    const float* pin_w  = (const float*)d_in[14];
    const float* dw_w   = (const float*)d_in[15];
    const float* dw1_w  = (const float*)d_in[16];
    const float* dw2_w  = (const float*)d_in[17];
    const float* pout_w = (const float*)d_in[18];
    float* out = (float*)d_out;

    // smalls at ws+0, pool at ws+64KiB
    char* ws = (char*)d_ws;
    float* attn      = (float*)ws;           // 8192 floats (B*HEADS*16*16)
    float* blocksums = attn + 8192;          // 256 floats
    int*   dk        = (int*)(blocksums + 256);
    float* pool      = (float*)(ws + 65536);

    const size_t CN    = (size_t)Cc * Nn;          // 2,097,152 floats (8 MiB)
    const size_t HN    = (size_t)HID * Nn;         // 5,570,560 floats (~21.25 MiB)
    const size_t SLOT1 = (size_t)Bn * CN;          // 32 MiB slot (floats)
    const size_t TIER1_NEED = 65536 + 6 * SLOT1 * 4;
    // Phase-B full-batch (BT=4): zn(Bn*CN) + 3 * Bn*HN floats
    const size_t TIER0_NEED = 65536 + (Bn * CN + 3 * Bn * HN) * 4;

    dim3 blk(256);
    const int PGX = Nn / 1024;   // 16 blocks in x for the vectorized conv

    if (ws_size >= TIER1_NEED) {
        // ================= Phase A: full-batch (6 x 32MiB slots) ============
        float* S0 = pool;             // xn -> zn (phase B)
        float* S1 = pool + 1 * SLOT1; // yn -> gmid -> attn partial
        float* S2 = pool + 2 * SLOT1; // scratch (q1/k1/v1) -> attn_out
        float* S3 = pool + 3 * SLOT1; // q2
        float* S4 = pool + 4 * SLOT1; // k2
        float* S5 = pool + 5 * SLOT1; // v2

        ln_kernel<<<dim3(Nn / 256, 1, Bn), blk, 0, stream>>>(x, ln_w, ln_b, S0);
        ln_kernel<<<dim3(Nn / 256, 1, Bn), blk, 0, stream>>>(y, ln_w, ln_b, S1);

        conv1x1v_kernel<8><<<dim3(PGX, 16, Bn), blk, 0, stream>>>(
            S0, q_w, Cc, nullptr, nullptr, S2, Cc, Cc, 0);
        dw3x3_kernel<<<dim3(Nn / 256, Cc, Bn), blk, 0, stream>>>(S2, qdw_w, S3, Cc);

        conv1x1v_kernel<8><<<dim3(PGX, 16, Bn), blk, 0, stream>>>(
            S1, kv_w, Cc, nullptr, nullptr, S2, Cc, Cc, 0);
        dw3x3_kernel<<<dim3(Nn / 256, Cc, Bn), blk, 0, stream>>>(S2, kvdw_w, S4, Cc);

        conv1x1v_kernel<8><<<dim3(PGX, 16, Bn), blk, 0, stream>>>(
            S1, kv_w + 128 * 128, Cc, nullptr, nullptr, S2, Cc, Cc, 0);
        dw3x3_kernel<<<dim3(Nn / 256, Cc, Bn), blk, 0, stream>>>(S2, kvdw_w + 128 * 9, S5, Cc);

        // gate (gmid overwrites yn in S1 — yn is dead)
        conv1x1v_kernel<4><<<dim3(PGX, 16, Bn), blk, 0, stream>>>(
            S0, g1_w, Cc, g1_b, nullptr, S1, Cc, 64, 1);
        gate2_kernel<<<dim3(Nn / 256, 1, Bn), blk, 0, stream>>>(S1, g2_w, g2_b, blocksums, 0);
        gate_final_kernel<<<dim3(1), blk, 0, stream>>>(blocksums, dk);

        l2norm_kernel<<<dim3(Cc, 1, Bn), blk, 0, stream>>>(S3);
        l2norm_kernel<<<dim3(Cc, 1, Bn), blk, 0, stream>>>(S4);

        // attn partial reuses S1 (gmid dead after gate2): 2 MiB
        float* partial = S1;
        attn_qk_partial_kernel<<<dim3(NS, HEADS, Bn), blk, 0, stream>>>(S3, S4, partial);
        attn_reduce_kernel<<<dim3(Bn * HEADS), blk, 0, stream>>>(partial, temp, attn);
        topk_softmax_kernel<<<dim3(Bn * HEADS), dim3(16), 0, stream>>>(attn, dk);
        attn_v_kernel<<<dim3(Nn / 256, Cc, Bn), blk, 0, stream>>>(attn, S5, S2);

        conv1x1v_kernel<8><<<dim3(PGX, 16, Bn), blk, 0, stream>>>(
            S2, po_w, Cc, nullptr, x, out, Cc, Cc, 0);

        // ================= Phase B: IEL, BT batches per dispatch ============
        // Layout (overlaps dead phase-A slots): ZN [Bn*CN], then T1/T2/PR
        // each [BT*HN]. BT=4 needs ~287 MiB total; BT=2 fits in 192 MiB.
        const int BT = (ws_size >= TIER0_NEED) ? 4 : 2;
        float* ZN = pool;                       // Bn*CN floats
        float* T1 = pool + Bn * CN;             // BT*HN
        float* T2 = T1 + (size_t)BT * HN;       // BT*HN
        float* PR = T2 + (size_t)BT * HN;       // BT*HN

        ln_kernel<<<dim3(Nn / 256, 1, Bn), blk, 0, stream>>>(out, ln_w, ln_b, ZN);

        for (int b0 = 0; b0 < Bn; b0 += BT) {
            float* znp  = ZN + (size_t)b0 * CN;
            float* outp = out + (size_t)b0 * CN;
            conv1x1v_kernel<20><<<dim3(PGX, 17, BT), blk, 0, stream>>>(
                znp, pin_w, Cc, nullptr, nullptr, T1, Cc, HID, 0);
            conv1x1v_kernel<20><<<dim3(PGX, 17, BT), blk, 0, stream>>>(
                znp, pin_w + (size_t)HID * Cc, Cc, nullptr, nullptr, T2, Cc, HID, 0);
            iel_tail_kernel<<<dim3(64, HID, BT), blk, 0, stream>>>(
                T1, T2, dw_w, dw_w + HID * 9, dw1_w, dw2_w, PR);
            conv1x1v_kernel<8><<<dim3(PGX, 16, BT), blk, 0, stream>>>(
                PR, pout_w, HID, nullptr, outp, outp, HID, Cc, 0);
        }
    } else {
        // ================= Tier 2: per-batch everything (~48 MiB pool) ======
        float* s0 = pool;
        float* s1 = pool + 1 * CN;
        float* s2 = pool + 2 * CN;
        float* s3 = pool + 3 * CN;
        float* s4 = pool + 4 * CN;
        float* s5 = pool + 5 * CN;

        for (int b = 0; b < Bn; ++b) {
            const float* xb = x + (size_t)b * CN;
            ln_kernel<<<dim3(Nn / 256, 1, 1), blk, 0, stream>>>(xb, ln_w, ln_b, s0);
            conv1x1v_kernel<4><<<dim3(PGX, 16, 1), blk, 0, stream>>>(
                s0, g1_w, Cc, g1_b, nullptr, s1, Cc, 64, 1);
            gate2_kernel<<<dim3(Nn / 256, 1, 1), blk, 0, stream>>>(
                s1, g2_w, g2_b, blocksums, b * 64);
        }
        gate_final_kernel<<<dim3(1), blk, 0, stream>>>(blocksums, dk);

        for (int b = 0; b < Bn; ++b) {
            const float* xb = x + (size_t)b * CN;
            const float* yb = y + (size_t)b * CN;
            float* outb = out + (size_t)b * CN;
            float* attnb = attn + (size_t)b * HEADS * CHh * CHh;

            ln_kernel<<<dim3(Nn / 256, 1, 1), blk, 0, stream>>>(xb, ln_w, ln_b, s0);
            ln_kernel<<<dim3(Nn / 256, 1, 1), blk, 0, stream>>>(yb, ln_w, ln_b, s1);

            conv1x1v_kernel<8><<<dim3(PGX, 16, 1), blk, 0, stream>>>(
                s0, q_w, Cc, nullptr, nullptr, s2, Cc, Cc, 0);
            dw3x3_kernel<<<dim3(Nn / 256, Cc, 1), blk, 0, stream>>>(s2, qdw_w, s3, Cc);
            l2norm_kernel<<<dim3(Cc, 1, 1), blk, 0, stream>>>(s3);

            conv1x1v_kernel<8><<<dim3(PGX, 16, 1), blk, 0, stream>>>(
                s1, kv_w, Cc, nullptr, nullptr, s2, Cc, Cc, 0);
            dw3x3_kernel<<<dim3(Nn / 256, Cc, 1), blk, 0, stream>>>(s2, kvdw_w, s4, Cc);
            l2norm_kernel<<<dim3(Cc, 1, 1), blk, 0, stream>>>(s4);

            conv1x1v_kernel<8><<<dim3(PGX, 16, 1), blk, 0, stream>>>(
                s1, kv_w + 128 * 128, Cc, nullptr, nullptr, s2, Cc, Cc, 0);
            dw3x3_kernel<<<dim3(Nn / 256, Cc, 1), blk, 0, stream>>>(s2, kvdw_w + 128 * 9, s5, Cc);

            attn_qk_partial_kernel<<<dim3(NS, HEADS, 1), blk, 0, stream>>>(s3, s4, s2);
            attn_reduce_kernel<<<dim3(HEADS), blk, 0, stream>>>(s2, temp, attnb);
            topk_softmax_kernel<<<dim3(HEADS), dim3(16), 0, stream>>>(attnb, dk);
            attn_v_kernel<<<dim3(Nn / 256, Cc, 1), blk, 0, stream>>>(attnb, s5, s2);

            conv1x1v_kernel<8><<<dim3(PGX, 16, 1), blk, 0, stream>>>(
                s2, po_w, Cc, nullptr, xb, outb, Cc, Cc, 0);
        }

        // IEL pass, 2 channel chunks of 170 (per batch)
        const int CHUNK = 170;
        const size_t TCH = (size_t)CHUNK * Nn;
        float* zn   = pool;            // 8 MiB
        float* T1   = pool + CN;
        float* T2   = T1 + TCH;
        float* prod = T2 + TCH;
        for (int b = 0; b < Bn; ++b) {
            float* outb = out + (size_t)b * CN;
            ln_kernel<<<dim3(Nn / 256, 1, 1), blk, 0, stream>>>(outb, ln_w, ln_b, zn);
            for (int c0 = 0; c0 < HID; c0 += CHUNK) {
                conv1x1v_kernel<20><<<dim3(PGX, 9, 1), blk, 0, stream>>>(
                    zn, pin_w + (size_t)c0 * Cc, Cc, nullptr, nullptr, T1, Cc, CHUNK, 0);
                conv1x1v_kernel<20><<<dim3(PGX, 9, 1), blk, 0, stream>>>(
                    zn, pin_w + (size_t)(HID + c0) * Cc, Cc, nullptr, nullptr, T2, Cc, CHUNK, 0);
                // single-batch iel: strides are c*Nn with HID=CHUNK rows; pass
                // batch-size-1 pointers (b=0) with HID-row layout per chunk
                iel_tail_kernel<<<dim3(64, CHUNK, 1), blk, 0, stream>>>(
                    T1, T2, dw_w + c0 * 9, dw_w + (HID + c0) * 9,
                    dw1_w + c0 * 9, dw2_w + c0 * 9, prod);
                conv1x1v_kernel<8><<<dim3(PGX, 16, 1), blk, 0, stream>>>(
                    prod, pout_w + c0, HID, nullptr, outb, outb, CHUNK, Cc, 0);
            }
        }
    }
}

// Round 6
// 879.229 us; speedup vs baseline: 3.4944x; 1.2327x over previous
//
#include <hip/hip_runtime.h>
#include <math.h>

// Problem constants
static constexpr int Bn    = 4;
static constexpr int Cc    = 128;
static constexpr int Hh    = 128;
static constexpr int Wb    = 128;
static constexpr int Nn    = Hh * Wb;      // 16384
static constexpr int HEADS = 8;
static constexpr int CHh   = 16;           // Cc / HEADS
static constexpr int HID   = 340;
static constexpr int HID2  = 680;
static constexpr int NS    = 64;           // n-splits for attn QK^T
static constexpr int MPAD  = 704;          // pin M padded (680 -> 44*16)
static constexpr int KPAD2 = 352;          // pout K padded (340 -> 11*32)

typedef unsigned short ushort_t;
typedef __attribute__((ext_vector_type(8))) short short8;
typedef __attribute__((ext_vector_type(4))) float f32x4;

__device__ __forceinline__ ushort_t f2bf(float f) {
    unsigned u = __float_as_uint(f);
    return (ushort_t)((u + 0x7FFFu + ((u >> 16) & 1u)) >> 16);   // RNE
}
__device__ __forceinline__ float bf2f(ushort_t h) {
    return __uint_as_float(((unsigned)h) << 16);
}

// ---------------------------------------------------------------------------
// LayerNorm over channel axis, f32 out. grid: (Nn/256, 1, Bt).
// ---------------------------------------------------------------------------
__global__ __launch_bounds__(256) void ln_kernel(const float* __restrict__ in,
                                                 const float* __restrict__ w,
                                                 const float* __restrict__ bias,
                                                 float* __restrict__ out) {
    int p = blockIdx.x * 256 + threadIdx.x;
    int b = blockIdx.z;
    const float* ib = in + (size_t)b * Cc * Nn + p;
    float s = 0.f, s2 = 0.f;
    #pragma unroll 8
    for (int c = 0; c < Cc; ++c) {
        float v = ib[(size_t)c * Nn];
        s += v; s2 += v * v;
    }
    float mean = s * (1.0f / Cc);
    float var  = s2 * (1.0f / Cc) - mean * mean;
    float inv  = 1.0f / sqrtf(var + 1e-6f);
    float* ob = out + (size_t)b * Cc * Nn + p;
    #pragma unroll 8
    for (int c = 0; c < Cc; ++c) {
        float v = ib[(size_t)c * Nn];
        ob[(size_t)c * Nn] = w[c] * ((v - mean) * inv) + bias[c];
    }
}

// LayerNorm writing bf16 (phase B: feeds the MFMA GEMM only).
__global__ __launch_bounds__(256) void ln_bf16_kernel(const float* __restrict__ in,
                                                      const float* __restrict__ w,
                                                      const float* __restrict__ bias,
                                                      ushort_t* __restrict__ out) {
    int p = blockIdx.x * 256 + threadIdx.x;
    int b = blockIdx.z;
    const float* ib = in + (size_t)b * Cc * Nn + p;
    float s = 0.f, s2 = 0.f;
    #pragma unroll 8
    for (int c = 0; c < Cc; ++c) {
        float v = ib[(size_t)c * Nn];
        s += v; s2 += v * v;
    }
    float mean = s * (1.0f / Cc);
    float var  = s2 * (1.0f / Cc) - mean * mean;
    float inv  = 1.0f / sqrtf(var + 1e-6f);
    ushort_t* ob = out + (size_t)b * Cc * Nn + p;
    #pragma unroll 8
    for (int c = 0; c < Cc; ++c) {
        float v = ib[(size_t)c * Nn];
        ob[(size_t)c * Nn] = f2bf(w[c] * ((v - mean) * inv) + bias[c]);
    }
}

// ---------------------------------------------------------------------------
// Weight conversion f32 -> bf16 with padding.
// pin: [680][128] -> [704][128] (zero rows >= 680)
// pout: [128][340] -> [128][352] (zero cols >= 340)
// ---------------------------------------------------------------------------
__global__ __launch_bounds__(256) void wconv_pad_rows_kernel(const float* __restrict__ w,
                                                             ushort_t* __restrict__ o,
                                                             int rows, int K) {
    int idx = blockIdx.x * 256 + threadIdx.x;     // over padded rows * K
    int r = idx / K, k = idx - r * K;
    o[idx] = (r < rows) ? f2bf(w[(size_t)r * K + k]) : (ushort_t)0;
}
__global__ __launch_bounds__(256) void wconv_pad_cols_kernel(const float* __restrict__ w,
                                                             ushort_t* __restrict__ o,
                                                             int K, int Kp) {
    int idx = blockIdx.x * 256 + threadIdx.x;     // over rows * Kp
    int r = idx / Kp, k = idx - r * Kp;
    o[idx] = (k < K) ? f2bf(w[(size_t)r * K + k]) : (ushort_t)0;
}

// ---------------------------------------------------------------------------
// bf16 MFMA GEMM: out[b,co,p] = sum_ci W[co,ci] * Z[b,ci,p]
// Z: bf16 channel-major [Cin][Nn] per batch. W: bf16 [Mpad][Kpad] row-major.
// Block: 256 thr = 4 waves; tile 64co x 64px; wave w handles px sub-tile w*16.
// B staged via LDS (px-major, stride 40 -> conflict-free b128 frag reads).
// A frags read directly from global (16B contiguous, L2-resident).
// C/D layout (verified m89/m91): col = lane&15 (=px), row = quad*4+reg (=co).
// grid: (Nn/64, Mpad/64, Bt)
// ---------------------------------------------------------------------------
__global__ __launch_bounds__(256) void gemm_bf16_kernel(const ushort_t* __restrict__ Zh,
                                                        const ushort_t* __restrict__ Wh,
                                                        const float* res,
                                                        float* outf,
                                                        ushort_t* outh,
                                                        int Cin, int Kpad, int Mreal) {
    const int b    = blockIdx.z;
    const int px0  = blockIdx.x * 64;
    const int co0  = blockIdx.y * 64;
    const int tid  = threadIdx.x;
    const int wv   = tid >> 6;
    const int lane = tid & 63;
    const int n    = lane & 15;
    const int q    = lane >> 4;
    const int px_w = wv * 16;

    __shared__ ushort_t Bl[64][40];   // [px_local][k] padded

    const ushort_t* Zb = Zh + (size_t)b * Cin * Nn;

    f32x4 acc[4];
    #pragma unroll
    for (int i = 0; i < 4; ++i) acc[i] = (f32x4){0.f, 0.f, 0.f, 0.f};

    for (int k0 = 0; k0 < Kpad; k0 += 32) {
        // stage Z[k0..k0+31][px0..px0+63] -> Bl
        {
            int r = tid >> 3;        // k row 0..31
            int s = tid & 7;         // px segment
            int ci = k0 + r;
            ushort_t tmp[8];
            if (ci < Cin) {
                const ushort_t* src = Zb + (size_t)ci * Nn + px0 + s * 8;
                uint4 v = *(const uint4*)src;
                tmp[0] = (ushort_t)(v.x & 0xFFFF); tmp[1] = (ushort_t)(v.x >> 16);
                tmp[2] = (ushort_t)(v.y & 0xFFFF); tmp[3] = (ushort_t)(v.y >> 16);
                tmp[4] = (ushort_t)(v.z & 0xFFFF); tmp[5] = (ushort_t)(v.z >> 16);
                tmp[6] = (ushort_t)(v.w & 0xFFFF); tmp[7] = (ushort_t)(v.w >> 16);
            } else {
                #pragma unroll
                for (int i = 0; i < 8; ++i) tmp[i] = 0;
            }
            #pragma unroll
            for (int i = 0; i < 8; ++i) Bl[s * 8 + i][r] = tmp[i];
        }
        __syncthreads();

        short8 bfrag = *(const short8*)&Bl[px_w + n][q * 8];
        #pragma unroll
        for (int mt = 0; mt < 4; ++mt) {
            const ushort_t* wp = Wh + (size_t)(co0 + mt * 16 + n) * Kpad + k0 + q * 8;
            short8 afrag = *(const short8*)wp;
            acc[mt] = __builtin_amdgcn_mfma_f32_16x16x32_bf16(afrag, bfrag, acc[mt], 0, 0, 0);
        }
        __syncthreads();
    }

    int px = px0 + px_w + n;
    #pragma unroll
    for (int mt = 0; mt < 4; ++mt) {
        #pragma unroll
        for (int reg = 0; reg < 4; ++reg) {
            int co = co0 + mt * 16 + q * 4 + reg;
            if (co < Mreal) {
                float v = acc[mt][reg];
                size_t o = ((size_t)b * Mreal + co) * Nn + px;
                if (res)  v += res[o];
                if (outf) outf[o] = v;
                if (outh) outh[o] = f2bf(v);
            }
        }
    }
}

// ---------------------------------------------------------------------------
// Vectorized f32 1x1 conv (phase A). grid: (Nn/1024, ceil(Cout/TCO), Bt)
// ---------------------------------------------------------------------------
template <int TCO>
__global__ __launch_bounds__(256) void conv1x1v_kernel(const float* __restrict__ in,
                                                       const float* __restrict__ wgt,
                                                       int wstride,
                                                       const float* __restrict__ bias,
                                                       const float* __restrict__ res,
                                                       float* __restrict__ out,
                                                       int Cin, int Cout, int act) {
    int pg  = blockIdx.x * 256 + threadIdx.x;
    int b   = blockIdx.z;
    int co0 = blockIdx.y * TCO;

    const float* wrow[TCO];
    #pragma unroll
    for (int i = 0; i < TCO; ++i) {
        int co = co0 + i; if (co > Cout - 1) co = Cout - 1;
        wrow[i] = wgt + (size_t)co * wstride;
    }

    float4 acc[TCO];
    #pragma unroll
    for (int i = 0; i < TCO; ++i) acc[i] = make_float4(0.f, 0.f, 0.f, 0.f);

    const float* ib = in + (size_t)b * Cin * Nn + (size_t)pg * 4;
    #pragma unroll 8
    for (int ci = 0; ci < Cin; ++ci) {
        float4 v = *(const float4*)(ib + (size_t)ci * Nn);
        #pragma unroll
        for (int i = 0; i < TCO; ++i) {
            float w = wrow[i][ci];
            acc[i].x += v.x * w; acc[i].y += v.y * w;
            acc[i].z += v.z * w; acc[i].w += v.w * w;
        }
    }

    #pragma unroll
    for (int i = 0; i < TCO; ++i) {
        int co = co0 + i;
        if (co < Cout) {
            float4 r = acc[i];
            if (bias) { float bb = bias[co]; r.x += bb; r.y += bb; r.z += bb; r.w += bb; }
            if (act == 1) {
                r.x = fmaxf(r.x, 0.f); r.y = fmaxf(r.y, 0.f);
                r.z = fmaxf(r.z, 0.f); r.w = fmaxf(r.w, 0.f);
            }
            size_t o = ((size_t)b * Cout + co) * Nn + (size_t)pg * 4;
            if (res) {
                float4 rv = *(const float4*)(res + o);
                r.x += rv.x; r.y += rv.y; r.z += rv.z; r.w += rv.w;
            }
            *(float4*)(out + o) = r;
        }
    }
}

// ---------------------------------------------------------------------------
// Depthwise 3x3 conv, pad=1 (f32, phase A). grid: (Nn/256, Ct, Bt).
// ---------------------------------------------------------------------------
__global__ __launch_bounds__(256) void dw3x3_kernel(const float* __restrict__ in,
                                                    const float* __restrict__ w,
                                                    float* __restrict__ out, int Ct) {
    int p = blockIdx.x * 256 + threadIdx.x;
    int c = blockIdx.y;
    int b = blockIdx.z;
    int y = p >> 7, x = p & (Wb - 1);
    const float* ib = in + ((size_t)b * Ct + c) * Nn;
    float wl[9];
    #pragma unroll
    for (int k = 0; k < 9; ++k) wl[k] = w[c * 9 + k];
    float acc = 0.f;
    #pragma unroll
    for (int dy = 0; dy < 3; ++dy) {
        int yy = y + dy - 1;
        if (yy < 0 || yy >= Hh) continue;
        #pragma unroll
        for (int dx = 0; dx < 3; ++dx) {
            int xx = x + dx - 1;
            if (xx < 0 || xx >= Wb) continue;
            acc += wl[dy * 3 + dx] * ib[yy * Wb + xx];
        }
    }
    out[((size_t)b * Ct + c) * Nn + p] = acc;
}

// ---------------------------------------------------------------------------
// L2 normalize along N (in-place). grid: (Cc, 1, Bt).
// ---------------------------------------------------------------------------
__global__ __launch_bounds__(256) void l2norm_kernel(float* __restrict__ data) {
    int b = blockIdx.z, c = blockIdx.x;
    float* ptr = data + ((size_t)b * Cc + c) * Nn;
    int t = threadIdx.x;
    float s = 0.f;
    for (int i = t; i < Nn; i += 256) { float v = ptr[i]; s += v * v; }
    __shared__ float red[256];
    red[t] = s; __syncthreads();
    for (int st = 128; st > 0; st >>= 1) { if (t < st) red[t] += red[t + st]; __syncthreads(); }
    float scale = 1.0f / fmaxf(sqrtf(red[0]), 1e-12f);
    for (int i = t; i < Nn; i += 256) ptr[i] *= scale;
}

// ---------------------------------------------------------------------------
// Gate stage 2 + final (unchanged).
// ---------------------------------------------------------------------------
__global__ __launch_bounds__(256) void gate2_kernel(const float* __restrict__ gmid,
                                                    const float* __restrict__ w2,
                                                    const float* __restrict__ b2,
                                                    float* __restrict__ blocksums,
                                                    int out_off) {
    int p = blockIdx.x * 256 + threadIdx.x;
    int b = blockIdx.z;
    float acc = b2[0];
    const float* ib = gmid + (size_t)b * 64 * Nn + p;
    #pragma unroll 8
    for (int ci = 0; ci < 64; ++ci) acc += ib[(size_t)ci * Nn] * w2[ci];
    float g = 1.0f / (1.0f + expf(-acc));
    __shared__ float red[256];
    int t = threadIdx.x;
    red[t] = g; __syncthreads();
    for (int st = 128; st > 0; st >>= 1) { if (t < st) red[t] += red[t + st]; __syncthreads(); }
    if (t == 0) blocksums[out_off + b * 64 + blockIdx.x] = red[0];
}

__global__ __launch_bounds__(256) void gate_final_kernel(const float* __restrict__ blocksums,
                                                         int* __restrict__ dk_out) {
    __shared__ double sred[256];
    int t = threadIdx.x;
    sred[t] = (double)blocksums[t];
    __syncthreads();
    for (int st = 128; st > 0; st >>= 1) { if (t < st) sred[t] += sred[t + st]; __syncthreads(); }
    if (t == 0) {
        double mean = sred[0] / (double)(Bn * Nn);
        float val = 16.0f * (float)mean;
        int dk = (int)val;
        if (dk < 1) dk = 1;
        if (dk > 16) dk = 16;
        *dk_out = dk;
    }
}

// ---------------------------------------------------------------------------
// QK^T partial + reduce + topk + attn_v (unchanged, f32 -> topk determinism).
// ---------------------------------------------------------------------------
__global__ __launch_bounds__(256) void attn_qk_partial_kernel(const float* __restrict__ q,
                                                              const float* __restrict__ k,
                                                              float* __restrict__ partial) {
    int ns = blockIdx.x, h = blockIdx.y, b = blockIdx.z;
    int t = threadIdx.x;
    int c = t >> 4, d = t & 15;
    __shared__ float qs[16][65];
    __shared__ float ks[16][65];
    const float* qb = q + ((size_t)b * Cc + h * CHh) * Nn;
    const float* kb = k + ((size_t)b * Cc + h * CHh) * Nn;
    float acc = 0.f;
    int nbeg = ns * (Nn / NS);
    for (int n0 = nbeg; n0 < nbeg + (Nn / NS); n0 += 64) {
        for (int idx = t; idx < 1024; idx += 256) {
            int r = idx >> 6, col = idx & 63;
            qs[r][col] = qb[(size_t)r * Nn + n0 + col];
            ks[r][col] = kb[(size_t)r * Nn + n0 + col];
        }
        __syncthreads();
        #pragma unroll
        for (int j = 0; j < 64; ++j) acc += qs[c][j] * ks[d][j];
        __syncthreads();
    }
    partial[(((size_t)(b * HEADS + h)) * NS + ns) * 256 + t] = acc;
}

__global__ __launch_bounds__(256) void attn_reduce_kernel(const float* __restrict__ partial,
                                                          const float* __restrict__ temp,
                                                          float* __restrict__ attnp) {
    int bh = blockIdx.x;
    int h = bh % HEADS;
    int t = threadIdx.x;
    const float* pp = partial + (size_t)bh * NS * 256 + t;
    float s = 0.f;
    #pragma unroll 8
    for (int ns = 0; ns < NS; ++ns) s += pp[(size_t)ns * 256];
    attnp[(size_t)bh * 256 + t] = s * temp[h];
}

__global__ void topk_softmax_kernel(float* __restrict__ attnp, const int* __restrict__ dkp) {
    int bh = blockIdx.x;
    int c = threadIdx.x;
    if (c >= 16) return;
    float* row = attnp + ((size_t)bh * CHh + c) * CHh;
    float a[16];
    #pragma unroll
    for (int d = 0; d < 16; ++d) a[d] = row[d];
    int dk = *dkp;
    unsigned keep = 0;
    float m = -INFINITY;
    #pragma unroll
    for (int d = 0; d < 16; ++d) {
        int rank = 0;
        #pragma unroll
        for (int j = 0; j < 16; ++j)
            rank += (a[j] > a[d]) || (a[j] == a[d] && j < d);
        if (rank < dk) { keep |= (1u << d); m = fmaxf(m, a[d]); }
    }
    float e[16]; float s = 0.f;
    #pragma unroll
    for (int d = 0; d < 16; ++d) {
        e[d] = (keep >> d & 1u) ? expf(a[d] - m) : 0.f;
        s += e[d];
    }
    float invs = 1.0f / s;
    #pragma unroll
    for (int d = 0; d < 16; ++d) row[d] = e[d] * invs;
}

__global__ __launch_bounds__(256) void attn_v_kernel(const float* __restrict__ attnp,
                                                     const float* __restrict__ v,
                                                     float* __restrict__ out) {
    int p = blockIdx.x * 256 + threadIdx.x;
    int cg = blockIdx.y;
    int b = blockIdx.z;
    int h = cg >> 4, cr = cg & 15;
    const float* arow = attnp + (((size_t)b * HEADS + h) * CHh + cr) * CHh;
    const float* vb = v + ((size_t)b * Cc + h * CHh) * Nn + p;
    float acc = 0.f;
    #pragma unroll
    for (int d = 0; d < 16; ++d) acc += arow[d] * vb[(size_t)d * Nn];
    out[((size_t)b * Cc + cg) * Nn + p] = acc;
}

// ---------------------------------------------------------------------------
// Fused IEL tail, bf16 in/out, batched. grid: (64, HID, Bt), block 256.
// Th: [b][680][Nn] bf16 (t1 = ch c, t2 = ch 340+c). PRh: [b][340][Nn] bf16.
// LDS strides padded to 24 (2-way banking only, free on CDNA4).
// ---------------------------------------------------------------------------
__global__ __launch_bounds__(256) void iel_tail_bf16_kernel(const ushort_t* __restrict__ Th,
                                                            const float* __restrict__ dww,
                                                            const float* __restrict__ dw1p,
                                                            const float* __restrict__ dw2p,
                                                            ushort_t* __restrict__ PRh) {
    const int c = blockIdx.y;
    const int b = blockIdx.z;
    const int tilesx = Wb / 16;
    const int ty0 = (blockIdx.x / tilesx) * 16;
    const int tx0 = (blockIdx.x % tilesx) * 16;
    const int tid = threadIdx.x;

    __shared__ float ts[2][20][24];
    __shared__ float us[2][18][24];

    const ushort_t* t1 = Th + ((size_t)b * HID2 + c) * Nn;
    const ushort_t* t2 = Th + ((size_t)b * HID2 + HID + c) * Nn;

    for (int idx = tid; idx < 400; idx += 256) {
        int i = idx / 20, j = idx % 20;
        int gy = ty0 - 2 + i, gx = tx0 - 2 + j;
        bool ok = (gy >= 0 && gy < Hh && gx >= 0 && gx < Wb);
        ts[0][i][j] = ok ? bf2f(t1[gy * Wb + gx]) : 0.f;
        ts[1][i][j] = ok ? bf2f(t2[gy * Wb + gx]) : 0.f;
    }
    __syncthreads();

    float wA[9], wB[9], w1[9], w2[9];
    #pragma unroll
    for (int k = 0; k < 9; ++k) {
        wA[k] = dww[c * 9 + k];
        wB[k] = dww[(HID + c) * 9 + k];
        w1[k] = dw1p[c * 9 + k];
        w2[k] = dw2p[c * 9 + k];
    }

    for (int idx = tid; idx < 324; idx += 256) {
        int i = idx / 18, j = idx % 18;
        int gy = ty0 - 1 + i, gx = tx0 - 1 + j;
        float a0 = 0.f, a1 = 0.f;
        if (gy >= 0 && gy < Hh && gx >= 0 && gx < Wb) {
            #pragma unroll
            for (int dy = 0; dy < 3; ++dy)
                #pragma unroll
                for (int dx = 0; dx < 3; ++dx) {
                    a0 += wA[dy * 3 + dx] * ts[0][i + dy][j + dx];
                    a1 += wB[dy * 3 + dx] * ts[1][i + dy][j + dx];
                }
        }
        us[0][i][j] = a0;
        us[1][i][j] = a1;
    }
    __syncthreads();

    int ty = tid >> 4, tx = tid & 15;
    float c1 = us[0][ty + 1][tx + 1];
    float c2 = us[1][ty + 1][tx + 1];
    float s1 = 0.f, s2 = 0.f;
    #pragma unroll
    for (int dy = 0; dy < 3; ++dy)
        #pragma unroll
        for (int dx = 0; dx < 3; ++dx) {
            s1 += w1[dy * 3 + dx] * us[0][ty + dy][tx + dx];
            s2 += w2[dy * 3 + dx] * us[1][ty + dy][tx + dx];
        }
    float x1t = tanhf(s1) + c1;
    float x2t = tanhf(s2) + c2;
    PRh[((size_t)b * HID + c) * Nn + (ty0 + ty) * Wb + (tx0 + tx)] = f2bf(x1t * x2t);
}

// f32 IEL tail (tier-2 fallback only; per-chunk layout).
__global__ __launch_bounds__(256) void iel_tail_f32_kernel(const float* __restrict__ t1p,
                                                           const float* __restrict__ t2p,
                                                           const float* __restrict__ dwA,
                                                           const float* __restrict__ dwB,
                                                           const float* __restrict__ dw1p,
                                                           const float* __restrict__ dw2p,
                                                           float* __restrict__ prod) {
    const int c = blockIdx.y;
    const int tilesx = Wb / 16;
    const int ty0 = (blockIdx.x / tilesx) * 16;
    const int tx0 = (blockIdx.x % tilesx) * 16;
    const int tid = threadIdx.x;

    __shared__ float ts[2][20][24];
    __shared__ float us[2][18][24];

    const float* t1 = t1p + (size_t)c * Nn;
    const float* t2 = t2p + (size_t)c * Nn;

    for (int idx = tid; idx < 400; idx += 256) {
        int i = idx / 20, j = idx % 20;
        int gy = ty0 - 2 + i, gx = tx0 - 2 + j;
        bool ok = (gy >= 0 && gy < Hh && gx >= 0 && gx < Wb);
        ts[0][i][j] = ok ? t1[gy * Wb + gx] : 0.f;
        ts[1][i][j] = ok ? t2[gy * Wb + gx] : 0.f;
    }
    __syncthreads();

    float wA[9], wB[9], w1[9], w2[9];
    #pragma unroll
    for (int k = 0; k < 9; ++k) {
        wA[k] = dwA[c * 9 + k];
        wB[k] = dwB[c * 9 + k];
        w1[k] = dw1p[c * 9 + k];
        w2[k] = dw2p[c * 9 + k];
    }

    for (int idx = tid; idx < 324; idx += 256) {
        int i = idx / 18, j = idx % 18;
        int gy = ty0 - 1 + i, gx = tx0 - 1 + j;
        float a0 = 0.f, a1 = 0.f;
        if (gy >= 0 && gy < Hh && gx >= 0 && gx < Wb) {
            #pragma unroll
            for (int dy = 0; dy < 3; ++dy)
                #pragma unroll
                for (int dx = 0; dx < 3; ++dx) {
                    a0 += wA[dy * 3 + dx] * ts[0][i + dy][j + dx];
                    a1 += wB[dy * 3 + dx] * ts[1][i + dy][j + dx];
                }
        }
        us[0][i][j] = a0;
        us[1][i][j] = a1;
    }
    __syncthreads();

    int ty = tid >> 4, tx = tid & 15;
    float c1 = us[0][ty + 1][tx + 1];
    float c2 = us[1][ty + 1][tx + 1];
    float s1 = 0.f, s2 = 0.f;
    #pragma unroll
    for (int dy = 0; dy < 3; ++dy)
        #pragma unroll
        for (int dx = 0; dx < 3; ++dx) {
            s1 += w1[dy * 3 + dx] * us[0][ty + dy][tx + dx];
            s2 += w2[dy * 3 + dx] * us[1][ty + dy][tx + dx];
        }
    float x1t = tanhf(s1) + c1;
    float x2t = tanhf(s2) + c2;
    prod[(size_t)c * Nn + (ty0 + ty) * Wb + (tx0 + tx)] = x1t * x2t;
}

// ---------------------------------------------------------------------------
// Host launcher
// ---------------------------------------------------------------------------
extern "C" void kernel_launch(void* const* d_in, const int* in_sizes, int n_in,
                              void* d_out, int out_size, void* d_ws, size_t ws_size,
                              hipStream_t stream) {
    const float* x      = (const float*)d_in[0];
    const float* y      = (const float*)d_in[1];
    const float* ln_w   = (const float*)d_in[2];
    const float* ln_b   = (const float*)d_in[3];
    const float* temp   = (const float*)d_in[4];
    const float* q_w    = (const float*)d_in[5];
    const float* qdw_w  = (const float*)d_in[6];
    const float* kv_w   = (const float*)d_in[7];
    const float* kvdw_w = (const float*)d_in[8];
    const float* po_w   = (const float*)d_in[9];
    const float* g1_w   = (const float*)d_in[10];
    const float* g1_b   = (const float*)d_in[11];
    const float* g2_w   = (const float*)d_in[12];
    const float* g2_b   = (const float*)d_in[13];
    const float* pin_w  = (const float*)d_in[14];
    const float* dw_w   = (const float*)d_in[15];
    const float* dw1_w  = (const float*)d_in[16];
    const float* dw2_w  = (const float*)d_in[17];
    const float* pout_w = (const float*)d_in[18];
    float* out = (float*)d_out;

    char* ws = (char*)d_ws;
    float* attn      = (float*)ws;           // 8192 floats
    float* blocksums = attn + 8192;          // 256 floats
    int*   dk        = (int*)(blocksums + 256);
    float* pool      = (float*)(ws + 65536);

    const size_t CN    = (size_t)Cc * Nn;          // 8 MiB in floats
    const size_t SLOT1 = (size_t)Bn * CN;          // 32 MiB slot
    const size_t TIER1_NEED = 65536 + 6 * SLOT1 * 4;

    dim3 blk(256);
    const int PGX = Nn / 1024;

    if (ws_size >= TIER1_NEED) {
        // ================= Phase A: full-batch (f32, unchanged) =============
        float* S0 = pool;
        float* S1 = pool + 1 * SLOT1;
        float* S2 = pool + 2 * SLOT1;
        float* S3 = pool + 3 * SLOT1;
        float* S4 = pool + 4 * SLOT1;
        float* S5 = pool + 5 * SLOT1;

        ln_kernel<<<dim3(Nn / 256, 1, Bn), blk, 0, stream>>>(x, ln_w, ln_b, S0);
        ln_kernel<<<dim3(Nn / 256, 1, Bn), blk, 0, stream>>>(y, ln_w, ln_b, S1);

        conv1x1v_kernel<8><<<dim3(PGX, 16, Bn), blk, 0, stream>>>(
            S0, q_w, Cc, nullptr, nullptr, S2, Cc, Cc, 0);
        dw3x3_kernel<<<dim3(Nn / 256, Cc, Bn), blk, 0, stream>>>(S2, qdw_w, S3, Cc);

        conv1x1v_kernel<8><<<dim3(PGX, 16, Bn), blk, 0, stream>>>(
            S1, kv_w, Cc, nullptr, nullptr, S2, Cc, Cc, 0);
        dw3x3_kernel<<<dim3(Nn / 256, Cc, Bn), blk, 0, stream>>>(S2, kvdw_w, S4, Cc);

        conv1x1v_kernel<8><<<dim3(PGX, 16, Bn), blk, 0, stream>>>(
            S1, kv_w + 128 * 128, Cc, nullptr, nullptr, S2, Cc, Cc, 0);
        dw3x3_kernel<<<dim3(Nn / 256, Cc, Bn), blk, 0, stream>>>(S2, kvdw_w + 128 * 9, S5, Cc);

        conv1x1v_kernel<4><<<dim3(PGX, 16, Bn), blk, 0, stream>>>(
            S0, g1_w, Cc, g1_b, nullptr, S1, Cc, 64, 1);
        gate2_kernel<<<dim3(Nn / 256, 1, Bn), blk, 0, stream>>>(S1, g2_w, g2_b, blocksums, 0);
        gate_final_kernel<<<dim3(1), blk, 0, stream>>>(blocksums, dk);

        l2norm_kernel<<<dim3(Cc, 1, Bn), blk, 0, stream>>>(S3);
        l2norm_kernel<<<dim3(Cc, 1, Bn), blk, 0, stream>>>(S4);

        float* partial = S1;
        attn_qk_partial_kernel<<<dim3(NS, HEADS, Bn), blk, 0, stream>>>(S3, S4, partial);
        attn_reduce_kernel<<<dim3(Bn * HEADS), blk, 0, stream>>>(partial, temp, attn);
        topk_softmax_kernel<<<dim3(Bn * HEADS), dim3(16), 0, stream>>>(attn, dk);
        attn_v_kernel<<<dim3(Nn / 256, Cc, Bn), blk, 0, stream>>>(attn, S5, S2);

        conv1x1v_kernel<8><<<dim3(PGX, 16, Bn), blk, 0, stream>>>(
            S2, po_w, Cc, nullptr, x, out, Cc, Cc, 0);

        // ================= Phase B: bf16 MFMA pipeline ======================
        // Layout over dead phase-A slots (~144 MiB total):
        ushort_t* ZNh = (ushort_t*)pool;                       // [Bn][128][Nn]
        ushort_t* Th  = ZNh + Bn * CN;                         // [Bn][680][Nn]
        ushort_t* PRh = Th + (size_t)Bn * HID2 * Nn;           // [Bn][340][Nn]
        ushort_t* Wh1 = PRh + (size_t)Bn * HID * Nn;           // [704][128]
        ushort_t* Wh2 = Wh1 + (size_t)MPAD * Cc;               // [128][352]

        wconv_pad_rows_kernel<<<dim3(MPAD * Cc / 256), blk, 0, stream>>>(
            pin_w, Wh1, HID2, Cc);
        wconv_pad_cols_kernel<<<dim3(Cc * KPAD2 / 256), blk, 0, stream>>>(
            pout_w, Wh2, HID, KPAD2);

        ln_bf16_kernel<<<dim3(Nn / 256, 1, Bn), blk, 0, stream>>>(out, ln_w, ln_b, ZNh);

        // pin: [680x128] @ ZNh -> Th (bf16), full batch, one dispatch
        gemm_bf16_kernel<<<dim3(Nn / 64, MPAD / 64, Bn), blk, 0, stream>>>(
            ZNh, Wh1, nullptr, nullptr, Th, Cc, Cc, HID2);

        iel_tail_bf16_kernel<<<dim3(64, HID, Bn), blk, 0, stream>>>(
            Th, dw_w, dw1_w, dw2_w, PRh);

        // pout: [128x340] @ PRh -> out (f32, += residual in-place)
        gemm_bf16_kernel<<<dim3(Nn / 64, 2, Bn), blk, 0, stream>>>(
            PRh, Wh2, out, out, nullptr, HID, KPAD2, Cc);
    } else {
        // ================= Tier 2: per-batch f32 fallback ===================
        float* s0 = pool;
        float* s1 = pool + 1 * CN;
        float* s2 = pool + 2 * CN;
        float* s3 = pool + 3 * CN;
        float* s4 = pool + 4 * CN;
        float* s5 = pool + 5 * CN;

        for (int b = 0; b < Bn; ++b) {
            const float* xb = x + (size_t)b * CN;
            ln_kernel<<<dim3(Nn / 256, 1, 1), blk, 0, stream>>>(xb, ln_w, ln_b, s0);
            conv1x1v_kernel<4><<<dim3(PGX, 16, 1), blk, 0, stream>>>(
                s0, g1_w, Cc, g1_b, nullptr, s1, Cc, 64, 1);
            gate2_kernel<<<dim3(Nn / 256, 1, 1), blk, 0, stream>>>(
                s1, g2_w, g2_b, blocksums, b * 64);
        }
        gate_final_kernel<<<dim3(1), blk, 0, stream>>>(blocksums, dk);

        for (int b = 0; b < Bn; ++b) {
            const float* xb = x + (size_t)b * CN;
            const float* yb = y + (size_t)b * CN;
            float* outb = out + (size_t)b * CN;
            float* attnb = attn + (size_t)b * HEADS * CHh * CHh;

            ln_kernel<<<dim3(Nn / 256, 1, 1), blk, 0, stream>>>(xb, ln_w, ln_b, s0);
            ln_kernel<<<dim3(Nn / 256, 1, 1), blk, 0, stream>>>(yb, ln_w, ln_b, s1);

            conv1x1v_kernel<8><<<dim3(PGX, 16, 1), blk, 0, stream>>>(
                s0, q_w, Cc, nullptr, nullptr, s2, Cc, Cc, 0);
            dw3x3_kernel<<<dim3(Nn / 256, Cc, 1), blk, 0, stream>>>(s2, qdw_w, s3, Cc);
            l2norm_kernel<<<dim3(Cc, 1, 1), blk, 0, stream>>>(s3);

            conv1x1v_kernel<8><<<dim3(PGX, 16, 1), blk, 0, stream>>>(
                s1, kv_w, Cc, nullptr, nullptr, s2, Cc, Cc, 0);
            dw3x3_kernel<<<dim3(Nn / 256, Cc, 1), blk, 0, stream>>>(s2, kvdw_w, s4, Cc);
            l2norm_kernel<<<dim3(Cc, 1, 1), blk, 0, stream>>>(s4);

            conv1x1v_kernel<8><<<dim3(PGX, 16, 1), blk, 0, stream>>>(
                s1, kv_w + 128 * 128, Cc, nullptr, nullptr, s2, Cc, Cc, 0);
            dw3x3_kernel<<<dim3(Nn / 256, Cc, 1), blk, 0, stream>>>(s2, kvdw_w + 128 * 9, s5, Cc);

            attn_qk_partial_kernel<<<dim3(NS, HEADS, 1), blk, 0, stream>>>(s3, s4, s2);
            attn_reduce_kernel<<<dim3(HEADS), blk, 0, stream>>>(s2, temp, attnb);
            topk_softmax_kernel<<<dim3(HEADS), dim3(16), 0, stream>>>(attnb, dk);
            attn_v_kernel<<<dim3(Nn / 256, Cc, 1), blk, 0, stream>>>(attnb, s5, s2);

            conv1x1v_kernel<8><<<dim3(PGX, 16, 1), blk, 0, stream>>>(
                s2, po_w, Cc, nullptr, xb, outb, Cc, Cc, 0);
        }

        const int CHUNK = 170;
        const size_t TCH = (size_t)CHUNK * Nn;
        float* zn   = pool;
        float* T1   = pool + CN;
        float* T2   = T1 + TCH;
        float* prod = T2 + TCH;
        for (int b = 0; b < Bn; ++b) {
            float* outb = out + (size_t)b * CN;
            ln_kernel<<<dim3(Nn / 256, 1, 1), blk, 0, stream>>>(outb, ln_w, ln_b, zn);
            for (int c0 = 0; c0 < HID; c0 += CHUNK) {
                conv1x1v_kernel<20><<<dim3(PGX, 9, 1), blk, 0, stream>>>(
                    zn, pin_w + (size_t)c0 * Cc, Cc, nullptr, nullptr, T1, Cc, CHUNK, 0);
                conv1x1v_kernel<20><<<dim3(PGX, 9, 1), blk, 0, stream>>>(
                    zn, pin_w + (size_t)(HID + c0) * Cc, Cc, nullptr, nullptr, T2, Cc, CHUNK, 0);
                iel_tail_f32_kernel<<<dim3(64, CHUNK, 1), blk, 0, stream>>>(
                    T1, T2, dw_w + c0 * 9, dw_w + (HID + c0) * 9,
                    dw1_w + c0 * 9, dw2_w + c0 * 9, prod);
                conv1x1v_kernel<8><<<dim3(PGX, 16, 1), blk, 0, stream>>>(
                    prod, pout_w + c0, HID, nullptr, outb, outb, CHUNK, Cc, 0);
            }
        }
    }
}

// Round 7
// 787.712 us; speedup vs baseline: 3.9004x; 1.1162x over previous
//
#include <hip/hip_runtime.h>
#include <math.h>

// Problem constants
static constexpr int Bn    = 4;
static constexpr int Cc    = 128;
static constexpr int Hh    = 128;
static constexpr int Wb    = 128;
static constexpr int Nn    = Hh * Wb;      // 16384
static constexpr int HEADS = 8;
static constexpr int CHh   = 16;
static constexpr int HID   = 340;
static constexpr int HID2  = 680;
static constexpr int NS    = 64;
static constexpr int MPAD  = 704;          // pin M padded (680 -> 44*16)
static constexpr int KPAD2 = 352;          // pout K padded (340 -> 11*32)

typedef unsigned short ushort_t;
typedef __attribute__((ext_vector_type(8))) short short8;
typedef __attribute__((ext_vector_type(4))) float f32x4;

__device__ __forceinline__ ushort_t f2bf(float f) {
    unsigned u = __float_as_uint(f);
    return (ushort_t)((u + 0x7FFFu + ((u >> 16) & 1u)) >> 16);   // RNE
}
__device__ __forceinline__ float bf2f(ushort_t h) {
    return __uint_as_float(((unsigned)h) << 16);
}

// ---------------------------------------------------------------------------
// LayerNorm over channel axis, f32 out (tier-2). grid: (Nn/256, 1, Bt).
// ---------------------------------------------------------------------------
__global__ __launch_bounds__(256) void ln_kernel(const float* __restrict__ in,
                                                 const float* __restrict__ w,
                                                 const float* __restrict__ bias,
                                                 float* __restrict__ out) {
    int p = blockIdx.x * 256 + threadIdx.x;
    int b = blockIdx.z;
    const float* ib = in + (size_t)b * Cc * Nn + p;
    float s = 0.f, s2 = 0.f;
    #pragma unroll 8
    for (int c = 0; c < Cc; ++c) {
        float v = ib[(size_t)c * Nn];
        s += v; s2 += v * v;
    }
    float mean = s * (1.0f / Cc);
    float var  = s2 * (1.0f / Cc) - mean * mean;
    float inv  = 1.0f / sqrtf(var + 1e-6f);
    float* ob = out + (size_t)b * Cc * Nn + p;
    #pragma unroll 8
    for (int c = 0; c < Cc; ++c) {
        float v = ib[(size_t)c * Nn];
        ob[(size_t)c * Nn] = w[c] * ((v - mean) * inv) + bias[c];
    }
}

// LayerNorm writing bf16 (feeds MFMA GEMMs).
__global__ __launch_bounds__(256) void ln_bf16_kernel(const float* __restrict__ in,
                                                      const float* __restrict__ w,
                                                      const float* __restrict__ bias,
                                                      ushort_t* __restrict__ out) {
    int p = blockIdx.x * 256 + threadIdx.x;
    int b = blockIdx.z;
    const float* ib = in + (size_t)b * Cc * Nn + p;
    float s = 0.f, s2 = 0.f;
    #pragma unroll 8
    for (int c = 0; c < Cc; ++c) {
        float v = ib[(size_t)c * Nn];
        s += v; s2 += v * v;
    }
    float mean = s * (1.0f / Cc);
    float var  = s2 * (1.0f / Cc) - mean * mean;
    float inv  = 1.0f / sqrtf(var + 1e-6f);
    ushort_t* ob = out + (size_t)b * Cc * Nn + p;
    #pragma unroll 8
    for (int c = 0; c < Cc; ++c) {
        float v = ib[(size_t)c * Nn];
        ob[(size_t)c * Nn] = f2bf(w[c] * ((v - mean) * inv) + bias[c]);
    }
}

// ---------------------------------------------------------------------------
// Weight conversion f32 -> bf16 (+ padding variants).
// ---------------------------------------------------------------------------
__global__ __launch_bounds__(256) void wconv_pad_rows_kernel(const float* __restrict__ w,
                                                             ushort_t* __restrict__ o,
                                                             int rows, int K) {
    int idx = blockIdx.x * 256 + threadIdx.x;
    int r = idx / K, k = idx - r * K;
    o[idx] = (r < rows) ? f2bf(w[(size_t)r * K + k]) : (ushort_t)0;
}
__global__ __launch_bounds__(256) void wconv_pad_cols_kernel(const float* __restrict__ w,
                                                             ushort_t* __restrict__ o,
                                                             int K, int Kp) {
    int idx = blockIdx.x * 256 + threadIdx.x;
    int r = idx / Kp, k = idx - r * Kp;
    o[idx] = (k < K) ? f2bf(w[(size_t)r * K + k]) : (ushort_t)0;
}

// ---------------------------------------------------------------------------
// bf16 MFMA GEMM: out[b,co,p] = sum_ci W[co,ci] * Z[b,ci,p] (+bias,relu,res)
// Z: bf16 [Cin][Nn] per batch (batch stride Cin*Nn). W: bf16 [M][Kpad].
// Tile 64co x 64px, 4 waves. C/D layout verified (m89/m91).
// grid: (Nn/64, ceil(M/64), Bt)
// ---------------------------------------------------------------------------
__global__ __launch_bounds__(256) void gemm_bf16_kernel(const ushort_t* __restrict__ Zh,
                                                        const ushort_t* __restrict__ Wh,
                                                        const float* __restrict__ bias,
                                                        const float* __restrict__ res,
                                                        float* outf,
                                                        ushort_t* outh,
                                                        int Cin, int Kpad, int Mreal,
                                                        int act) {
    const int b    = blockIdx.z;
    const int px0  = blockIdx.x * 64;
    const int co0  = blockIdx.y * 64;
    const int tid  = threadIdx.x;
    const int wv   = tid >> 6;
    const int lane = tid & 63;
    const int n    = lane & 15;
    const int q    = lane >> 4;
    const int px_w = wv * 16;

    __shared__ ushort_t Bl[64][40];

    const ushort_t* Zb = Zh + (size_t)b * Cin * Nn;

    f32x4 acc[4];
    #pragma unroll
    for (int i = 0; i < 4; ++i) acc[i] = (f32x4){0.f, 0.f, 0.f, 0.f};

    for (int k0 = 0; k0 < Kpad; k0 += 32) {
        {
            int r = tid >> 3;
            int s = tid & 7;
            int ci = k0 + r;
            ushort_t tmp[8];
            if (ci < Cin) {
                const ushort_t* src = Zb + (size_t)ci * Nn + px0 + s * 8;
                uint4 v = *(const uint4*)src;
                tmp[0] = (ushort_t)(v.x & 0xFFFF); tmp[1] = (ushort_t)(v.x >> 16);
                tmp[2] = (ushort_t)(v.y & 0xFFFF); tmp[3] = (ushort_t)(v.y >> 16);
                tmp[4] = (ushort_t)(v.z & 0xFFFF); tmp[5] = (ushort_t)(v.z >> 16);
                tmp[6] = (ushort_t)(v.w & 0xFFFF); tmp[7] = (ushort_t)(v.w >> 16);
            } else {
                #pragma unroll
                for (int i = 0; i < 8; ++i) tmp[i] = 0;
            }
            #pragma unroll
            for (int i = 0; i < 8; ++i) Bl[s * 8 + i][r] = tmp[i];
        }
        __syncthreads();

        short8 bfrag = *(const short8*)&Bl[px_w + n][q * 8];
        #pragma unroll
        for (int mt = 0; mt < 4; ++mt) {
            const ushort_t* wp = Wh + (size_t)(co0 + mt * 16 + n) * Kpad + k0 + q * 8;
            short8 afrag = *(const short8*)wp;
            acc[mt] = __builtin_amdgcn_mfma_f32_16x16x32_bf16(afrag, bfrag, acc[mt], 0, 0, 0);
        }
        __syncthreads();
    }

    int px = px0 + px_w + n;
    #pragma unroll
    for (int mt = 0; mt < 4; ++mt) {
        #pragma unroll
        for (int reg = 0; reg < 4; ++reg) {
            int co = co0 + mt * 16 + q * 4 + reg;
            if (co < Mreal) {
                float v = acc[mt][reg];
                if (bias) v += bias[co];
                if (act == 1) v = fmaxf(v, 0.f);
                size_t o = ((size_t)b * Mreal + co) * Nn + px;
                if (res)  v += res[o];
                if (outf) outf[o] = v;
                if (outh) outh[o] = f2bf(v);
            }
        }
    }
}

// ---------------------------------------------------------------------------
// Vectorized f32 1x1 conv (tier-2 only).
// ---------------------------------------------------------------------------
template <int TCO>
__global__ __launch_bounds__(256) void conv1x1v_kernel(const float* __restrict__ in,
                                                       const float* __restrict__ wgt,
                                                       int wstride,
                                                       const float* __restrict__ bias,
                                                       const float* __restrict__ res,
                                                       float* __restrict__ out,
                                                       int Cin, int Cout, int act) {
    int pg  = blockIdx.x * 256 + threadIdx.x;
    int b   = blockIdx.z;
    int co0 = blockIdx.y * TCO;

    const float* wrow[TCO];
    #pragma unroll
    for (int i = 0; i < TCO; ++i) {
        int co = co0 + i; if (co > Cout - 1) co = Cout - 1;
        wrow[i] = wgt + (size_t)co * wstride;
    }

    float4 acc[TCO];
    #pragma unroll
    for (int i = 0; i < TCO; ++i) acc[i] = make_float4(0.f, 0.f, 0.f, 0.f);

    const float* ib = in + (size_t)b * Cin * Nn + (size_t)pg * 4;
    #pragma unroll 8
    for (int ci = 0; ci < Cin; ++ci) {
        float4 v = *(const float4*)(ib + (size_t)ci * Nn);
        #pragma unroll
        for (int i = 0; i < TCO; ++i) {
            float w = wrow[i][ci];
            acc[i].x += v.x * w; acc[i].y += v.y * w;
            acc[i].z += v.z * w; acc[i].w += v.w * w;
        }
    }

    #pragma unroll
    for (int i = 0; i < TCO; ++i) {
        int co = co0 + i;
        if (co < Cout) {
            float4 r = acc[i];
            if (bias) { float bb = bias[co]; r.x += bb; r.y += bb; r.z += bb; r.w += bb; }
            if (act == 1) {
                r.x = fmaxf(r.x, 0.f); r.y = fmaxf(r.y, 0.f);
                r.z = fmaxf(r.z, 0.f); r.w = fmaxf(r.w, 0.f);
            }
            size_t o = ((size_t)b * Cout + co) * Nn + (size_t)pg * 4;
            if (res) {
                float4 rv = *(const float4*)(res + o);
                r.x += rv.x; r.y += rv.y; r.z += rv.z; r.w += rv.w;
            }
            *(float4*)(out + o) = r;
        }
    }
}

// ---------------------------------------------------------------------------
// Depthwise 3x3, pad=1. f32 (tier-2) and bf16-in/f32-out variants.
// grid: (Nn/256, Ct, Bt). Batch stride = Ct*Nn.
// ---------------------------------------------------------------------------
__global__ __launch_bounds__(256) void dw3x3_kernel(const float* __restrict__ in,
                                                    const float* __restrict__ w,
                                                    float* __restrict__ out, int Ct) {
    int p = blockIdx.x * 256 + threadIdx.x;
    int c = blockIdx.y;
    int b = blockIdx.z;
    int y = p >> 7, x = p & (Wb - 1);
    const float* ib = in + ((size_t)b * Ct + c) * Nn;
    float wl[9];
    #pragma unroll
    for (int k = 0; k < 9; ++k) wl[k] = w[c * 9 + k];
    float acc = 0.f;
    #pragma unroll
    for (int dy = 0; dy < 3; ++dy) {
        int yy = y + dy - 1;
        if (yy < 0 || yy >= Hh) continue;
        #pragma unroll
        for (int dx = 0; dx < 3; ++dx) {
            int xx = x + dx - 1;
            if (xx < 0 || xx >= Wb) continue;
            acc += wl[dy * 3 + dx] * ib[yy * Wb + xx];
        }
    }
    out[((size_t)b * Ct + c) * Nn + p] = acc;
}

__global__ __launch_bounds__(256) void dw3x3_bf16_kernel(const ushort_t* __restrict__ in,
                                                         const float* __restrict__ w,
                                                         float* __restrict__ out, int Ct) {
    int p = blockIdx.x * 256 + threadIdx.x;
    int c = blockIdx.y;
    int b = blockIdx.z;
    int y = p >> 7, x = p & (Wb - 1);
    const ushort_t* ib = in + ((size_t)b * Ct + c) * Nn;
    float wl[9];
    #pragma unroll
    for (int k = 0; k < 9; ++k) wl[k] = w[c * 9 + k];
    float acc = 0.f;
    #pragma unroll
    for (int dy = 0; dy < 3; ++dy) {
        int yy = y + dy - 1;
        if (yy < 0 || yy >= Hh) continue;
        #pragma unroll
        for (int dx = 0; dx < 3; ++dx) {
            int xx = x + dx - 1;
            if (xx < 0 || xx >= Wb) continue;
            acc += wl[dy * 3 + dx] * bf2f(ib[yy * Wb + xx]);
        }
    }
    out[((size_t)b * Ct + c) * Nn + p] = acc;
}

// ---------------------------------------------------------------------------
// L2 normalize along N (in-place). cstride = channels per batch in buffer.
// grid: (Cc, 1, Bt).
// ---------------------------------------------------------------------------
__global__ __launch_bounds__(256) void l2norm_kernel(float* __restrict__ data, int cstride) {
    int b = blockIdx.z, c = blockIdx.x;
    float* ptr = data + ((size_t)b * cstride + c) * Nn;
    int t = threadIdx.x;
    float s = 0.f;
    for (int i = t; i < Nn; i += 256) { float v = ptr[i]; s += v * v; }
    __shared__ float red[256];
    red[t] = s; __syncthreads();
    for (int st = 128; st > 0; st >>= 1) { if (t < st) red[t] += red[t + st]; __syncthreads(); }
    float scale = 1.0f / fmaxf(sqrtf(red[0]), 1e-12f);
    for (int i = t; i < Nn; i += 256) ptr[i] *= scale;
}

// ---------------------------------------------------------------------------
// Gate stage 2 + final.
// ---------------------------------------------------------------------------
__global__ __launch_bounds__(256) void gate2_kernel(const float* __restrict__ gmid,
                                                    const float* __restrict__ w2,
                                                    const float* __restrict__ b2,
                                                    float* __restrict__ blocksums,
                                                    int out_off) {
    int p = blockIdx.x * 256 + threadIdx.x;
    int b = blockIdx.z;
    float acc = b2[0];
    const float* ib = gmid + (size_t)b * 64 * Nn + p;
    #pragma unroll 8
    for (int ci = 0; ci < 64; ++ci) acc += ib[(size_t)ci * Nn] * w2[ci];
    float g = 1.0f / (1.0f + expf(-acc));
    __shared__ float red[256];
    int t = threadIdx.x;
    red[t] = g; __syncthreads();
    for (int st = 128; st > 0; st >>= 1) { if (t < st) red[t] += red[t + st]; __syncthreads(); }
    if (t == 0) blocksums[out_off + b * 64 + blockIdx.x] = red[0];
}

__global__ __launch_bounds__(256) void gate_final_kernel(const float* __restrict__ blocksums,
                                                         int* __restrict__ dk_out) {
    __shared__ double sred[256];
    int t = threadIdx.x;
    sred[t] = (double)blocksums[t];
    __syncthreads();
    for (int st = 128; st > 0; st >>= 1) { if (t < st) sred[t] += sred[t + st]; __syncthreads(); }
    if (t == 0) {
        double mean = sred[0] / (double)(Bn * Nn);
        float val = 16.0f * (float)mean;
        int dk = (int)val;
        if (dk < 1) dk = 1;
        if (dk > 16) dk = 16;
        *dk_out = dk;
    }
}

// ---------------------------------------------------------------------------
// QK^T partial (f32). kstride = channels per batch in k buffer.
// grid: (NS, HEADS, Bt).
// ---------------------------------------------------------------------------
__global__ __launch_bounds__(256) void attn_qk_partial_kernel(const float* __restrict__ q,
                                                              const float* __restrict__ k,
                                                              int kstride,
                                                              float* __restrict__ partial) {
    int ns = blockIdx.x, h = blockIdx.y, b = blockIdx.z;
    int t = threadIdx.x;
    int c = t >> 4, d = t & 15;
    __shared__ float qs[16][65];
    __shared__ float ks[16][65];
    const float* qb = q + ((size_t)b * Cc + h * CHh) * Nn;
    const float* kb = k + ((size_t)b * kstride + h * CHh) * Nn;
    float acc = 0.f;
    int nbeg = ns * (Nn / NS);
    for (int n0 = nbeg; n0 < nbeg + (Nn / NS); n0 += 64) {
        for (int idx = t; idx < 1024; idx += 256) {
            int r = idx >> 6, col = idx & 63;
            qs[r][col] = qb[(size_t)r * Nn + n0 + col];
            ks[r][col] = kb[(size_t)r * Nn + n0 + col];
        }
        __syncthreads();
        #pragma unroll
        for (int j = 0; j < 64; ++j) acc += qs[c][j] * ks[d][j];
        __syncthreads();
    }
    partial[(((size_t)(b * HEADS + h)) * NS + ns) * 256 + t] = acc;
}

__global__ __launch_bounds__(256) void attn_reduce_kernel(const float* __restrict__ partial,
                                                          const float* __restrict__ temp,
                                                          float* __restrict__ attnp) {
    int bh = blockIdx.x;
    int h = bh % HEADS;
    int t = threadIdx.x;
    const float* pp = partial + (size_t)bh * NS * 256 + t;
    float s = 0.f;
    #pragma unroll 8
    for (int ns = 0; ns < NS; ++ns) s += pp[(size_t)ns * 256];
    attnp[(size_t)bh * 256 + t] = s * temp[h];
}

__global__ void topk_softmax_kernel(float* __restrict__ attnp, const int* __restrict__ dkp) {
    int bh = blockIdx.x;
    int c = threadIdx.x;
    if (c >= 16) return;
    float* row = attnp + ((size_t)bh * CHh + c) * CHh;
    float a[16];
    #pragma unroll
    for (int d = 0; d < 16; ++d) a[d] = row[d];
    int dk = *dkp;
    unsigned keep = 0;
    float m = -INFINITY;
    #pragma unroll
    for (int d = 0; d < 16; ++d) {
        int rank = 0;
        #pragma unroll
        for (int j = 0; j < 16; ++j)
            rank += (a[j] > a[d]) || (a[j] == a[d] && j < d);
        if (rank < dk) { keep |= (1u << d); m = fmaxf(m, a[d]); }
    }
    float e[16]; float s = 0.f;
    #pragma unroll
    for (int d = 0; d < 16; ++d) {
        e[d] = (keep >> d & 1u) ? expf(a[d] - m) : 0.f;
        s += e[d];
    }
    float invs = 1.0f / s;
    #pragma unroll
    for (int d = 0; d < 16; ++d) row[d] = e[d] * invs;
}

// attn_v: f32 out (tier-2)
__global__ __launch_bounds__(256) void attn_v_kernel(const float* __restrict__ attnp,
                                                     const float* __restrict__ v,
                                                     float* __restrict__ out) {
    int p = blockIdx.x * 256 + threadIdx.x;
    int cg = blockIdx.y;
    int b = blockIdx.z;
    int h = cg >> 4, cr = cg & 15;
    const float* arow = attnp + (((size_t)b * HEADS + h) * CHh + cr) * CHh;
    const float* vb = v + ((size_t)b * Cc + h * CHh) * Nn + p;
    float acc = 0.f;
    #pragma unroll
    for (int d = 0; d < 16; ++d) acc += arow[d] * vb[(size_t)d * Nn];
    out[((size_t)b * Cc + cg) * Nn + p] = acc;
}

// attn_v: bf16 out, v buffer has vstride channels/batch with +voff offset.
__global__ __launch_bounds__(256) void attn_v_bf16_kernel(const float* __restrict__ attnp,
                                                          const float* __restrict__ v,
                                                          int vstride, int voff,
                                                          ushort_t* __restrict__ out) {
    int p = blockIdx.x * 256 + threadIdx.x;
    int cg = blockIdx.y;
    int b = blockIdx.z;
    int h = cg >> 4, cr = cg & 15;
    const float* arow = attnp + (((size_t)b * HEADS + h) * CHh + cr) * CHh;
    const float* vb = v + ((size_t)b * vstride + voff + h * CHh) * Nn + p;
    float acc = 0.f;
    #pragma unroll
    for (int d = 0; d < 16; ++d) acc += arow[d] * vb[(size_t)d * Nn];
    out[((size_t)b * Cc + cg) * Nn + p] = f2bf(acc);
}

// ---------------------------------------------------------------------------
// Fused IEL tail v3: full-width tiles 128x16, halo 2, bf16 in/out.
// Th: [b][680][Nn] bf16 (t1 = ch c, t2 = ch 340+c). PRh: [b][340][Nn] bf16.
// ts cols 0..131 <-> gx -2..129 (pads zero); us cols 0..129 <-> gx -1..128.
// grid: (Hh/16, HID, Bt), block 256. LDS ~39 KB.
// ---------------------------------------------------------------------------
__global__ __launch_bounds__(256) void iel_tail_v3_kernel(const ushort_t* __restrict__ Th,
                                                          const float* __restrict__ dww,
                                                          const float* __restrict__ dw1p,
                                                          const float* __restrict__ dw2p,
                                                          ushort_t* __restrict__ PRh) {
    const int gy0 = blockIdx.x * 16;
    const int c   = blockIdx.y;
    const int b   = blockIdx.z;
    const int tid = threadIdx.x;

    __shared__ float ts[2][20][132];
    __shared__ float us[2][18][130];

    const ushort_t* t1 = Th + ((size_t)b * HID2 + c) * Nn;
    const ushort_t* t2 = Th + ((size_t)b * HID2 + HID + c) * Nn;

    // stage: 2 tensors x 20 rows x 16 segs of 8 px (vector loads)
    for (int idx = tid; idx < 640; idx += 256) {
        int ti  = idx / 320;
        int rem = idx - ti * 320;
        int i   = rem >> 4;          // row 0..19
        int seg = rem & 15;          // 8-px segment
        int gy  = gy0 - 2 + i;
        const ushort_t* tp = ti ? t2 : t1;
        float vals[8];
        if (gy >= 0 && gy < Hh) {
            uint4 v = *(const uint4*)(tp + gy * Wb + seg * 8);
            vals[0] = bf2f((ushort_t)(v.x & 0xFFFF)); vals[1] = bf2f((ushort_t)(v.x >> 16));
            vals[2] = bf2f((ushort_t)(v.y & 0xFFFF)); vals[3] = bf2f((ushort_t)(v.y >> 16));
            vals[4] = bf2f((ushort_t)(v.z & 0xFFFF)); vals[5] = bf2f((ushort_t)(v.z >> 16));
            vals[6] = bf2f((ushort_t)(v.w & 0xFFFF)); vals[7] = bf2f((ushort_t)(v.w >> 16));
        } else {
            #pragma unroll
            for (int k = 0; k < 8; ++k) vals[k] = 0.f;
        }
        #pragma unroll
        for (int k = 0; k < 8; ++k) ts[ti][i][2 + seg * 8 + k] = vals[k];
        if (seg == 0)  { ts[ti][i][0] = 0.f; ts[ti][i][1] = 0.f; }
        if (seg == 15) { ts[ti][i][130] = 0.f; ts[ti][i][131] = 0.f; }
    }
    __syncthreads();

    float wA[9], wB[9], w1[9], w2[9];
    #pragma unroll
    for (int k = 0; k < 9; ++k) {
        wA[k] = dww[c * 9 + k];
        wB[k] = dww[(HID + c) * 9 + k];
        w1[k] = dw1p[c * 9 + k];
        w2[k] = dw2p[c * 9 + k];
    }

    // u = dw(t): 2 x 18 x 130 (zero outside image)
    for (int idx = tid; idx < 4680; idx += 256) {
        int ti  = idx / 2340;
        int rem = idx - ti * 2340;
        int i   = rem / 130;         // row: gy = gy0-1+i
        int j   = rem - i * 130;     // col: gx = j-1
        int gy  = gy0 - 1 + i;
        int gx  = j - 1;
        float a = 0.f;
        if (gy >= 0 && gy < Hh && gx >= 0 && gx < Wb) {
            const float* wp = ti ? wB : wA;
            #pragma unroll
            for (int dy = 0; dy < 3; ++dy)
                #pragma unroll
                for (int dx = 0; dx < 3; ++dx)
                    a += wp[dy * 3 + dx] * ts[ti][i + dy][j + dx];
        }
        us[ti][i][j] = a;
    }
    __syncthreads();

    // final: x = tid&127 (stride-1 lanes -> conflict-free), 8 rows per thread
    int x    = tid & 127;
    int half = tid >> 7;
    ushort_t* outp = PRh + ((size_t)b * HID + c) * Nn;
    #pragma unroll
    for (int rr = 0; rr < 8; ++rr) {
        int r = half * 8 + rr;       // row in tile, gy = gy0 + r
        float c1 = us[0][r + 1][x + 1];
        float c2 = us[1][r + 1][x + 1];
        float s1 = 0.f, s2 = 0.f;
        #pragma unroll
        for (int dy = 0; dy < 3; ++dy)
            #pragma unroll
            for (int dx = 0; dx < 3; ++dx) {
                s1 += w1[dy * 3 + dx] * us[0][r + dy][x + dx];
                s2 += w2[dy * 3 + dx] * us[1][r + dy][x + dx];
            }
        float x1t = tanhf(s1) + c1;
        float x2t = tanhf(s2) + c2;
        outp[(gy0 + r) * Wb + x] = f2bf(x1t * x2t);
    }
}

// f32 IEL tail (tier-2 fallback; per-chunk layout).
__global__ __launch_bounds__(256) void iel_tail_f32_kernel(const float* __restrict__ t1p,
                                                           const float* __restrict__ t2p,
                                                           const float* __restrict__ dwA,
                                                           const float* __restrict__ dwB,
                                                           const float* __restrict__ dw1p,
                                                           const float* __restrict__ dw2p,
                                                           float* __restrict__ prod) {
    const int c = blockIdx.y;
    const int tilesx = Wb / 16;
    const int ty0 = (blockIdx.x / tilesx) * 16;
    const int tx0 = (blockIdx.x % tilesx) * 16;
    const int tid = threadIdx.x;

    __shared__ float ts[2][20][24];
    __shared__ float us[2][18][24];

    const float* t1 = t1p + (size_t)c * Nn;
    const float* t2 = t2p + (size_t)c * Nn;

    for (int idx = tid; idx < 400; idx += 256) {
        int i = idx / 20, j = idx % 20;
        int gy = ty0 - 2 + i, gx = tx0 - 2 + j;
        bool ok = (gy >= 0 && gy < Hh && gx >= 0 && gx < Wb);
        ts[0][i][j] = ok ? t1[gy * Wb + gx] : 0.f;
        ts[1][i][j] = ok ? t2[gy * Wb + gx] : 0.f;
    }
    __syncthreads();

    float wA[9], wB[9], w1[9], w2[9];
    #pragma unroll
    for (int k = 0; k < 9; ++k) {
        wA[k] = dwA[c * 9 + k];
        wB[k] = dwB[c * 9 + k];
        w1[k] = dw1p[c * 9 + k];
        w2[k] = dw2p[c * 9 + k];
    }

    for (int idx = tid; idx < 324; idx += 256) {
        int i = idx / 18, j = idx % 18;
        int gy = ty0 - 1 + i, gx = tx0 - 1 + j;
        float a0 = 0.f, a1 = 0.f;
        if (gy >= 0 && gy < Hh && gx >= 0 && gx < Wb) {
            #pragma unroll
            for (int dy = 0; dy < 3; ++dy)
                #pragma unroll
                for (int dx = 0; dx < 3; ++dx) {
                    a0 += wA[dy * 3 + dx] * ts[0][i + dy][j + dx];
                    a1 += wB[dy * 3 + dx] * ts[1][i + dy][j + dx];
                }
        }
        us[0][i][j] = a0;
        us[1][i][j] = a1;
    }
    __syncthreads();

    int ty = tid >> 4, tx = tid & 15;
    float c1 = us[0][ty + 1][tx + 1];
    float c2 = us[1][ty + 1][tx + 1];
    float s1 = 0.f, s2 = 0.f;
    #pragma unroll
    for (int dy = 0; dy < 3; ++dy)
        #pragma unroll
        for (int dx = 0; dx < 3; ++dx) {
            s1 += w1[dy * 3 + dx] * us[0][ty + dy][tx + dx];
            s2 += w2[dy * 3 + dx] * us[1][ty + dy][tx + dx];
        }
    float x1t = tanhf(s1) + c1;
    float x2t = tanhf(s2) + c2;
    prod[(size_t)c * Nn + (ty0 + ty) * Wb + (tx0 + tx)] = x1t * x2t;
}

// ---------------------------------------------------------------------------
// Host launcher
// ---------------------------------------------------------------------------
extern "C" void kernel_launch(void* const* d_in, const int* in_sizes, int n_in,
                              void* d_out, int out_size, void* d_ws, size_t ws_size,
                              hipStream_t stream) {
    const float* x      = (const float*)d_in[0];
    const float* y      = (const float*)d_in[1];
    const float* ln_w   = (const float*)d_in[2];
    const float* ln_b   = (const float*)d_in[3];
    const float* temp   = (const float*)d_in[4];
    const float* q_w    = (const float*)d_in[5];
    const float* qdw_w  = (const float*)d_in[6];
    const float* kv_w   = (const float*)d_in[7];
    const float* kvdw_w = (const float*)d_in[8];
    const float* po_w   = (const float*)d_in[9];
    const float* g1_w   = (const float*)d_in[10];
    const float* g1_b   = (const float*)d_in[11];
    const float* g2_w   = (const float*)d_in[12];
    const float* g2_b   = (const float*)d_in[13];
    const float* pin_w  = (const float*)d_in[14];
    const float* dw_w   = (const float*)d_in[15];
    const float* dw1_w  = (const float*)d_in[16];
    const float* dw2_w  = (const float*)d_in[17];
    const float* pout_w = (const float*)d_in[18];
    float* out = (float*)d_out;

    // smalls in first 1 MiB
    char* ws = (char*)d_ws;
    float* attn      = (float*)ws;                        // 32 KB
    float* blocksums = (float*)(ws + 32768);              // 1 KB
    int*   dk        = (int*)(ws + 33792);
    ushort_t* qWh  = (ushort_t*)(ws + 34816);             // 128x128
    ushort_t* kvWh = qWh + 16384;                         // 256x128
    ushort_t* poWh = kvWh + 32768;                        // 128x128
    ushort_t* g1Wh = poWh + 16384;                        // 64x128
    ushort_t* Wh1  = g1Wh + 8192;                         // 704x128
    ushort_t* Wh2  = Wh1 + (size_t)MPAD * Cc;             // 128x352
    float* pool    = (float*)(ws + (1u << 20));

    const size_t CN    = (size_t)Cc * Nn;                 // floats per 128-ch batch
    const size_t SLOT1 = (size_t)Bn * CN;
    const size_t TIER1_NEED = 65536 + 6 * SLOT1 * 4;      // same threshold as r4-r6

    dim3 blk(256);
    const int PGX = Nn / 1024;

    if (ws_size >= TIER1_NEED) {
        // ---- buffers (peak 176 MiB + 1 MiB smalls) ----
        float* S3 = pool;                                  // q2 f32 [B][128][Nn]
        float* S4 = pool + 8 * 1024 * 1024;                // k2+v2 f32 [B][256][Nn] (64 MiB)
        ushort_t* XNh  = (ushort_t*)(pool + 24 * 1024 * 1024);  // [B][128][Nn] bf16
        ushort_t* YNh  = XNh + Bn * CN;
        ushort_t* KV1h = YNh + Bn * CN;                    // [B][256][Nn] bf16
        ushort_t* Q1h  = KV1h + 2 * Bn * CN;               // [B][128][Nn] bf16
        float* gmid    = (float*)Q1h;                      // reuse after dw(q)
        float* partial = gmid;                             // reuse after gate2
        ushort_t* AOh  = XNh;                              // reuse after gate gemm

        // weight conversions
        wconv_pad_rows_kernel<<<dim3(64), blk, 0, stream>>>(q_w, qWh, 128, Cc);
        wconv_pad_rows_kernel<<<dim3(128), blk, 0, stream>>>(kv_w, kvWh, 256, Cc);
        wconv_pad_rows_kernel<<<dim3(64), blk, 0, stream>>>(po_w, poWh, 128, Cc);
        wconv_pad_rows_kernel<<<dim3(32), blk, 0, stream>>>(g1_w, g1Wh, 64, Cc);
        wconv_pad_rows_kernel<<<dim3(MPAD * Cc / 256), blk, 0, stream>>>(pin_w, Wh1, HID2, Cc);
        wconv_pad_cols_kernel<<<dim3(Cc * KPAD2 / 256), blk, 0, stream>>>(pout_w, Wh2, HID, KPAD2);

        // ---- Phase A ----
        ln_bf16_kernel<<<dim3(Nn / 256, 1, Bn), blk, 0, stream>>>(x, ln_w, ln_b, XNh);
        ln_bf16_kernel<<<dim3(Nn / 256, 1, Bn), blk, 0, stream>>>(y, ln_w, ln_b, YNh);

        // q = qdw(q_w @ xn)
        gemm_bf16_kernel<<<dim3(Nn / 64, 2, Bn), blk, 0, stream>>>(
            XNh, qWh, nullptr, nullptr, nullptr, Q1h, Cc, Cc, Cc, 0);
        dw3x3_bf16_kernel<<<dim3(Nn / 256, Cc, Bn), blk, 0, stream>>>(Q1h, qdw_w, S3, Cc);

        // kv = kvdw(kv_w @ yn): 256 channels in one buffer (k=0-127, v=128-255)
        gemm_bf16_kernel<<<dim3(Nn / 64, 4, Bn), blk, 0, stream>>>(
            YNh, kvWh, nullptr, nullptr, nullptr, KV1h, Cc, Cc, 2 * Cc, 0);
        dw3x3_bf16_kernel<<<dim3(Nn / 256, 2 * Cc, Bn), blk, 0, stream>>>(KV1h, kvdw_w, S4, 2 * Cc);

        // gate: gmid = relu(g1 @ xn + b1); Q1h dead -> gmid
        gemm_bf16_kernel<<<dim3(Nn / 64, 1, Bn), blk, 0, stream>>>(
            XNh, g1Wh, g1_b, nullptr, gmid, nullptr, Cc, Cc, 64, 1);
        gate2_kernel<<<dim3(Nn / 256, 1, Bn), blk, 0, stream>>>(gmid, g2_w, g2_b, blocksums, 0);
        gate_final_kernel<<<dim3(1), blk, 0, stream>>>(blocksums, dk);

        l2norm_kernel<<<dim3(Cc, 1, Bn), blk, 0, stream>>>(S3, Cc);       // q rows
        l2norm_kernel<<<dim3(Cc, 1, Bn), blk, 0, stream>>>(S4, 2 * Cc);   // k rows (0-127)

        attn_qk_partial_kernel<<<dim3(NS, HEADS, Bn), blk, 0, stream>>>(S3, S4, 2 * Cc, partial);
        attn_reduce_kernel<<<dim3(Bn * HEADS), blk, 0, stream>>>(partial, temp, attn);
        topk_softmax_kernel<<<dim3(Bn * HEADS), dim3(16), 0, stream>>>(attn, dk);
        attn_v_bf16_kernel<<<dim3(Nn / 256, Cc, Bn), blk, 0, stream>>>(
            attn, S4, 2 * Cc, Cc, AOh);

        // x_scab = x + po @ attn_out  -> out (f32)
        gemm_bf16_kernel<<<dim3(Nn / 64, 2, Bn), blk, 0, stream>>>(
            AOh, poWh, nullptr, x, out, nullptr, Cc, Cc, Cc, 0);

        // ---- Phase B (bf16 MFMA + fused tail) ----
        ushort_t* ZNh = (ushort_t*)pool;                   // [B][128][Nn]
        ushort_t* Th  = ZNh + Bn * CN;                     // [B][680][Nn]
        ushort_t* PRh = Th + (size_t)Bn * HID2 * Nn;       // [B][340][Nn]

        ln_bf16_kernel<<<dim3(Nn / 256, 1, Bn), blk, 0, stream>>>(out, ln_w, ln_b, ZNh);

        gemm_bf16_kernel<<<dim3(Nn / 64, MPAD / 64, Bn), blk, 0, stream>>>(
            ZNh, Wh1, nullptr, nullptr, nullptr, Th, Cc, Cc, HID2, 0);

        iel_tail_v3_kernel<<<dim3(Hh / 16, HID, Bn), blk, 0, stream>>>(
            Th, dw_w, dw1_w, dw2_w, PRh);

        gemm_bf16_kernel<<<dim3(Nn / 64, 2, Bn), blk, 0, stream>>>(
            PRh, Wh2, nullptr, out, out, nullptr, HID, KPAD2, Cc, 0);
    } else {
        // ================= Tier 2: per-batch f32 fallback ===================
        float* s0 = pool;
        float* s1 = pool + 1 * CN;
        float* s2 = pool + 2 * CN;
        float* s3 = pool + 3 * CN;
        float* s4 = pool + 4 * CN;
        float* s5 = pool + 5 * CN;

        for (int b = 0; b < Bn; ++b) {
            const float* xb = x + (size_t)b * CN;
            ln_kernel<<<dim3(Nn / 256, 1, 1), blk, 0, stream>>>(xb, ln_w, ln_b, s0);
            conv1x1v_kernel<4><<<dim3(PGX, 16, 1), blk, 0, stream>>>(
                s0, g1_w, Cc, g1_b, nullptr, s1, Cc, 64, 1);
            gate2_kernel<<<dim3(Nn / 256, 1, 1), blk, 0, stream>>>(
                s1, g2_w, g2_b, blocksums, b * 64);
        }
        gate_final_kernel<<<dim3(1), blk, 0, stream>>>(blocksums, dk);

        for (int b = 0; b < Bn; ++b) {
            const float* xb = x + (size_t)b * CN;
            const float* yb = y + (size_t)b * CN;
            float* outb = out + (size_t)b * CN;
            float* attnb = attn + (size_t)b * HEADS * CHh * CHh;

            ln_kernel<<<dim3(Nn / 256, 1, 1), blk, 0, stream>>>(xb, ln_w, ln_b, s0);
            ln_kernel<<<dim3(Nn / 256, 1, 1), blk, 0, stream>>>(yb, ln_w, ln_b, s1);

            conv1x1v_kernel<8><<<dim3(PGX, 16, 1), blk, 0, stream>>>(
                s0, q_w, Cc, nullptr, nullptr, s2, Cc, Cc, 0);
            dw3x3_kernel<<<dim3(Nn / 256, Cc, 1), blk, 0, stream>>>(s2, qdw_w, s3, Cc);
            l2norm_kernel<<<dim3(Cc, 1, 1), blk, 0, stream>>>(s3, Cc);

            conv1x1v_kernel<8><<<dim3(PGX, 16, 1), blk, 0, stream>>>(
                s1, kv_w, Cc, nullptr, nullptr, s2, Cc, Cc, 0);
            dw3x3_kernel<<<dim3(Nn / 256, Cc, 1), blk, 0, stream>>>(s2, kvdw_w, s4, Cc);
            l2norm_kernel<<<dim3(Cc, 1, 1), blk, 0, stream>>>(s4, Cc);

            conv1x1v_kernel<8><<<dim3(PGX, 16, 1), blk, 0, stream>>>(
                s1, kv_w + 128 * 128, Cc, nullptr, nullptr, s2, Cc, Cc, 0);
            dw3x3_kernel<<<dim3(Nn / 256, Cc, 1), blk, 0, stream>>>(s2, kvdw_w + 128 * 9, s5, Cc);

            attn_qk_partial_kernel<<<dim3(NS, HEADS, 1), blk, 0, stream>>>(s3, s4, Cc, s2);
            attn_reduce_kernel<<<dim3(HEADS), blk, 0, stream>>>(s2, temp, attnb);
            topk_softmax_kernel<<<dim3(HEADS), dim3(16), 0, stream>>>(attnb, dk);
            attn_v_kernel<<<dim3(Nn / 256, Cc, 1), blk, 0, stream>>>(attnb, s5, s2);

            conv1x1v_kernel<8><<<dim3(PGX, 16, 1), blk, 0, stream>>>(
                s2, po_w, Cc, nullptr, xb, outb, Cc, Cc, 0);
        }

        const int CHUNK = 170;
        const size_t TCH = (size_t)CHUNK * Nn;
        float* zn   = pool;
        float* T1   = pool + CN;
        float* T2   = T1 + TCH;
        float* prod = T2 + TCH;
        for (int b = 0; b < Bn; ++b) {
            float* outb = out + (size_t)b * CN;
            ln_kernel<<<dim3(Nn / 256, 1, 1), blk, 0, stream>>>(outb, ln_w, ln_b, zn);
            for (int c0 = 0; c0 < HID; c0 += CHUNK) {
                conv1x1v_kernel<20><<<dim3(PGX, 9, 1), blk, 0, stream>>>(
                    zn, pin_w + (size_t)c0 * Cc, Cc, nullptr, nullptr, T1, Cc, CHUNK, 0);
                conv1x1v_kernel<20><<<dim3(PGX, 9, 1), blk, 0, stream>>>(
                    zn, pin_w + (size_t)(HID + c0) * Cc, Cc, nullptr, nullptr, T2, Cc, CHUNK, 0);
                iel_tail_f32_kernel<<<dim3(64, CHUNK, 1), blk, 0, stream>>>(
                    T1, T2, dw_w + c0 * 9, dw_w + (HID + c0) * 9,
                    dw1_w + c0 * 9, dw2_w + c0 * 9, prod);
                conv1x1v_kernel<8><<<dim3(PGX, 16, 1), blk, 0, stream>>>(
                    prod, pout_w + c0, HID, nullptr, outb, outb, CHUNK, Cc, 0);
            }
        }
    }
}

// Round 8
// 720.221 us; speedup vs baseline: 4.2659x; 1.0937x over previous
//
#include <hip/hip_runtime.h>
#include <math.h>

// Problem constants
static constexpr int Bn    = 4;
static constexpr int Cc    = 128;
static constexpr int Hh    = 128;
static constexpr int Wb    = 128;
static constexpr int Nn    = Hh * Wb;      // 16384
static constexpr int HEADS = 8;
static constexpr int CHh   = 16;
static constexpr int HID   = 340;
static constexpr int HID2  = 680;
static constexpr int NS    = 64;
static constexpr int MPAD  = 704;          // pin M padded (680 -> 44*16)
static constexpr int KPAD2 = 352;          // pout K padded (340 -> 11*32)

typedef unsigned short ushort_t;
typedef __attribute__((ext_vector_type(8))) short short8;
typedef __attribute__((ext_vector_type(4))) float f32x4;

__device__ __forceinline__ ushort_t f2bf(float f) {
    unsigned u = __float_as_uint(f);
    return (ushort_t)((u + 0x7FFFu + ((u >> 16) & 1u)) >> 16);   // RNE
}
__device__ __forceinline__ float bf2f(ushort_t h) {
    return __uint_as_float(((unsigned)h) << 16);
}

// ---------------------------------------------------------------------------
// LayerNorm over channel axis, f32 out (tier-2). grid: (Nn/256, 1, Bt).
// ---------------------------------------------------------------------------
__global__ __launch_bounds__(256) void ln_kernel(const float* __restrict__ in,
                                                 const float* __restrict__ w,
                                                 const float* __restrict__ bias,
                                                 float* __restrict__ out) {
    int p = blockIdx.x * 256 + threadIdx.x;
    int b = blockIdx.z;
    const float* ib = in + (size_t)b * Cc * Nn + p;
    float s = 0.f, s2 = 0.f;
    #pragma unroll 8
    for (int c = 0; c < Cc; ++c) {
        float v = ib[(size_t)c * Nn];
        s += v; s2 += v * v;
    }
    float mean = s * (1.0f / Cc);
    float var  = s2 * (1.0f / Cc) - mean * mean;
    float inv  = 1.0f / sqrtf(var + 1e-6f);
    float* ob = out + (size_t)b * Cc * Nn + p;
    #pragma unroll 8
    for (int c = 0; c < Cc; ++c) {
        float v = ib[(size_t)c * Nn];
        ob[(size_t)c * Nn] = w[c] * ((v - mean) * inv) + bias[c];
    }
}

// LayerNorm writing bf16 (feeds MFMA GEMMs).
__global__ __launch_bounds__(256) void ln_bf16_kernel(const float* __restrict__ in,
                                                      const float* __restrict__ w,
                                                      const float* __restrict__ bias,
                                                      ushort_t* __restrict__ out) {
    int p = blockIdx.x * 256 + threadIdx.x;
    int b = blockIdx.z;
    const float* ib = in + (size_t)b * Cc * Nn + p;
    float s = 0.f, s2 = 0.f;
    #pragma unroll 8
    for (int c = 0; c < Cc; ++c) {
        float v = ib[(size_t)c * Nn];
        s += v; s2 += v * v;
    }
    float mean = s * (1.0f / Cc);
    float var  = s2 * (1.0f / Cc) - mean * mean;
    float inv  = 1.0f / sqrtf(var + 1e-6f);
    ushort_t* ob = out + (size_t)b * Cc * Nn + p;
    #pragma unroll 8
    for (int c = 0; c < Cc; ++c) {
        float v = ib[(size_t)c * Nn];
        ob[(size_t)c * Nn] = f2bf(w[c] * ((v - mean) * inv) + bias[c]);
    }
}

// ---------------------------------------------------------------------------
// Weight conversion f32 -> bf16 (+ padding variants).
// ---------------------------------------------------------------------------
__global__ __launch_bounds__(256) void wconv_pad_rows_kernel(const float* __restrict__ w,
                                                             ushort_t* __restrict__ o,
                                                             int rows, int K) {
    int idx = blockIdx.x * 256 + threadIdx.x;
    int r = idx / K, k = idx - r * K;
    o[idx] = (r < rows) ? f2bf(w[(size_t)r * K + k]) : (ushort_t)0;
}
__global__ __launch_bounds__(256) void wconv_pad_cols_kernel(const float* __restrict__ w,
                                                             ushort_t* __restrict__ o,
                                                             int K, int Kp) {
    int idx = blockIdx.x * 256 + threadIdx.x;
    int r = idx / Kp, k = idx - r * Kp;
    o[idx] = (k < K) ? f2bf(w[(size_t)r * K + k]) : (ushort_t)0;
}

// ---------------------------------------------------------------------------
// bf16 MFMA GEMM v2: out[b,co,p] = sum_ci W[co,ci] * Z[b,ci,p]
// Tile 64co x 128px, 4 waves; wave handles 32 px (2 sub-tiles of 16).
// grid: (Nn/128, ceil(M/64), Bt)
// ---------------------------------------------------------------------------
__global__ __launch_bounds__(256) void gemm_bf16_kernel(const ushort_t* __restrict__ Zh,
                                                        const ushort_t* __restrict__ Wh,
                                                        const float* __restrict__ bias,
                                                        const float* __restrict__ res,
                                                        float* outf,
                                                        ushort_t* outh,
                                                        int Cin, int Kpad, int Mreal,
                                                        int act) {
    const int b    = blockIdx.z;
    const int px0  = blockIdx.x * 128;
    const int co0  = blockIdx.y * 64;
    const int tid  = threadIdx.x;
    const int wv   = tid >> 6;
    const int lane = tid & 63;
    const int n    = lane & 15;
    const int q    = lane >> 4;

    __shared__ ushort_t Bl[128][40];

    const ushort_t* Zb = Zh + (size_t)b * Cin * Nn;

    f32x4 acc[4][2];
    #pragma unroll
    for (int i = 0; i < 4; ++i)
        #pragma unroll
        for (int j = 0; j < 2; ++j) acc[i][j] = (f32x4){0.f, 0.f, 0.f, 0.f};

    for (int k0 = 0; k0 < Kpad; k0 += 32) {
        // stage Z[k0..k0+31][px0..px0+127] -> Bl
        {
            int r = tid >> 3;        // k row 0..31
            int s = tid & 7;         // 16-px chunk
            int ci = k0 + r;
            ushort_t tmp[16];
            if (ci < Cin) {
                const ushort_t* src = Zb + (size_t)ci * Nn + px0 + s * 16;
                uint4 v0 = *(const uint4*)src;
                uint4 v1 = *(const uint4*)(src + 8);
                tmp[0]  = (ushort_t)(v0.x & 0xFFFF); tmp[1]  = (ushort_t)(v0.x >> 16);
                tmp[2]  = (ushort_t)(v0.y & 0xFFFF); tmp[3]  = (ushort_t)(v0.y >> 16);
                tmp[4]  = (ushort_t)(v0.z & 0xFFFF); tmp[5]  = (ushort_t)(v0.z >> 16);
                tmp[6]  = (ushort_t)(v0.w & 0xFFFF); tmp[7]  = (ushort_t)(v0.w >> 16);
                tmp[8]  = (ushort_t)(v1.x & 0xFFFF); tmp[9]  = (ushort_t)(v1.x >> 16);
                tmp[10] = (ushort_t)(v1.y & 0xFFFF); tmp[11] = (ushort_t)(v1.y >> 16);
                tmp[12] = (ushort_t)(v1.z & 0xFFFF); tmp[13] = (ushort_t)(v1.z >> 16);
                tmp[14] = (ushort_t)(v1.w & 0xFFFF); tmp[15] = (ushort_t)(v1.w >> 16);
            } else {
                #pragma unroll
                for (int i = 0; i < 16; ++i) tmp[i] = 0;
            }
            #pragma unroll
            for (int i = 0; i < 16; ++i) Bl[s * 16 + i][r] = tmp[i];
        }
        __syncthreads();

        short8 bfrag[2];
        #pragma unroll
        for (int px16 = 0; px16 < 2; ++px16)
            bfrag[px16] = *(const short8*)&Bl[wv * 32 + px16 * 16 + n][q * 8];
        #pragma unroll
        for (int mt = 0; mt < 4; ++mt) {
            const ushort_t* wp = Wh + (size_t)(co0 + mt * 16 + n) * Kpad + k0 + q * 8;
            short8 afrag = *(const short8*)wp;
            #pragma unroll
            for (int px16 = 0; px16 < 2; ++px16)
                acc[mt][px16] = __builtin_amdgcn_mfma_f32_16x16x32_bf16(
                    afrag, bfrag[px16], acc[mt][px16], 0, 0, 0);
        }
        __syncthreads();
    }

    #pragma unroll
    for (int px16 = 0; px16 < 2; ++px16) {
        int px = px0 + wv * 32 + px16 * 16 + n;
        #pragma unroll
        for (int mt = 0; mt < 4; ++mt) {
            #pragma unroll
            for (int reg = 0; reg < 4; ++reg) {
                int co = co0 + mt * 16 + q * 4 + reg;
                if (co < Mreal) {
                    float v = acc[mt][px16][reg];
                    if (bias) v += bias[co];
                    if (act == 1) v = fmaxf(v, 0.f);
                    size_t o = ((size_t)b * Mreal + co) * Nn + px;
                    if (res)  v += res[o];
                    if (outf) outf[o] = v;
                    if (outh) outh[o] = f2bf(v);
                }
            }
        }
    }
}

// ---------------------------------------------------------------------------
// Vectorized f32 1x1 conv (tier-2 only).
// ---------------------------------------------------------------------------
template <int TCO>
__global__ __launch_bounds__(256) void conv1x1v_kernel(const float* __restrict__ in,
                                                       const float* __restrict__ wgt,
                                                       int wstride,
                                                       const float* __restrict__ bias,
                                                       const float* __restrict__ res,
                                                       float* __restrict__ out,
                                                       int Cin, int Cout, int act) {
    int pg  = blockIdx.x * 256 + threadIdx.x;
    int b   = blockIdx.z;
    int co0 = blockIdx.y * TCO;

    const float* wrow[TCO];
    #pragma unroll
    for (int i = 0; i < TCO; ++i) {
        int co = co0 + i; if (co > Cout - 1) co = Cout - 1;
        wrow[i] = wgt + (size_t)co * wstride;
    }

    float4 acc[TCO];
    #pragma unroll
    for (int i = 0; i < TCO; ++i) acc[i] = make_float4(0.f, 0.f, 0.f, 0.f);

    const float* ib = in + (size_t)b * Cin * Nn + (size_t)pg * 4;
    #pragma unroll 8
    for (int ci = 0; ci < Cin; ++ci) {
        float4 v = *(const float4*)(ib + (size_t)ci * Nn);
        #pragma unroll
        for (int i = 0; i < TCO; ++i) {
            float w = wrow[i][ci];
            acc[i].x += v.x * w; acc[i].y += v.y * w;
            acc[i].z += v.z * w; acc[i].w += v.w * w;
        }
    }

    #pragma unroll
    for (int i = 0; i < TCO; ++i) {
        int co = co0 + i;
        if (co < Cout) {
            float4 r = acc[i];
            if (bias) { float bb = bias[co]; r.x += bb; r.y += bb; r.z += bb; r.w += bb; }
            if (act == 1) {
                r.x = fmaxf(r.x, 0.f); r.y = fmaxf(r.y, 0.f);
                r.z = fmaxf(r.z, 0.f); r.w = fmaxf(r.w, 0.f);
            }
            size_t o = ((size_t)b * Cout + co) * Nn + (size_t)pg * 4;
            if (res) {
                float4 rv = *(const float4*)(res + o);
                r.x += rv.x; r.y += rv.y; r.z += rv.z; r.w += rv.w;
            }
            *(float4*)(out + o) = r;
        }
    }
}

// ---------------------------------------------------------------------------
// Depthwise 3x3, pad=1. f32 (tier-2) and bf16-in/f32-out variants.
// ---------------------------------------------------------------------------
__global__ __launch_bounds__(256) void dw3x3_kernel(const float* __restrict__ in,
                                                    const float* __restrict__ w,
                                                    float* __restrict__ out, int Ct) {
    int p = blockIdx.x * 256 + threadIdx.x;
    int c = blockIdx.y;
    int b = blockIdx.z;
    int y = p >> 7, x = p & (Wb - 1);
    const float* ib = in + ((size_t)b * Ct + c) * Nn;
    float wl[9];
    #pragma unroll
    for (int k = 0; k < 9; ++k) wl[k] = w[c * 9 + k];
    float acc = 0.f;
    #pragma unroll
    for (int dy = 0; dy < 3; ++dy) {
        int yy = y + dy - 1;
        if (yy < 0 || yy >= Hh) continue;
        #pragma unroll
        for (int dx = 0; dx < 3; ++dx) {
            int xx = x + dx - 1;
            if (xx < 0 || xx >= Wb) continue;
            acc += wl[dy * 3 + dx] * ib[yy * Wb + xx];
        }
    }
    out[((size_t)b * Ct + c) * Nn + p] = acc;
}

__global__ __launch_bounds__(256) void dw3x3_bf16_kernel(const ushort_t* __restrict__ in,
                                                         const float* __restrict__ w,
                                                         float* __restrict__ out, int Ct) {
    int p = blockIdx.x * 256 + threadIdx.x;
    int c = blockIdx.y;
    int b = blockIdx.z;
    int y = p >> 7, x = p & (Wb - 1);
    const ushort_t* ib = in + ((size_t)b * Ct + c) * Nn;
    float wl[9];
    #pragma unroll
    for (int k = 0; k < 9; ++k) wl[k] = w[c * 9 + k];
    float acc = 0.f;
    #pragma unroll
    for (int dy = 0; dy < 3; ++dy) {
        int yy = y + dy - 1;
        if (yy < 0 || yy >= Hh) continue;
        #pragma unroll
        for (int dx = 0; dx < 3; ++dx) {
            int xx = x + dx - 1;
            if (xx < 0 || xx >= Wb) continue;
            acc += wl[dy * 3 + dx] * bf2f(ib[yy * Wb + xx]);
        }
    }
    out[((size_t)b * Ct + c) * Nn + p] = acc;
}

// ---------------------------------------------------------------------------
// L2 normalize along N (in-place). grid: (Cc, 1, Bt).
// ---------------------------------------------------------------------------
__global__ __launch_bounds__(256) void l2norm_kernel(float* __restrict__ data, int cstride) {
    int b = blockIdx.z, c = blockIdx.x;
    float* ptr = data + ((size_t)b * cstride + c) * Nn;
    int t = threadIdx.x;
    float s = 0.f;
    for (int i = t; i < Nn; i += 256) { float v = ptr[i]; s += v * v; }
    __shared__ float red[256];
    red[t] = s; __syncthreads();
    for (int st = 128; st > 0; st >>= 1) { if (t < st) red[t] += red[t + st]; __syncthreads(); }
    float scale = 1.0f / fmaxf(sqrtf(red[0]), 1e-12f);
    for (int i = t; i < Nn; i += 256) ptr[i] *= scale;
}

// ---------------------------------------------------------------------------
// Gate stage 2 + final.
// ---------------------------------------------------------------------------
__global__ __launch_bounds__(256) void gate2_kernel(const float* __restrict__ gmid,
                                                    const float* __restrict__ w2,
                                                    const float* __restrict__ b2,
                                                    float* __restrict__ blocksums,
                                                    int out_off) {
    int p = blockIdx.x * 256 + threadIdx.x;
    int b = blockIdx.z;
    float acc = b2[0];
    const float* ib = gmid + (size_t)b * 64 * Nn + p;
    #pragma unroll 8
    for (int ci = 0; ci < 64; ++ci) acc += ib[(size_t)ci * Nn] * w2[ci];
    float g = 1.0f / (1.0f + expf(-acc));
    __shared__ float red[256];
    int t = threadIdx.x;
    red[t] = g; __syncthreads();
    for (int st = 128; st > 0; st >>= 1) { if (t < st) red[t] += red[t + st]; __syncthreads(); }
    if (t == 0) blocksums[out_off + b * 64 + blockIdx.x] = red[0];
}

__global__ __launch_bounds__(256) void gate_final_kernel(const float* __restrict__ blocksums,
                                                         int* __restrict__ dk_out) {
    __shared__ double sred[256];
    int t = threadIdx.x;
    sred[t] = (double)blocksums[t];
    __syncthreads();
    for (int st = 128; st > 0; st >>= 1) { if (t < st) sred[t] += sred[t + st]; __syncthreads(); }
    if (t == 0) {
        double mean = sred[0] / (double)(Bn * Nn);
        float val = 16.0f * (float)mean;
        int dk = (int)val;
        if (dk < 1) dk = 1;
        if (dk > 16) dk = 16;
        *dk_out = dk;
    }
}

// ---------------------------------------------------------------------------
// QK^T partial (f32). grid: (NS, HEADS, Bt).
// ---------------------------------------------------------------------------
__global__ __launch_bounds__(256) void attn_qk_partial_kernel(const float* __restrict__ q,
                                                              const float* __restrict__ k,
                                                              int kstride,
                                                              float* __restrict__ partial) {
    int ns = blockIdx.x, h = blockIdx.y, b = blockIdx.z;
    int t = threadIdx.x;
    int c = t >> 4, d = t & 15;
    __shared__ float qs[16][65];
    __shared__ float ks[16][65];
    const float* qb = q + ((size_t)b * Cc + h * CHh) * Nn;
    const float* kb = k + ((size_t)b * kstride + h * CHh) * Nn;
    float acc = 0.f;
    int nbeg = ns * (Nn / NS);
    for (int n0 = nbeg; n0 < nbeg + (Nn / NS); n0 += 64) {
        for (int idx = t; idx < 1024; idx += 256) {
            int r = idx >> 6, col = idx & 63;
            qs[r][col] = qb[(size_t)r * Nn + n0 + col];
            ks[r][col] = kb[(size_t)r * Nn + n0 + col];
        }
        __syncthreads();
        #pragma unroll
        for (int j = 0; j < 64; ++j) acc += qs[c][j] * ks[d][j];
        __syncthreads();
    }
    partial[(((size_t)(b * HEADS + h)) * NS + ns) * 256 + t] = acc;
}

__global__ __launch_bounds__(256) void attn_reduce_kernel(const float* __restrict__ partial,
                                                          const float* __restrict__ temp,
                                                          float* __restrict__ attnp) {
    int bh = blockIdx.x;
    int h = bh % HEADS;
    int t = threadIdx.x;
    const float* pp = partial + (size_t)bh * NS * 256 + t;
    float s = 0.f;
    #pragma unroll 8
    for (int ns = 0; ns < NS; ++ns) s += pp[(size_t)ns * 256];
    attnp[(size_t)bh * 256 + t] = s * temp[h];
}

__global__ void topk_softmax_kernel(float* __restrict__ attnp, const int* __restrict__ dkp) {
    int bh = blockIdx.x;
    int c = threadIdx.x;
    if (c >= 16) return;
    float* row = attnp + ((size_t)bh * CHh + c) * CHh;
    float a[16];
    #pragma unroll
    for (int d = 0; d < 16; ++d) a[d] = row[d];
    int dk = *dkp;
    unsigned keep = 0;
    float m = -INFINITY;
    #pragma unroll
    for (int d = 0; d < 16; ++d) {
        int rank = 0;
        #pragma unroll
        for (int j = 0; j < 16; ++j)
            rank += (a[j] > a[d]) || (a[j] == a[d] && j < d);
        if (rank < dk) { keep |= (1u << d); m = fmaxf(m, a[d]); }
    }
    float e[16]; float s = 0.f;
    #pragma unroll
    for (int d = 0; d < 16; ++d) {
        e[d] = (keep >> d & 1u) ? expf(a[d] - m) : 0.f;
        s += e[d];
    }
    float invs = 1.0f / s;
    #pragma unroll
    for (int d = 0; d < 16; ++d) row[d] = e[d] * invs;
}

// attn_v: f32 out (tier-2)
__global__ __launch_bounds__(256) void attn_v_kernel(const float* __restrict__ attnp,
                                                     const float* __restrict__ v,
                                                     float* __restrict__ out) {
    int p = blockIdx.x * 256 + threadIdx.x;
    int cg = blockIdx.y;
    int b = blockIdx.z;
    int h = cg >> 4, cr = cg & 15;
    const float* arow = attnp + (((size_t)b * HEADS + h) * CHh + cr) * CHh;
    const float* vb = v + ((size_t)b * Cc + h * CHh) * Nn + p;
    float acc = 0.f;
    #pragma unroll
    for (int d = 0; d < 16; ++d) acc += arow[d] * vb[(size_t)d * Nn];
    out[((size_t)b * Cc + cg) * Nn + p] = acc;
}

// attn_v: bf16 out.
__global__ __launch_bounds__(256) void attn_v_bf16_kernel(const float* __restrict__ attnp,
                                                          const float* __restrict__ v,
                                                          int vstride, int voff,
                                                          ushort_t* __restrict__ out) {
    int p = blockIdx.x * 256 + threadIdx.x;
    int cg = blockIdx.y;
    int b = blockIdx.z;
    int h = cg >> 4, cr = cg & 15;
    const float* arow = attnp + (((size_t)b * HEADS + h) * CHh + cr) * CHh;
    const float* vb = v + ((size_t)b * vstride + voff + h * CHh) * Nn + p;
    float acc = 0.f;
    #pragma unroll
    for (int d = 0; d < 16; ++d) acc += arow[d] * vb[(size_t)d * Nn];
    out[((size_t)b * Cc + cg) * Nn + p] = f2bf(acc);
}

// ---------------------------------------------------------------------------
// Fused IEL tail v4: full-width 128x16 tiles, vectorized LDS stencil.
// ts col j <-> gx = j-1 (j 0..129 valid; j=0 & 129 zero). stride 132 (16B rows).
// us col j <-> gx = j-1 (j 0..129; j=0 & 129 zero).
// u strip s (s 0..31): outputs j = 1+4s..4+4s, reads ts[j0-1..j0+4] = [4s..4s+5]
//   -> aligned b128 + b64. Final strip x0=4s: reads us[x0..x0+5] aligned.
// grid: (Hh/16, HID, Bt), block 256. LDS ~40 KB.
// ---------------------------------------------------------------------------
__global__ __launch_bounds__(256) void iel_tail_v4_kernel(const ushort_t* __restrict__ Th,
                                                          const float* __restrict__ dww,
                                                          const float* __restrict__ dw1p,
                                                          const float* __restrict__ dw2p,
                                                          ushort_t* __restrict__ PRh) {
    const int gy0 = blockIdx.x * 16;
    const int c   = blockIdx.y;
    const int b   = blockIdx.z;
    const int tid = threadIdx.x;

    __shared__ float ts[2][20][132];
    __shared__ float us[2][18][132];

    const ushort_t* t1 = Th + ((size_t)b * HID2 + c) * Nn;
    const ushort_t* t2 = Th + ((size_t)b * HID2 + HID + c) * Nn;

    // stage: 2 tensors x 20 rows x 16 segs of 8 px. ts[j] with j = gx+1.
    for (int idx = tid; idx < 640; idx += 256) {
        int ti  = idx / 320;
        int rem = idx - ti * 320;
        int i   = rem >> 4;
        int seg = rem & 15;
        int gy  = gy0 - 2 + i;
        const ushort_t* tp = ti ? t2 : t1;
        float vals[8];
        if (gy >= 0 && gy < Hh) {
            uint4 v = *(const uint4*)(tp + gy * Wb + seg * 8);
            vals[0] = bf2f((ushort_t)(v.x & 0xFFFF)); vals[1] = bf2f((ushort_t)(v.x >> 16));
            vals[2] = bf2f((ushort_t)(v.y & 0xFFFF)); vals[3] = bf2f((ushort_t)(v.y >> 16));
            vals[4] = bf2f((ushort_t)(v.z & 0xFFFF)); vals[5] = bf2f((ushort_t)(v.z >> 16));
            vals[6] = bf2f((ushort_t)(v.w & 0xFFFF)); vals[7] = bf2f((ushort_t)(v.w >> 16));
        } else {
            #pragma unroll
            for (int k = 0; k < 8; ++k) vals[k] = 0.f;
        }
        #pragma unroll
        for (int k = 0; k < 8; ++k) ts[ti][i][1 + seg * 8 + k] = vals[k];
        if (seg == 0)  ts[ti][i][0] = 0.f;
        if (seg == 15) { ts[ti][i][129] = 0.f; ts[ti][i][130] = 0.f; ts[ti][i][131] = 0.f; }
    }
    __syncthreads();

    float wA[9], wB[9], w1[9], w2[9];
    #pragma unroll
    for (int k = 0; k < 9; ++k) {
        wA[k] = dww[c * 9 + k];
        wB[k] = dww[(HID + c) * 9 + k];
        w1[k] = dw1p[c * 9 + k];
        w2[k] = dw2p[c * 9 + k];
    }

    // u-stage: 1152 strips (2 tensors x 18 rows x 32 strips of 4).
    for (int idx = tid; idx < 1152; idx += 256) {
        int ti  = idx / 576;
        int rem = idx - ti * 576;
        int i   = rem >> 5;          // row 0..17, gy = gy0-1+i
        int s   = rem & 31;          // strip, outputs j = 1+4s .. 4+4s
        int gy  = gy0 - 1 + i;
        float o0 = 0.f, o1 = 0.f, o2 = 0.f, o3 = 0.f;
        if (gy >= 0 && gy < Hh) {
            const float* wp = ti ? wB : wA;
            #pragma unroll
            for (int dy = 0; dy < 3; ++dy) {
                const float* row = &ts[ti][i + dy][4 * s];
                float4 a = *(const float4*)row;          // j0-1..j0+2
                float2 bb = *(const float2*)(row + 4);   // j0+3, j0+4
                float w0 = wp[dy * 3 + 0], w1t = wp[dy * 3 + 1], w2t = wp[dy * 3 + 2];
                o0 += w0 * a.x + w1t * a.y + w2t * a.z;
                o1 += w0 * a.y + w1t * a.z + w2t * a.w;
                o2 += w0 * a.z + w1t * a.w + w2t * bb.x;
                o3 += w0 * a.w + w1t * bb.x + w2t * bb.y;
            }
        }
        int j0 = 1 + 4 * s;
        us[ti][i][j0]     = o0;
        us[ti][i][j0 + 1] = o1;
        us[ti][i][j0 + 2] = o2;
        us[ti][i][j0 + 3] = o3;
    }
    // edge zeros: us[ti][i][0] and us[ti][i][129]
    if (tid < 72) {
        int ti = tid / 36;
        int r  = tid - ti * 36;
        int i  = r >> 1;
        us[ti][i][(r & 1) ? 129 : 0] = 0.f;
    }
    __syncthreads();

    // final: 512 strips (16 rows x 32 strips of 4 px).
    ushort_t* outp = PRh + ((size_t)b * HID + c) * Nn;
    for (int idx = tid; idx < 512; idx += 256) {
        int r  = idx >> 5;           // tile row, gy = gy0 + r
        int s  = idx & 31;
        int x0 = 4 * s;
        float s1a[4] = {0.f, 0.f, 0.f, 0.f};
        float s2a[4] = {0.f, 0.f, 0.f, 0.f};
        float c1a[4], c2a[4];
        #pragma unroll
        for (int dy = 0; dy < 3; ++dy) {
            const float* r0 = &us[0][r + dy][x0];
            float4 a0 = *(const float4*)r0;
            float2 b0 = *(const float2*)(r0 + 4);
            const float* r1 = &us[1][r + dy][x0];
            float4 a1 = *(const float4*)r1;
            float2 b1 = *(const float2*)(r1 + 4);
            float w10 = w1[dy * 3], w11 = w1[dy * 3 + 1], w12 = w1[dy * 3 + 2];
            float w20 = w2[dy * 3], w21 = w2[dy * 3 + 1], w22 = w2[dy * 3 + 2];
            s1a[0] += w10 * a0.x + w11 * a0.y + w12 * a0.z;
            s1a[1] += w10 * a0.y + w11 * a0.z + w12 * a0.w;
            s1a[2] += w10 * a0.z + w11 * a0.w + w12 * b0.x;
            s1a[3] += w10 * a0.w + w11 * b0.x + w12 * b0.y;
            s2a[0] += w20 * a1.x + w21 * a1.y + w22 * a1.z;
            s2a[1] += w20 * a1.y + w21 * a1.z + w22 * a1.w;
            s2a[2] += w20 * a1.z + w21 * a1.w + w22 * b1.x;
            s2a[3] += w20 * a1.w + w21 * b1.x + w22 * b1.y;
            if (dy == 1) {
                c1a[0] = a0.y; c1a[1] = a0.z; c1a[2] = a0.w; c1a[3] = b0.x;
                c2a[0] = a1.y; c2a[1] = a1.z; c2a[2] = a1.w; c2a[3] = b1.x;
            }
        }
        uint2 pk;
        float v0 = (tanhf(s1a[0]) + c1a[0]) * (tanhf(s2a[0]) + c2a[0]);
        float v1 = (tanhf(s1a[1]) + c1a[1]) * (tanhf(s2a[1]) + c2a[1]);
        float v2 = (tanhf(s1a[2]) + c1a[2]) * (tanhf(s2a[2]) + c2a[2]);
        float v3 = (tanhf(s1a[3]) + c1a[3]) * (tanhf(s2a[3]) + c2a[3]);
        pk.x = (unsigned)f2bf(v0) | ((unsigned)f2bf(v1) << 16);
        pk.y = (unsigned)f2bf(v2) | ((unsigned)f2bf(v3) << 16);
        *(uint2*)(outp + (gy0 + r) * Wb + x0) = pk;
    }
}

// f32 IEL tail (tier-2 fallback; per-chunk layout).
__global__ __launch_bounds__(256) void iel_tail_f32_kernel(const float* __restrict__ t1p,
                                                           const float* __restrict__ t2p,
                                                           const float* __restrict__ dwA,
                                                           const float* __restrict__ dwB,
                                                           const float* __restrict__ dw1p,
                                                           const float* __restrict__ dw2p,
                                                           float* __restrict__ prod) {
    const int c = blockIdx.y;
    const int tilesx = Wb / 16;
    const int ty0 = (blockIdx.x / tilesx) * 16;
    const int tx0 = (blockIdx.x % tilesx) * 16;
    const int tid = threadIdx.x;

    __shared__ float ts[2][20][24];
    __shared__ float us[2][18][24];

    const float* t1 = t1p + (size_t)c * Nn;
    const float* t2 = t2p + (size_t)c * Nn;

    for (int idx = tid; idx < 400; idx += 256) {
        int i = idx / 20, j = idx % 20;
        int gy = ty0 - 2 + i, gx = tx0 - 2 + j;
        bool ok = (gy >= 0 && gy < Hh && gx >= 0 && gx < Wb);
        ts[0][i][j] = ok ? t1[gy * Wb + gx] : 0.f;
        ts[1][i][j] = ok ? t2[gy * Wb + gx] : 0.f;
    }
    __syncthreads();

    float wA[9], wB[9], w1[9], w2[9];
    #pragma unroll
    for (int k = 0; k < 9; ++k) {
        wA[k] = dwA[c * 9 + k];
        wB[k] = dwB[c * 9 + k];
        w1[k] = dw1p[c * 9 + k];
        w2[k] = dw2p[c * 9 + k];
    }

    for (int idx = tid; idx < 324; idx += 256) {
        int i = idx / 18, j = idx % 18;
        int gy = ty0 - 1 + i, gx = tx0 - 1 + j;
        float a0 = 0.f, a1 = 0.f;
        if (gy >= 0 && gy < Hh && gx >= 0 && gx < Wb) {
            #pragma unroll
            for (int dy = 0; dy < 3; ++dy)
                #pragma unroll
                for (int dx = 0; dx < 3; ++dx) {
                    a0 += wA[dy * 3 + dx] * ts[0][i + dy][j + dx];
                    a1 += wB[dy * 3 + dx] * ts[1][i + dy][j + dx];
                }
        }
        us[0][i][j] = a0;
        us[1][i][j] = a1;
    }
    __syncthreads();

    int ty = tid >> 4, tx = tid & 15;
    float c1 = us[0][ty + 1][tx + 1];
    float c2 = us[1][ty + 1][tx + 1];
    float s1 = 0.f, s2 = 0.f;
    #pragma unroll
    for (int dy = 0; dy < 3; ++dy)
        #pragma unroll
        for (int dx = 0; dx < 3; ++dx) {
            s1 += w1[dy * 3 + dx] * us[0][ty + dy][tx + dx];
            s2 += w2[dy * 3 + dx] * us[1][ty + dy][tx + dx];
        }
    float x1t = tanhf(s1) + c1;
    float x2t = tanhf(s2) + c2;
    prod[(size_t)c * Nn + (ty0 + ty) * Wb + (tx0 + tx)] = x1t * x2t;
}

// ---------------------------------------------------------------------------
// Host launcher
// ---------------------------------------------------------------------------
extern "C" void kernel_launch(void* const* d_in, const int* in_sizes, int n_in,
                              void* d_out, int out_size, void* d_ws, size_t ws_size,
                              hipStream_t stream) {
    const float* x      = (const float*)d_in[0];
    const float* y      = (const float*)d_in[1];
    const float* ln_w   = (const float*)d_in[2];
    const float* ln_b   = (const float*)d_in[3];
    const float* temp   = (const float*)d_in[4];
    const float* q_w    = (const float*)d_in[5];
    const float* qdw_w  = (const float*)d_in[6];
    const float* kv_w   = (const float*)d_in[7];
    const float* kvdw_w = (const float*)d_in[8];
    const float* po_w   = (const float*)d_in[9];
    const float* g1_w   = (const float*)d_in[10];
    const float* g1_b   = (const float*)d_in[11];
    const float* g2_w   = (const float*)d_in[12];
    const float* g2_b   = (const float*)d_in[13];
    const float* pin_w  = (const float*)d_in[14];
    const float* dw_w   = (const float*)d_in[15];
    const float* dw1_w  = (const float*)d_in[16];
    const float* dw2_w  = (const float*)d_in[17];
    const float* pout_w = (const float*)d_in[18];
    float* out = (float*)d_out;

    // smalls in first 1 MiB
    char* ws = (char*)d_ws;
    float* attn      = (float*)ws;                        // 32 KB
    float* blocksums = (float*)(ws + 32768);              // 1 KB
    int*   dk        = (int*)(ws + 33792);
    ushort_t* qWh  = (ushort_t*)(ws + 34816);             // 128x128
    ushort_t* kvWh = qWh + 16384;                         // 256x128
    ushort_t* poWh = kvWh + 32768;                        // 128x128
    ushort_t* g1Wh = poWh + 16384;                        // 64x128
    ushort_t* Wh1  = g1Wh + 8192;                         // 704x128
    ushort_t* Wh2  = Wh1 + (size_t)MPAD * Cc;             // 128x352
    float* pool    = (float*)(ws + (1u << 20));

    const size_t CN    = (size_t)Cc * Nn;
    const size_t SLOT1 = (size_t)Bn * CN;
    const size_t TIER1_NEED = 65536 + 6 * SLOT1 * 4;

    dim3 blk(256);
    const int PGX = Nn / 1024;

    if (ws_size >= TIER1_NEED) {
        // ---- buffers ----
        float* S3 = pool;                                  // q2 f32 [B][128][Nn]
        float* S4 = pool + 8 * 1024 * 1024;                // k2+v2 f32 [B][256][Nn]
        ushort_t* XNh  = (ushort_t*)(pool + 24 * 1024 * 1024);
        ushort_t* YNh  = XNh + Bn * CN;
        ushort_t* KV1h = YNh + Bn * CN;
        ushort_t* Q1h  = KV1h + 2 * Bn * CN;
        float* gmid    = (float*)Q1h;
        float* partial = gmid;
        ushort_t* AOh  = XNh;

        wconv_pad_rows_kernel<<<dim3(64), blk, 0, stream>>>(q_w, qWh, 128, Cc);
        wconv_pad_rows_kernel<<<dim3(128), blk, 0, stream>>>(kv_w, kvWh, 256, Cc);
        wconv_pad_rows_kernel<<<dim3(64), blk, 0, stream>>>(po_w, poWh, 128, Cc);
        wconv_pad_rows_kernel<<<dim3(32), blk, 0, stream>>>(g1_w, g1Wh, 64, Cc);
        wconv_pad_rows_kernel<<<dim3(MPAD * Cc / 256), blk, 0, stream>>>(pin_w, Wh1, HID2, Cc);
        wconv_pad_cols_kernel<<<dim3(Cc * KPAD2 / 256), blk, 0, stream>>>(pout_w, Wh2, HID, KPAD2);

        // ---- Phase A ----
        ln_bf16_kernel<<<dim3(Nn / 256, 1, Bn), blk, 0, stream>>>(x, ln_w, ln_b, XNh);
        ln_bf16_kernel<<<dim3(Nn / 256, 1, Bn), blk, 0, stream>>>(y, ln_w, ln_b, YNh);

        gemm_bf16_kernel<<<dim3(Nn / 128, 2, Bn), blk, 0, stream>>>(
            XNh, qWh, nullptr, nullptr, nullptr, Q1h, Cc, Cc, Cc, 0);
        dw3x3_bf16_kernel<<<dim3(Nn / 256, Cc, Bn), blk, 0, stream>>>(Q1h, qdw_w, S3, Cc);

        gemm_bf16_kernel<<<dim3(Nn / 128, 4, Bn), blk, 0, stream>>>(
            YNh, kvWh, nullptr, nullptr, nullptr, KV1h, Cc, Cc, 2 * Cc, 0);
        dw3x3_bf16_kernel<<<dim3(Nn / 256, 2 * Cc, Bn), blk, 0, stream>>>(KV1h, kvdw_w, S4, 2 * Cc);

        gemm_bf16_kernel<<<dim3(Nn / 128, 1, Bn), blk, 0, stream>>>(
            XNh, g1Wh, g1_b, nullptr, gmid, nullptr, Cc, Cc, 64, 1);
        gate2_kernel<<<dim3(Nn / 256, 1, Bn), blk, 0, stream>>>(gmid, g2_w, g2_b, blocksums, 0);
        gate_final_kernel<<<dim3(1), blk, 0, stream>>>(blocksums, dk);

        l2norm_kernel<<<dim3(Cc, 1, Bn), blk, 0, stream>>>(S3, Cc);
        l2norm_kernel<<<dim3(Cc, 1, Bn), blk, 0, stream>>>(S4, 2 * Cc);

        attn_qk_partial_kernel<<<dim3(NS, HEADS, Bn), blk, 0, stream>>>(S3, S4, 2 * Cc, partial);
        attn_reduce_kernel<<<dim3(Bn * HEADS), blk, 0, stream>>>(partial, temp, attn);
        topk_softmax_kernel<<<dim3(Bn * HEADS), dim3(16), 0, stream>>>(attn, dk);
        attn_v_bf16_kernel<<<dim3(Nn / 256, Cc, Bn), blk, 0, stream>>>(
            attn, S4, 2 * Cc, Cc, AOh);

        gemm_bf16_kernel<<<dim3(Nn / 128, 2, Bn), blk, 0, stream>>>(
            AOh, poWh, nullptr, x, out, nullptr, Cc, Cc, Cc, 0);

        // ---- Phase B ----
        ushort_t* ZNh = (ushort_t*)pool;
        ushort_t* Th  = ZNh + Bn * CN;
        ushort_t* PRh = Th + (size_t)Bn * HID2 * Nn;

        ln_bf16_kernel<<<dim3(Nn / 256, 1, Bn), blk, 0, stream>>>(out, ln_w, ln_b, ZNh);

        gemm_bf16_kernel<<<dim3(Nn / 128, MPAD / 64, Bn), blk, 0, stream>>>(
            ZNh, Wh1, nullptr, nullptr, nullptr, Th, Cc, Cc, HID2, 0);

        iel_tail_v4_kernel<<<dim3(Hh / 16, HID, Bn), blk, 0, stream>>>(
            Th, dw_w, dw1_w, dw2_w, PRh);

        gemm_bf16_kernel<<<dim3(Nn / 128, 2, Bn), blk, 0, stream>>>(
            PRh, Wh2, nullptr, out, out, nullptr, HID, KPAD2, Cc, 0);
    } else {
        // ================= Tier 2: per-batch f32 fallback ===================
        float* s0 = pool;
        float* s1 = pool + 1 * CN;
        float* s2 = pool + 2 * CN;
        float* s3 = pool + 3 * CN;
        float* s4 = pool + 4 * CN;
        float* s5 = pool + 5 * CN;

        for (int b = 0; b < Bn; ++b) {
            const float* xb = x + (size_t)b * CN;
            ln_kernel<<<dim3(Nn / 256, 1, 1), blk, 0, stream>>>(xb, ln_w, ln_b, s0);
            conv1x1v_kernel<4><<<dim3(PGX, 16, 1), blk, 0, stream>>>(
                s0, g1_w, Cc, g1_b, nullptr, s1, Cc, 64, 1);
            gate2_kernel<<<dim3(Nn / 256, 1, 1), blk, 0, stream>>>(
                s1, g2_w, g2_b, blocksums, b * 64);
        }
        gate_final_kernel<<<dim3(1), blk, 0, stream>>>(blocksums, dk);

        for (int b = 0; b < Bn; ++b) {
            const float* xb = x + (size_t)b * CN;
            const float* yb = y + (size_t)b * CN;
            float* outb = out + (size_t)b * CN;
            float* attnb = attn + (size_t)b * HEADS * CHh * CHh;

            ln_kernel<<<dim3(Nn / 256, 1, 1), blk, 0, stream>>>(xb, ln_w, ln_b, s0);
            ln_kernel<<<dim3(Nn / 256, 1, 1), blk, 0, stream>>>(yb, ln_w, ln_b, s1);

            conv1x1v_kernel<8><<<dim3(PGX, 16, 1), blk, 0, stream>>>(
                s0, q_w, Cc, nullptr, nullptr, s2, Cc, Cc, 0);
            dw3x3_kernel<<<dim3(Nn / 256, Cc, 1), blk, 0, stream>>>(s2, qdw_w, s3, Cc);
            l2norm_kernel<<<dim3(Cc, 1, 1), blk, 0, stream>>>(s3, Cc);

            conv1x1v_kernel<8><<<dim3(PGX, 16, 1), blk, 0, stream>>>(
                s1, kv_w, Cc, nullptr, nullptr, s2, Cc, Cc, 0);
            dw3x3_kernel<<<dim3(Nn / 256, Cc, 1), blk, 0, stream>>>(s2, kvdw_w, s4, Cc);
            l2norm_kernel<<<dim3(Cc, 1, 1), blk, 0, stream>>>(s4, Cc);

            conv1x1v_kernel<8><<<dim3(PGX, 16, 1), blk, 0, stream>>>(
                s1, kv_w + 128 * 128, Cc, nullptr, nullptr, s2, Cc, Cc, 0);
            dw3x3_kernel<<<dim3(Nn / 256, Cc, 1), blk, 0, stream>>>(s2, kvdw_w + 128 * 9, s5, Cc);

            attn_qk_partial_kernel<<<dim3(NS, HEADS, 1), blk, 0, stream>>>(s3, s4, Cc, s2);
            attn_reduce_kernel<<<dim3(HEADS), blk, 0, stream>>>(s2, temp, attnb);
            topk_softmax_kernel<<<dim3(HEADS), dim3(16), 0, stream>>>(attnb, dk);
            attn_v_kernel<<<dim3(Nn / 256, Cc, 1), blk, 0, stream>>>(attnb, s5, s2);

            conv1x1v_kernel<8><<<dim3(PGX, 16, 1), blk, 0, stream>>>(
                s2, po_w, Cc, nullptr, xb, outb, Cc, Cc, 0);
        }

        const int CHUNK = 170;
        const size_t TCH = (size_t)CHUNK * Nn;
        float* zn   = pool;
        float* T1   = pool + CN;
        float* T2   = T1 + TCH;
        float* prod = T2 + TCH;
        for (int b = 0; b < Bn; ++b) {
            float* outb = out + (size_t)b * CN;
            ln_kernel<<<dim3(Nn / 256, 1, 1), blk, 0, stream>>>(outb, ln_w, ln_b, zn);
            for (int c0 = 0; c0 < HID; c0 += CHUNK) {
                conv1x1v_kernel<20><<<dim3(PGX, 9, 1), blk, 0, stream>>>(
                    zn, pin_w + (size_t)c0 * Cc, Cc, nullptr, nullptr, T1, Cc, CHUNK, 0);
                conv1x1v_kernel<20><<<dim3(PGX, 9, 1), blk, 0, stream>>>(
                    zn, pin_w + (size_t)(HID + c0) * Cc, Cc, nullptr, nullptr, T2, Cc, CHUNK, 0);
                iel_tail_f32_kernel<<<dim3(64, CHUNK, 1), blk, 0, stream>>>(
                    T1, T2, dw_w + c0 * 9, dw_w + (HID + c0) * 9,
                    dw1_w + c0 * 9, dw2_w + c0 * 9, prod);
                conv1x1v_kernel<8><<<dim3(PGX, 16, 1), blk, 0, stream>>>(
                    prod, pout_w + c0, HID, nullptr, outb, outb, CHUNK, Cc, 0);
            }
        }
    }
}